// Round 1
// baseline (5658.638 us; speedup 1.0000x reference)
//
#include <hip/hip_runtime.h>
#include <hip/hip_bf16.h>
#include <cstddef>

#define DEVI __device__ __forceinline__

typedef __attribute__((ext_vector_type(4))) float f4v;
typedef __attribute__((ext_vector_type(8))) short s8v;
typedef __attribute__((ext_vector_type(4))) short s4v;

using bf16 = __hip_bfloat16;

// L=8, B=8, N=512, C=1024, H=16, D=64
constexpr float SELU_A = 1.6732632423543772f;
constexpr float SELU_S = 1.0507009873554805f;
constexpr float TPINV  = 0.08838834764831845f; // 1/sqrt(2*D) = 1/sqrt(128)

DEVI float bfbits(short s) { return __uint_as_float(((unsigned)(unsigned short)s) << 16); }
DEVI unsigned short f2bu(float f) {
  bf16 h = __float2bfloat16(f);
  return __builtin_bit_cast(unsigned short, h);
}
DEVI float seluf(float x) { return x > 0.f ? SELU_S * x : SELU_S * SELU_A * (__expf(x) - 1.f); }

// ---------------- conditioning: cs[b][j] = selu(label.Wl[j] + bl[j] + te(b,j))
__global__ void k_cond(const float* __restrict__ tim, const float* __restrict__ lab,
                       const float* __restrict__ Wl, const float* __restrict__ bl,
                       float* __restrict__ cs)
{
  int b = blockIdx.x, t = threadIdx.x;
  float l0 = lab[b * 2 + 0], l1 = lab[b * 2 + 1], tv = tim[b];
  #pragma unroll
  for (int i = 0; i < 4; i++) {
    int j = t + 256 * i;
    float e = powf(10000.f, (2.f * (float)j) * (1.f / 1024.f));
    float arg = tv / e;
    float te = ((j & 1) == 0) ? sinf(arg) : cosf(arg);
    float c = l0 * Wl[j * 2 + 0] + l1 * Wl[j * 2 + 1] + bl[j] + te;
    cs[b * 1024 + j] = seluf(c);
  }
}

// ---------------- small matvec batch: out = cs(8x1024) @ W(O x 1024)^T + bias
// mode 0: O=49152 (L*6144), out[(l*8+b)*6144 + feat]; mode 1: O=2048, out[b*2048+o]
__global__ __launch_bounds__(256) void k_small(
    const float* __restrict__ cs, const float* __restrict__ W, const float* __restrict__ bias,
    float* __restrict__ out, int O, int mode)
{
  __shared__ float cls[8192];
  int t = threadIdx.x;
  #pragma unroll
  for (int i = 0; i < 8; i++)
    *(f4v*)&cls[i * 1024 + t * 4] = *(const f4v*)&cs[i * 1024 + t * 4];
  __syncthreads();
  int w = t >> 6, l = t & 63;
  int o = blockIdx.x * 4 + w;
  if (o >= O) return;
  float acc[8] = {0.f, 0.f, 0.f, 0.f, 0.f, 0.f, 0.f, 0.f};
  const float* Wr = W + (size_t)o * 1024;
  for (int i = 0; i < 16; i++) {
    int k = i * 64 + l;
    float wv = Wr[k];
    #pragma unroll
    for (int b = 0; b < 8; b++) acc[b] += wv * cls[b * 1024 + k];
  }
  #pragma unroll
  for (int b = 0; b < 8; b++) {
    #pragma unroll
    for (int off = 32; off; off >>= 1) acc[b] += __shfl_xor(acc[b], off);
  }
  float bv = bias[o];
  #pragma unroll
  for (int b = 0; b < 8; b++) {
    if (l == b) {
      float val = acc[b] + bv;
      size_t dst;
      if (mode == 0) { int ll = o / 6144, ft = o - ll * 6144; dst = ((size_t)ll * 8 + b) * 6144 + ft; }
      else dst = (size_t)b * 2048 + o;
      out[dst] = val;
    }
  }
}

// ---------------- row LN + modulate (+optional mask) -> bf16
__global__ __launch_bounds__(256) void k_lnmod(
    const float* __restrict__ x, const float* __restrict__ shiftB, const float* __restrict__ scaleB,
    int bstride, const float* __restrict__ xm, bf16* __restrict__ out, int domask)
{
  int row = blockIdx.x, t = threadIdx.x, b = row >> 9;
  const float* xr = x + (size_t)row * 1024;
  f4v v = *(const f4v*)&xr[t * 4];
  float s = v[0] + v[1] + v[2] + v[3];
  float ss = v[0]*v[0] + v[1]*v[1] + v[2]*v[2] + v[3]*v[3];
  #pragma unroll
  for (int off = 32; off; off >>= 1) { s += __shfl_xor(s, off); ss += __shfl_xor(ss, off); }
  __shared__ float rs[4], rss[4];
  int w = t >> 6;
  if ((t & 63) == 0) { rs[w] = s; rss[w] = ss; }
  __syncthreads();
  s = rs[0] + rs[1] + rs[2] + rs[3];
  ss = rss[0] + rss[1] + rss[2] + rss[3];
  float mean = s * (1.f / 1024.f);
  float var = ss * (1.f / 1024.f) - mean * mean;
  float rstd = rsqrtf(var + 1e-6f);
  float mk = domask ? xm[row] : 1.f;
  f4v sh = *(const f4v*)&shiftB[(size_t)b * bstride + t * 4];
  f4v sc = *(const f4v*)&scaleB[(size_t)b * bstride + t * 4];
  s4v o;
  #pragma unroll
  for (int i = 0; i < 4; i++) {
    float hv = ((v[i] - mean) * rstd * (1.f + sc[i]) + sh[i]) * mk;
    o[i] = (short)f2bu(hv);
  }
  *(s4v*)&out[(size_t)row * 1024 + t * 4] = o;
}

// ---------------- x += gm*att; write x; h2 = modulate(ln(x), sf, cf) -> bf16
__global__ __launch_bounds__(256) void k_resid(
    float* __restrict__ x, const bf16* __restrict__ att, const float* __restrict__ m6b,
    bf16* __restrict__ h2)
{
  int row = blockIdx.x, t = threadIdx.x, b = row >> 9;
  float* xr = x + (size_t)row * 1024;
  const float* gm = m6b + (size_t)b * 6144 + 2048;
  const float* sf = m6b + (size_t)b * 6144 + 3072;
  const float* cf = m6b + (size_t)b * 6144 + 4096;
  f4v xv = *(const f4v*)&xr[t * 4];
  s4v av = *(const s4v*)&att[(size_t)row * 1024 + t * 4];
  f4v gv = *(const f4v*)&gm[t * 4];
  f4v vv;
  #pragma unroll
  for (int i = 0; i < 4; i++) vv[i] = xv[i] + gv[i] * bfbits(av[i]);
  *(f4v*)&xr[t * 4] = vv;
  float s = vv[0] + vv[1] + vv[2] + vv[3];
  float ss = vv[0]*vv[0] + vv[1]*vv[1] + vv[2]*vv[2] + vv[3]*vv[3];
  #pragma unroll
  for (int off = 32; off; off >>= 1) { s += __shfl_xor(s, off); ss += __shfl_xor(ss, off); }
  __shared__ float rs[4], rss[4];
  int w = t >> 6;
  if ((t & 63) == 0) { rs[w] = s; rss[w] = ss; }
  __syncthreads();
  s = rs[0] + rs[1] + rs[2] + rs[3];
  ss = rss[0] + rss[1] + rss[2] + rss[3];
  float mean = s * (1.f / 1024.f);
  float var = ss * (1.f / 1024.f) - mean * mean;
  float rstd = rsqrtf(var + 1e-6f);
  f4v sfv = *(const f4v*)&sf[t * 4];
  f4v cfv = *(const f4v*)&cf[t * 4];
  s4v o;
  #pragma unroll
  for (int i = 0; i < 4; i++)
    o[i] = (short)f2bu((vv[i] - mean) * rstd * (1.f + cfv[i]) + sfv[i]);
  *(s4v*)&h2[(size_t)row * 1024 + t * 4] = o;
}

// ---------------- attention: online softmax, per (b,h,qtile32) block; q/k/v (B,H,N,64) bf16
__global__ __launch_bounds__(256) void k_attn(
    const bf16* __restrict__ q, const bf16* __restrict__ k, const bf16* __restrict__ v,
    const float* __restrict__ xm, bf16* __restrict__ att)
{
  int bh = blockIdx.y, b = bh >> 4, hh = bh & 15;
  int qt = blockIdx.x;
  int t = threadIdx.x, w = t >> 6, lane = t & 63;
  int qg = lane >> 3, li = lane & 7;
  int qi = w * 8 + qg;
  int nq = qt * 32 + qi;

  __shared__ float qls[32][68];
  __shared__ float xkl[512];
  __shared__ bf16 kls[64][68];
  __shared__ bf16 vls[64][68];

  const size_t ho = (size_t)bh * (512 * 64);

  { int qr = t >> 3, d0 = (t & 7) * 8;
    s8v qv = *(const s8v*)(q + ho + (size_t)(qt * 32 + qr) * 64 + d0);
    #pragma unroll
    for (int i = 0; i < 8; i++) qls[qr][d0 + i] = bfbits(qv[i]);
  }
  for (int i = t; i < 512; i += 256) xkl[i] = xm[b * 512 + i];
  __syncthreads();

  float xq = xkl[nq];
  float qreg[64];
  #pragma unroll
  for (int d4 = 0; d4 < 16; d4++) *(f4v*)&qreg[d4 * 4] = *(const f4v*)&qls[qi][d4 * 4];

  float m = -3.0e38f, lsum = 0.f;
  float ov[64];
  #pragma unroll
  for (int d = 0; d < 64; d++) ov[d] = 0.f;

  for (int kt = 0; kt < 8; kt++) {
    __syncthreads();
    { int kr = t >> 2, c0 = (t & 3) * 16;
      const s4v* ks = (const s4v*)(k + ho + (size_t)(kt * 64 + kr) * 64 + c0);
      const s4v* vs = (const s4v*)(v + ho + (size_t)(kt * 64 + kr) * 64 + c0);
      s4v k0 = ks[0], k1 = ks[1], k2 = ks[2], k3 = ks[3];
      s4v v0 = vs[0], v1 = vs[1], v2 = vs[2], v3 = vs[3];
      s4v* kd = (s4v*)&kls[kr][c0];
      kd[0] = k0; kd[1] = k1; kd[2] = k2; kd[3] = k3;
      s4v* vd = (s4v*)&vls[kr][c0];
      vd[0] = v0; vd[1] = v1; vd[2] = v2; vd[3] = v3;
    }
    __syncthreads();
    float s[8];
    #pragma unroll
    for (int jj = 0; jj < 8; jj++) {
      int j = jj * 8 + li;
      float acc = 0.f;
      #pragma unroll
      for (int d4 = 0; d4 < 16; d4++) {
        s4v kv = *(const s4v*)&kls[j][d4 * 4];
        acc += qreg[d4 * 4 + 0] * bfbits(kv[0]);
        acc += qreg[d4 * 4 + 1] * bfbits(kv[1]);
        acc += qreg[d4 * 4 + 2] * bfbits(kv[2]);
        acc += qreg[d4 * 4 + 3] * bfbits(kv[3]);
      }
      float sv = acc * TPINV;
      if (xq != xkl[kt * 64 + j]) sv = -3.0e38f;
      s[jj] = sv;
    }
    float tm = s[0];
    #pragma unroll
    for (int jj = 1; jj < 8; jj++) tm = fmaxf(tm, s[jj]);
    tm = fmaxf(tm, __shfl_xor(tm, 1));
    tm = fmaxf(tm, __shfl_xor(tm, 2));
    tm = fmaxf(tm, __shfl_xor(tm, 4));
    float mn = fmaxf(m, tm);
    float corr = (m > -1e30f) ? __expf(m - mn) : 0.f;
    lsum *= corr;
    #pragma unroll
    for (int d = 0; d < 64; d++) ov[d] *= corr;
    float p[8];
    #pragma unroll
    for (int jj = 0; jj < 8; jj++) {
      p[jj] = (s[jj] > -1e30f) ? __expf(s[jj] - mn) : 0.f;
      lsum += p[jj];
    }
    #pragma unroll
    for (int jj = 0; jj < 8; jj++) {
      int j = jj * 8 + li;
      #pragma unroll
      for (int d4 = 0; d4 < 16; d4++) {
        s4v vv2 = *(const s4v*)&vls[j][d4 * 4];
        ov[d4 * 4 + 0] += p[jj] * bfbits(vv2[0]);
        ov[d4 * 4 + 1] += p[jj] * bfbits(vv2[1]);
        ov[d4 * 4 + 2] += p[jj] * bfbits(vv2[2]);
        ov[d4 * 4 + 3] += p[jj] * bfbits(vv2[3]);
      }
    }
    m = mn;
  }
  lsum += __shfl_xor(lsum, 1);
  lsum += __shfl_xor(lsum, 2);
  lsum += __shfl_xor(lsum, 4);
  float inv = 1.f / lsum;
  #pragma unroll
  for (int d = 0; d < 64; d++) {
    float o = ov[d];
    o += __shfl_xor(o, 1); o += __shfl_xor(o, 2); o += __shfl_xor(o, 4);
    ov[d] = o * inv;
  }
  if (li == 0) {
    unsigned* dp = (unsigned*)(att + (size_t)(b * 512 + nq) * 1024 + hh * 64);
    #pragma unroll
    for (int i = 0; i < 32; i++) {
      unsigned pk = (unsigned)f2bu(ov[2 * i]) | ((unsigned)f2bu(ov[2 * i + 1]) << 16);
      dp[i] = pk;
    }
  }
}

// ---------------- GEMM: out[m][n] = epi( sum_k A[m][k]*W[n][k] + bias[n] )
// A bf16 (MxK), W fp32 (NxK). EPI: 0=QKV permuted store (3 fused weights),
// 1=selu+bias->bf16, 2=residual+gate+mask (x in/out f32), 3=bias+mask->f32
template <int EPI>
__global__ __launch_bounds__(256) void k_gemm(
    const bf16* __restrict__ A, const float* __restrict__ W,
    const float* __restrict__ Wb2, const float* __restrict__ Wb3,
    const float* __restrict__ bias, int K, int Ncols,
    bf16* __restrict__ outb, float* __restrict__ outf,
    float* __restrict__ xio, const float* __restrict__ gfb,
    const float* __restrict__ xmk)
{
  __shared__ bf16 As[128][40];
  __shared__ bf16 Ws[128][40];
  int t = threadIdx.x, lane = t & 63, w = t >> 6;
  int wr = w >> 1, wc = w & 1;
  int m0 = blockIdx.y * 128, n0 = blockIdx.x * 128;

  const float* Wuse = W;
  int nloc = n0;
  if (EPI == 0) {
    int sel = n0 >> 10;
    Wuse = (sel == 0) ? W : ((sel == 1) ? Wb2 : Wb3);
    nloc = n0 & 1023;
  }

  int arow = t >> 1, ac0 = (t & 1) * 16;
  const bf16* aptr = A + (size_t)(m0 + arow) * K + ac0;
  const float* wptr = Wuse + (size_t)(nloc + arow) * K + ac0;

  const f4v vzero = {0.f, 0.f, 0.f, 0.f};
  f4v acc[4][4];
  #pragma unroll
  for (int i = 0; i < 4; i++)
    #pragma unroll
    for (int j = 0; j < 4; j++) acc[i][j] = vzero;

  int fr = lane & 15, kq = (lane >> 4) * 8;
  int nkt = K >> 5;
  for (int kt = 0; kt < nkt; kt++) {
    __syncthreads();
    s8v a0 = *(const s8v*)(aptr);
    s8v a1 = *(const s8v*)(aptr + 8);
    f4v w0 = *(const f4v*)(wptr);
    f4v w1 = *(const f4v*)(wptr + 4);
    f4v w2 = *(const f4v*)(wptr + 8);
    f4v w3 = *(const f4v*)(wptr + 12);
    *(s8v*)&As[arow][ac0] = a0;
    *(s8v*)&As[arow][ac0 + 8] = a1;
    s4v wb;
    wb[0] = (short)f2bu(w0[0]); wb[1] = (short)f2bu(w0[1]); wb[2] = (short)f2bu(w0[2]); wb[3] = (short)f2bu(w0[3]);
    *(s4v*)&Ws[arow][ac0 + 0] = wb;
    wb[0] = (short)f2bu(w1[0]); wb[1] = (short)f2bu(w1[1]); wb[2] = (short)f2bu(w1[2]); wb[3] = (short)f2bu(w1[3]);
    *(s4v*)&Ws[arow][ac0 + 4] = wb;
    wb[0] = (short)f2bu(w2[0]); wb[1] = (short)f2bu(w2[1]); wb[2] = (short)f2bu(w2[2]); wb[3] = (short)f2bu(w2[3]);
    *(s4v*)&Ws[arow][ac0 + 8] = wb;
    wb[0] = (short)f2bu(w3[0]); wb[1] = (short)f2bu(w3[1]); wb[2] = (short)f2bu(w3[2]); wb[3] = (short)f2bu(w3[3]);
    *(s4v*)&Ws[arow][ac0 + 12] = wb;
    __syncthreads();
    s8v af[4], bfr[4];
    #pragma unroll
    for (int mf = 0; mf < 4; mf++) af[mf] = *(const s8v*)&As[wr * 64 + mf * 16 + fr][kq];
    #pragma unroll
    for (int nf = 0; nf < 4; nf++) bfr[nf] = *(const s8v*)&Ws[wc * 64 + nf * 16 + fr][kq];
    #pragma unroll
    for (int mf = 0; mf < 4; mf++)
      #pragma unroll
      for (int nf = 0; nf < 4; nf++)
        acc[mf][nf] = __builtin_amdgcn_mfma_f32_16x16x32_bf16(af[mf], bfr[nf], acc[mf][nf], 0, 0, 0);
    aptr += 32;
    wptr += 32;
  }

  int rq = (lane >> 4) * 4;
  #pragma unroll
  for (int mf = 0; mf < 4; mf++) {
    #pragma unroll
    for (int nf = 0; nf < 4; nf++) {
      #pragma unroll
      for (int r = 0; r < 4; r++) {
        int row = m0 + wr * 64 + mf * 16 + rq + r;
        int col = n0 + wc * 64 + nf * 16 + fr;
        float val = acc[mf][nf][r];
        if (EPI == 0) {
          int sel = col >> 10, cl = col & 1023;
          int bb = row >> 9, nn = row & 511, h2 = cl >> 6, dd = cl & 63;
          outb[(size_t)sel * 4194304 + (((size_t)bb * 16 + h2) * 512 + nn) * 64 + dd] = __float2bfloat16(val);
        } else if (EPI == 1) {
          outb[(size_t)row * Ncols + col] = __float2bfloat16(seluf(val + bias[col]));
        } else if (EPI == 2) {
          int bb = row >> 9;
          size_t idx = (size_t)row * 1024 + col;
          float nx = (xio[idx] + gfb[(size_t)bb * 6144 + col] * (val + bias[col])) * xmk[row];
          xio[idx] = nx;
        } else {
          outf[(size_t)row * 1024 + col] = (val + bias[col]) * xmk[row];
        }
      }
    }
  }
}

extern "C" void kernel_launch(void* const* d_in, const int* in_sizes, int n_in,
                              void* d_out, int out_size, void* d_ws, size_t ws_size,
                              hipStream_t stream)
{
  const float* x_in  = (const float*)d_in[0];
  const float* tim   = (const float*)d_in[1];
  const float* lab   = (const float*)d_in[2];
  const float* xmask = (const float*)d_in[3];
  const float* Wl  = (const float*)d_in[4];
  const float* bl  = (const float*)d_in[5];
  const float* Wq  = (const float*)d_in[6];
  const float* Wk  = (const float*)d_in[7];
  const float* Wv  = (const float*)d_in[8];
  const float* W1  = (const float*)d_in[9];
  const float* b1  = (const float*)d_in[10];
  const float* W2  = (const float*)d_in[11];
  const float* b2  = (const float*)d_in[12];
  const float* Wm  = (const float*)d_in[13];
  const float* bm  = (const float*)d_in[14];
  const float* Wf  = (const float*)d_in[15];
  const float* bfp = (const float*)d_in[16];
  const float* Wmf = (const float*)d_in[17];
  const float* bmf = (const float*)d_in[18];

  char* ws = (char*)d_ws;
  float* x    = (float*)(ws + 0);         // 16777216 B
  float* cs   = (float*)(ws + 16777216);  // 32768 B
  float* mAll = (float*)(ws + 16809984);  // 1572864 B  [L][B][6144]
  float* m2v  = (float*)(ws + 18382848);  // 65536 B    [B][2048]
  bf16*  h    = (bf16*)(ws + 18448384);   // 8388608 B
  bf16*  qb   = (bf16*)(ws + 26836992);   // 8388608 B  (B,H,N,D)
  bf16*  kb   = (bf16*)(ws + 35225600);   // 8388608 B
  bf16*  vb   = (bf16*)(ws + 43614208);   // 8388608 B
  bf16*  att  = (bf16*)(ws + 52002816);   // 8388608 B  (B,N,C)
  bf16*  f1   = (bf16*)(ws + 60391424);   // 33554432 B (4096 x 4096)

  hipMemcpyAsync(x, x_in, (size_t)4096 * 1024 * 4, hipMemcpyDeviceToDevice, stream);

  k_cond<<<8, 256, 0, stream>>>(tim, lab, Wl, bl, cs);
  k_small<<<12288, 256, 0, stream>>>(cs, Wm, bm, mAll, 49152, 0);
  k_small<<<512, 256, 0, stream>>>(cs, Wmf, bmf, m2v, 2048, 1);

  for (int l = 0; l < 8; l++) {
    const float* m6b = mAll + (size_t)l * 8 * 6144;
    const float* wq = Wq + (size_t)l * 1024 * 1024;
    const float* wk = Wk + (size_t)l * 1024 * 1024;
    const float* wv = Wv + (size_t)l * 1024 * 1024;

    k_lnmod<<<4096, 256, 0, stream>>>(x, m6b + 0, m6b + 1024, 6144, xmask, h, 1);
    k_gemm<0><<<dim3(24, 32), 256, 0, stream>>>(h, wq, wk, wv, nullptr, 1024, 1024,
                                                qb, nullptr, nullptr, nullptr, nullptr);
    k_attn<<<dim3(16, 128), 256, 0, stream>>>(qb, kb, vb, xmask, att);
    k_resid<<<4096, 256, 0, stream>>>(x, att, m6b, h);
    k_gemm<1><<<dim3(32, 32), 256, 0, stream>>>(h, W1 + (size_t)l * 4096 * 1024, nullptr, nullptr,
                                                b1 + l * 4096, 1024, 4096,
                                                f1, nullptr, nullptr, nullptr, nullptr);
    k_gemm<2><<<dim3(8, 32), 256, 0, stream>>>(f1, W2 + (size_t)l * 1024 * 4096, nullptr, nullptr,
                                               b2 + l * 1024, 4096, 1024,
                                               nullptr, nullptr, x, m6b + 5120, xmask);
  }

  k_lnmod<<<4096, 256, 0, stream>>>(x, m2v + 0, m2v + 1024, 2048, xmask, h, 0);
  k_gemm<3><<<dim3(8, 32), 256, 0, stream>>>(h, Wf, nullptr, nullptr, bfp, 1024, 1024,
                                             nullptr, (float*)d_out, nullptr, nullptr, xmask);
}

// Round 2
// 2920.212 us; speedup vs baseline: 1.9377x; 1.9377x over previous
//
#include <hip/hip_runtime.h>
#include <hip/hip_bf16.h>
#include <cstddef>

#define DEVI __device__ __forceinline__

typedef __attribute__((ext_vector_type(4))) float f4v;
typedef __attribute__((ext_vector_type(8))) short s8v;
typedef __attribute__((ext_vector_type(4))) short s4v;

using bf16 = __hip_bfloat16;

// L=8, B=8, N=512, C=1024, H=16, D=64
constexpr float SELU_A = 1.6732632423543772f;
constexpr float SELU_S = 1.0507009873554805f;
constexpr float TPINV  = 0.08838834764831845f; // 1/sqrt(2*D) = 1/sqrt(128)

DEVI float bfbits(short s) { return __uint_as_float(((unsigned)(unsigned short)s) << 16); }
DEVI unsigned short f2bu(float f) {
  bf16 h = __float2bfloat16(f);
  return __builtin_bit_cast(unsigned short, h);
}
DEVI float seluf(float x) { return x > 0.f ? SELU_S * x : SELU_S * SELU_A * (__expf(x) - 1.f); }

// ---------------- conditioning: cs[b][j] = selu(label.Wl[j] + bl[j] + te(b,j))
__global__ void k_cond(const float* __restrict__ tim, const float* __restrict__ lab,
                       const float* __restrict__ Wl, const float* __restrict__ bl,
                       float* __restrict__ cs)
{
  int b = blockIdx.x, t = threadIdx.x;
  float l0 = lab[b * 2 + 0], l1 = lab[b * 2 + 1], tv = tim[b];
  #pragma unroll
  for (int i = 0; i < 4; i++) {
    int j = t + 256 * i;
    float e = powf(10000.f, (2.f * (float)j) * (1.f / 1024.f));
    float arg = tv / e;
    float te = ((j & 1) == 0) ? sinf(arg) : cosf(arg);
    float c = l0 * Wl[j * 2 + 0] + l1 * Wl[j * 2 + 1] + bl[j] + te;
    cs[b * 1024 + j] = seluf(c);
  }
}

// ---------------- small matvec batch: out = cs(8x1024) @ W(O x 1024)^T + bias
__global__ __launch_bounds__(256) void k_small(
    const float* __restrict__ cs, const float* __restrict__ W, const float* __restrict__ bias,
    float* __restrict__ out, int O, int mode)
{
  __shared__ float cls[8192];
  int t = threadIdx.x;
  #pragma unroll
  for (int i = 0; i < 8; i++)
    *(f4v*)&cls[i * 1024 + t * 4] = *(const f4v*)&cs[i * 1024 + t * 4];
  __syncthreads();
  int w = t >> 6, l = t & 63;
  int o = blockIdx.x * 4 + w;
  if (o >= O) return;
  float acc[8] = {0.f, 0.f, 0.f, 0.f, 0.f, 0.f, 0.f, 0.f};
  const float* Wr = W + (size_t)o * 1024;
  for (int i = 0; i < 16; i++) {
    int k = i * 64 + l;
    float wv = Wr[k];
    #pragma unroll
    for (int b = 0; b < 8; b++) acc[b] += wv * cls[b * 1024 + k];
  }
  #pragma unroll
  for (int b = 0; b < 8; b++) {
    #pragma unroll
    for (int off = 32; off; off >>= 1) acc[b] += __shfl_xor(acc[b], off);
  }
  float bv = bias[o];
  #pragma unroll
  for (int b = 0; b < 8; b++) {
    if (l == b) {
      float val = acc[b] + bv;
      size_t dst;
      if (mode == 0) { int ll = o / 6144, ft = o - ll * 6144; dst = ((size_t)ll * 8 + b) * 6144 + ft; }
      else dst = (size_t)b * 2048 + o;
      out[dst] = val;
    }
  }
}

// ---------------- row LN + modulate (+optional mask) -> bf16
__global__ __launch_bounds__(256) void k_lnmod(
    const float* __restrict__ x, const float* __restrict__ shiftB, const float* __restrict__ scaleB,
    int bstride, const float* __restrict__ xm, bf16* __restrict__ out, int domask)
{
  int row = blockIdx.x, t = threadIdx.x, b = row >> 9;
  const float* xr = x + (size_t)row * 1024;
  f4v v = *(const f4v*)&xr[t * 4];
  float s = v[0] + v[1] + v[2] + v[3];
  float ss = v[0]*v[0] + v[1]*v[1] + v[2]*v[2] + v[3]*v[3];
  #pragma unroll
  for (int off = 32; off; off >>= 1) { s += __shfl_xor(s, off); ss += __shfl_xor(ss, off); }
  __shared__ float rs[4], rss[4];
  int w = t >> 6;
  if ((t & 63) == 0) { rs[w] = s; rss[w] = ss; }
  __syncthreads();
  s = rs[0] + rs[1] + rs[2] + rs[3];
  ss = rss[0] + rss[1] + rss[2] + rss[3];
  float mean = s * (1.f / 1024.f);
  float var = ss * (1.f / 1024.f) - mean * mean;
  float rstd = rsqrtf(var + 1e-6f);
  float mk = domask ? xm[row] : 1.f;
  f4v sh = *(const f4v*)&shiftB[(size_t)b * bstride + t * 4];
  f4v sc = *(const f4v*)&scaleB[(size_t)b * bstride + t * 4];
  s4v o;
  #pragma unroll
  for (int i = 0; i < 4; i++) {
    float hv = ((v[i] - mean) * rstd * (1.f + sc[i]) + sh[i]) * mk;
    o[i] = (short)f2bu(hv);
  }
  *(s4v*)&out[(size_t)row * 1024 + t * 4] = o;
}

// ---------------- x += gm*att; write x; h2 = modulate(ln(x), sf, cf) -> bf16
__global__ __launch_bounds__(256) void k_resid(
    float* __restrict__ x, const bf16* __restrict__ att, const float* __restrict__ m6b,
    bf16* __restrict__ h2)
{
  int row = blockIdx.x, t = threadIdx.x, b = row >> 9;
  float* xr = x + (size_t)row * 1024;
  const float* gm = m6b + (size_t)b * 6144 + 2048;
  const float* sf = m6b + (size_t)b * 6144 + 3072;
  const float* cf = m6b + (size_t)b * 6144 + 4096;
  f4v xv = *(const f4v*)&xr[t * 4];
  s4v av = *(const s4v*)&att[(size_t)row * 1024 + t * 4];
  f4v gv = *(const f4v*)&gm[t * 4];
  f4v vv;
  #pragma unroll
  for (int i = 0; i < 4; i++) vv[i] = xv[i] + gv[i] * bfbits(av[i]);
  *(f4v*)&xr[t * 4] = vv;
  float s = vv[0] + vv[1] + vv[2] + vv[3];
  float ss = vv[0]*vv[0] + vv[1]*vv[1] + vv[2]*vv[2] + vv[3]*vv[3];
  #pragma unroll
  for (int off = 32; off; off >>= 1) { s += __shfl_xor(s, off); ss += __shfl_xor(ss, off); }
  __shared__ float rs[4], rss[4];
  int w = t >> 6;
  if ((t & 63) == 0) { rs[w] = s; rss[w] = ss; }
  __syncthreads();
  s = rs[0] + rs[1] + rs[2] + rs[3];
  ss = rss[0] + rss[1] + rss[2] + rss[3];
  float mean = s * (1.f / 1024.f);
  float var = ss * (1.f / 1024.f) - mean * mean;
  float rstd = rsqrtf(var + 1e-6f);
  f4v sfv = *(const f4v*)&sf[t * 4];
  f4v cfv = *(const f4v*)&cf[t * 4];
  s4v o;
  #pragma unroll
  for (int i = 0; i < 4; i++)
    o[i] = (short)f2bu((vv[i] - mean) * rstd * (1.f + cfv[i]) + sfv[i]);
  *(s4v*)&h2[(size_t)row * 1024 + t * 4] = o;
}

// ---------------- MFMA flash attention
// q,k: (B,H,N,64) bf16 row-major; vt: (B,H,64,N) bf16 (V transposed).
// Block: one (b,h), 128 q-rows; 4 waves x 32 q-rows. K-tiles of 64.
__global__ __launch_bounds__(256) void k_attn(
    const bf16* __restrict__ q, const bf16* __restrict__ k, const bf16* __restrict__ vt,
    const float* __restrict__ xm, bf16* __restrict__ att)
{
  int bh = blockIdx.y, b = bh >> 4, hh = bh & 15;
  int t = threadIdx.x, w = t >> 6, lane = t & 63;
  int fr = lane & 15, g = lane >> 4;
  int qw = blockIdx.x * 128 + w * 32;
  const size_t ho = (size_t)bh * (512 * 64);

  __shared__ float xkl[512];
  __shared__ bf16 Pb[4][32][72];

  for (int i = t; i < 512; i += 256) xkl[i] = xm[b * 512 + i];
  __syncthreads();

  // Q fragments: A[m=q-row][k=d]
  s8v qf[2][2];
  #pragma unroll
  for (int mf = 0; mf < 2; mf++)
    #pragma unroll
    for (int kk = 0; kk < 2; kk++)
      qf[mf][kk] = *(const s8v*)(q + ho + (size_t)(qw + mf * 16 + fr) * 64 + kk * 32 + g * 8);

  float xq[2][4];
  #pragma unroll
  for (int mf = 0; mf < 2; mf++)
    #pragma unroll
    for (int r = 0; r < 4; r++) xq[mf][r] = xkl[qw + mf * 16 + g * 4 + r];

  float mrow[2][4], lsum[2][4];
  f4v oacc[2][4];
  const f4v vzero = {0.f, 0.f, 0.f, 0.f};
  #pragma unroll
  for (int mf = 0; mf < 2; mf++)
    #pragma unroll
    for (int r = 0; r < 4; r++) { mrow[mf][r] = -3.0e38f; lsum[mf][r] = 0.f; }
  #pragma unroll
  for (int mf = 0; mf < 2; mf++)
    #pragma unroll
    for (int nd = 0; nd < 4; nd++) oacc[mf][nd] = vzero;

  for (int kt = 0; kt < 8; kt++) {
    int kb0 = kt * 64;
    // S = Q K^T
    f4v sacc[2][4];
    #pragma unroll
    for (int mf = 0; mf < 2; mf++)
      #pragma unroll
      for (int nf = 0; nf < 4; nf++) sacc[mf][nf] = vzero;
    #pragma unroll
    for (int kk = 0; kk < 2; kk++) {
      s8v kf[4];
      #pragma unroll
      for (int nf = 0; nf < 4; nf++)
        kf[nf] = *(const s8v*)(k + ho + (size_t)(kb0 + nf * 16 + fr) * 64 + kk * 32 + g * 8);
      #pragma unroll
      for (int mf = 0; mf < 2; mf++)
        #pragma unroll
        for (int nf = 0; nf < 4; nf++)
          sacc[mf][nf] = __builtin_amdgcn_mfma_f32_16x16x32_bf16(qf[mf][kk], kf[nf], sacc[mf][nf], 0, 0, 0);
    }
    // mask + scale + online softmax
    float xk[4];
    #pragma unroll
    for (int nf = 0; nf < 4; nf++) xk[nf] = xkl[kb0 + nf * 16 + fr];
    #pragma unroll
    for (int mf = 0; mf < 2; mf++) {
      #pragma unroll
      for (int r = 0; r < 4; r++) {
        float mx = -3.0e38f;
        #pragma unroll
        for (int nf = 0; nf < 4; nf++) {
          float s = sacc[mf][nf][r] * TPINV;
          if (xq[mf][r] + xk[nf] == 1.0f) s = -1.0e30f;
          sacc[mf][nf][r] = s;
          mx = fmaxf(mx, s);
        }
        mx = fmaxf(mx, __shfl_xor(mx, 1));
        mx = fmaxf(mx, __shfl_xor(mx, 2));
        mx = fmaxf(mx, __shfl_xor(mx, 4));
        mx = fmaxf(mx, __shfl_xor(mx, 8));
        float mnew = fmaxf(mrow[mf][r], mx);
        float corr = __expf(mrow[mf][r] - mnew);
        mrow[mf][r] = mnew;
        float ps = 0.f;
        #pragma unroll
        for (int nf = 0; nf < 4; nf++) {
          float p = __expf(sacc[mf][nf][r] - mnew);
          ps += p;
          Pb[w][mf * 16 + g * 4 + r][nf * 16 + fr] = __float2bfloat16(p);
        }
        lsum[mf][r] = lsum[mf][r] * corr + ps;
        #pragma unroll
        for (int nd = 0; nd < 4; nd++) oacc[mf][nd][r] *= corr;
      }
    }
    // O += P V   (A = P[m=q][k=key] from LDS, B = V^T[n=d][k=key] from global)
    #pragma unroll
    for (int kk = 0; kk < 2; kk++) {
      s8v pf[2], vf[4];
      #pragma unroll
      for (int mf = 0; mf < 2; mf++)
        pf[mf] = *(const s8v*)&Pb[w][mf * 16 + fr][kk * 32 + g * 8];
      #pragma unroll
      for (int nd = 0; nd < 4; nd++)
        vf[nd] = *(const s8v*)(vt + ho + (size_t)(nd * 16 + fr) * 512 + kb0 + kk * 32 + g * 8);
      #pragma unroll
      for (int mf = 0; mf < 2; mf++)
        #pragma unroll
        for (int nd = 0; nd < 4; nd++)
          oacc[mf][nd] = __builtin_amdgcn_mfma_f32_16x16x32_bf16(pf[mf], vf[nd], oacc[mf][nd], 0, 0, 0);
    }
  }
  // finalize: reduce lsum across the 16-lane row group, divide, store
  float inv[2][4];
  #pragma unroll
  for (int mf = 0; mf < 2; mf++)
    #pragma unroll
    for (int r = 0; r < 4; r++) {
      float ls = lsum[mf][r];
      ls += __shfl_xor(ls, 1);
      ls += __shfl_xor(ls, 2);
      ls += __shfl_xor(ls, 4);
      ls += __shfl_xor(ls, 8);
      inv[mf][r] = 1.f / ls;
    }
  #pragma unroll
  for (int mf = 0; mf < 2; mf++)
    #pragma unroll
    for (int nd = 0; nd < 4; nd++)
      #pragma unroll
      for (int r = 0; r < 4; r++) {
        int row = qw + mf * 16 + g * 4 + r;
        att[(size_t)(b * 512 + row) * 1024 + hh * 64 + nd * 16 + fr] =
            __float2bfloat16(oacc[mf][nd][r] * inv[mf][r]);
      }
}

// ---------------- GEMM: out[m][n] = epi( sum_k A[m][k]*W[n][k] + bias[n] )
// A bf16 (MxK), W fp32 (NxK). EPI: 0=QKV store (Q,K:(B,H,N,D); V:(B,H,D,N) transposed),
// 1=selu+bias->bf16, 2=residual+gate+mask (x in/out f32), 3=bias+mask->f32
template <int EPI>
__global__ __launch_bounds__(256) void k_gemm(
    const bf16* __restrict__ A, const float* __restrict__ W,
    const float* __restrict__ Wb2, const float* __restrict__ Wb3,
    const float* __restrict__ bias, int K, int Ncols,
    bf16* __restrict__ outb, float* __restrict__ outf,
    float* __restrict__ xio, const float* __restrict__ gfb,
    const float* __restrict__ xmk)
{
  __shared__ bf16 As[128][40];
  __shared__ bf16 Ws[128][40];
  int t = threadIdx.x, lane = t & 63, w = t >> 6;
  int wr = w >> 1, wc = w & 1;
  int m0 = blockIdx.y * 128, n0 = blockIdx.x * 128;

  const float* Wuse = W;
  int nloc = n0;
  if (EPI == 0) {
    int sel = n0 >> 10;
    Wuse = (sel == 0) ? W : ((sel == 1) ? Wb2 : Wb3);
    nloc = n0 & 1023;
  }

  int arow = t >> 1, ac0 = (t & 1) * 16;
  const bf16* aptr = A + (size_t)(m0 + arow) * K + ac0;
  const float* wptr = Wuse + (size_t)(nloc + arow) * K + ac0;

  const f4v vzero = {0.f, 0.f, 0.f, 0.f};
  f4v acc[4][4];
  #pragma unroll
  for (int i = 0; i < 4; i++)
    #pragma unroll
    for (int j = 0; j < 4; j++) acc[i][j] = vzero;

  int fr = lane & 15, kq = (lane >> 4) * 8;
  int nkt = K >> 5;
  for (int kt = 0; kt < nkt; kt++) {
    __syncthreads();
    s8v a0 = *(const s8v*)(aptr);
    s8v a1 = *(const s8v*)(aptr + 8);
    f4v w0 = *(const f4v*)(wptr);
    f4v w1 = *(const f4v*)(wptr + 4);
    f4v w2 = *(const f4v*)(wptr + 8);
    f4v w3 = *(const f4v*)(wptr + 12);
    *(s8v*)&As[arow][ac0] = a0;
    *(s8v*)&As[arow][ac0 + 8] = a1;
    s4v wb;
    wb[0] = (short)f2bu(w0[0]); wb[1] = (short)f2bu(w0[1]); wb[2] = (short)f2bu(w0[2]); wb[3] = (short)f2bu(w0[3]);
    *(s4v*)&Ws[arow][ac0 + 0] = wb;
    wb[0] = (short)f2bu(w1[0]); wb[1] = (short)f2bu(w1[1]); wb[2] = (short)f2bu(w1[2]); wb[3] = (short)f2bu(w1[3]);
    *(s4v*)&Ws[arow][ac0 + 4] = wb;
    wb[0] = (short)f2bu(w2[0]); wb[1] = (short)f2bu(w2[1]); wb[2] = (short)f2bu(w2[2]); wb[3] = (short)f2bu(w2[3]);
    *(s4v*)&Ws[arow][ac0 + 8] = wb;
    wb[0] = (short)f2bu(w3[0]); wb[1] = (short)f2bu(w3[1]); wb[2] = (short)f2bu(w3[2]); wb[3] = (short)f2bu(w3[3]);
    *(s4v*)&Ws[arow][ac0 + 12] = wb;
    __syncthreads();
    s8v af[4], bfr[4];
    #pragma unroll
    for (int mf = 0; mf < 4; mf++) af[mf] = *(const s8v*)&As[wr * 64 + mf * 16 + fr][kq];
    #pragma unroll
    for (int nf = 0; nf < 4; nf++) bfr[nf] = *(const s8v*)&Ws[wc * 64 + nf * 16 + fr][kq];
    #pragma unroll
    for (int mf = 0; mf < 4; mf++)
      #pragma unroll
      for (int nf = 0; nf < 4; nf++)
        acc[mf][nf] = __builtin_amdgcn_mfma_f32_16x16x32_bf16(af[mf], bfr[nf], acc[mf][nf], 0, 0, 0);
    aptr += 32;
    wptr += 32;
  }

  int rq = (lane >> 4) * 4;
  #pragma unroll
  for (int mf = 0; mf < 4; mf++) {
    #pragma unroll
    for (int nf = 0; nf < 4; nf++) {
      int row0 = m0 + wr * 64 + mf * 16 + rq;
      int col = n0 + wc * 64 + nf * 16 + fr;
      if (EPI == 0) {
        int sel = col >> 10, cl = col & 1023;
        int bb = row0 >> 9, nn = row0 & 511;
        int h2 = cl >> 6, dd = cl & 63;
        if (sel == 2) {
          s4v o4;
          #pragma unroll
          for (int r = 0; r < 4; r++) o4[r] = (short)f2bu(acc[mf][nf][r]);
          *(s4v*)&outb[(size_t)2 * 4194304 + (((size_t)bb * 16 + h2) * 64 + dd) * 512 + nn] = o4;
        } else {
          #pragma unroll
          for (int r = 0; r < 4; r++)
            outb[(size_t)sel * 4194304 + (((size_t)bb * 16 + h2) * 512 + (nn + r)) * 64 + dd] =
                __float2bfloat16(acc[mf][nf][r]);
        }
      } else {
        #pragma unroll
        for (int r = 0; r < 4; r++) {
          int row = row0 + r;
          float val = acc[mf][nf][r];
          if (EPI == 1) {
            outb[(size_t)row * Ncols + col] = __float2bfloat16(seluf(val + bias[col]));
          } else if (EPI == 2) {
            int bb = row >> 9;
            size_t idx = (size_t)row * 1024 + col;
            float nx = (xio[idx] + gfb[(size_t)bb * 6144 + col] * (val + bias[col])) * xmk[row];
            xio[idx] = nx;
          } else {
            outf[(size_t)row * 1024 + col] = (val + bias[col]) * xmk[row];
          }
        }
      }
    }
  }
}

extern "C" void kernel_launch(void* const* d_in, const int* in_sizes, int n_in,
                              void* d_out, int out_size, void* d_ws, size_t ws_size,
                              hipStream_t stream)
{
  const float* x_in  = (const float*)d_in[0];
  const float* tim   = (const float*)d_in[1];
  const float* lab   = (const float*)d_in[2];
  const float* xmask = (const float*)d_in[3];
  const float* Wl  = (const float*)d_in[4];
  const float* bl  = (const float*)d_in[5];
  const float* Wq  = (const float*)d_in[6];
  const float* Wk  = (const float*)d_in[7];
  const float* Wv  = (const float*)d_in[8];
  const float* W1  = (const float*)d_in[9];
  const float* b1  = (const float*)d_in[10];
  const float* W2  = (const float*)d_in[11];
  const float* b2  = (const float*)d_in[12];
  const float* Wm  = (const float*)d_in[13];
  const float* bm  = (const float*)d_in[14];
  const float* Wf  = (const float*)d_in[15];
  const float* bfp = (const float*)d_in[16];
  const float* Wmf = (const float*)d_in[17];
  const float* bmf = (const float*)d_in[18];

  char* ws = (char*)d_ws;
  float* x    = (float*)(ws + 0);         // 16777216 B
  float* cs   = (float*)(ws + 16777216);  // 32768 B
  float* mAll = (float*)(ws + 16809984);  // 1572864 B  [L][B][6144]
  float* m2v  = (float*)(ws + 18382848);  // 65536 B    [B][2048]
  bf16*  h    = (bf16*)(ws + 18448384);   // 8388608 B
  bf16*  qb   = (bf16*)(ws + 26836992);   // 8388608 B  (B,H,N,D)
  bf16*  kb   = (bf16*)(ws + 35225600);   // 8388608 B  (B,H,N,D)
  bf16*  vb   = (bf16*)(ws + 43614208);   // 8388608 B  (B,H,D,N)  V transposed
  bf16*  att  = (bf16*)(ws + 52002816);   // 8388608 B  (B,N,C)
  bf16*  f1   = (bf16*)(ws + 60391424);   // 33554432 B (4096 x 4096)

  hipMemcpyAsync(x, x_in, (size_t)4096 * 1024 * 4, hipMemcpyDeviceToDevice, stream);

  k_cond<<<8, 256, 0, stream>>>(tim, lab, Wl, bl, cs);
  k_small<<<12288, 256, 0, stream>>>(cs, Wm, bm, mAll, 49152, 0);
  k_small<<<512, 256, 0, stream>>>(cs, Wmf, bmf, m2v, 2048, 1);

  for (int l = 0; l < 8; l++) {
    const float* m6b = mAll + (size_t)l * 8 * 6144;
    const float* wq = Wq + (size_t)l * 1024 * 1024;
    const float* wk = Wk + (size_t)l * 1024 * 1024;
    const float* wv = Wv + (size_t)l * 1024 * 1024;

    k_lnmod<<<4096, 256, 0, stream>>>(x, m6b + 0, m6b + 1024, 6144, xmask, h, 1);
    k_gemm<0><<<dim3(24, 32), 256, 0, stream>>>(h, wq, wk, wv, nullptr, 1024, 1024,
                                                qb, nullptr, nullptr, nullptr, nullptr);
    k_attn<<<dim3(4, 128), 256, 0, stream>>>(qb, kb, vb, xmask, att);
    k_resid<<<4096, 256, 0, stream>>>(x, att, m6b, h);
    k_gemm<1><<<dim3(32, 32), 256, 0, stream>>>(h, W1 + (size_t)l * 4096 * 1024, nullptr, nullptr,
                                                b1 + l * 4096, 1024, 4096,
                                                f1, nullptr, nullptr, nullptr, nullptr);
    k_gemm<2><<<dim3(8, 32), 256, 0, stream>>>(f1, W2 + (size_t)l * 1024 * 4096, nullptr, nullptr,
                                               b2 + l * 1024, 4096, 1024,
                                               nullptr, nullptr, x, m6b + 5120, xmask);
  }

  k_lnmod<<<4096, 256, 0, stream>>>(x, m2v + 0, m2v + 1024, 2048, xmask, h, 0);
  k_gemm<3><<<dim3(8, 32), 256, 0, stream>>>(h, Wf, nullptr, nullptr, bfp, 1024, 1024,
                                             nullptr, (float*)d_out, nullptr, nullptr, xmask);
}

// Round 3
// 2171.338 us; speedup vs baseline: 2.6061x; 1.3449x over previous
//
#include <hip/hip_runtime.h>
#include <hip/hip_bf16.h>
#include <cstddef>

#define DEVI __device__ __forceinline__

typedef __attribute__((ext_vector_type(4))) float f4v;
typedef __attribute__((ext_vector_type(8))) short s8v;
typedef __attribute__((ext_vector_type(4))) short s4v;

using bf16 = __hip_bfloat16;

// L=8, B=8, N=512, C=1024, H=16, D=64
constexpr float SELU_A = 1.6732632423543772f;
constexpr float SELU_S = 1.0507009873554805f;
constexpr float TPINV  = 0.08838834764831845f; // 1/sqrt(2*D)

DEVI float bfbits(short s) { return __uint_as_float(((unsigned)(unsigned short)s) << 16); }
DEVI unsigned short f2bu(float f) {
  bf16 h = __float2bfloat16(f);
  return __builtin_bit_cast(unsigned short, h);
}
DEVI float seluf(float x) { return x > 0.f ? SELU_S * x : SELU_S * SELU_A * (__expf(x) - 1.f); }

DEVI void gl16(const void* g, void* l) {
  __builtin_amdgcn_global_load_lds((__attribute__((address_space(1))) void*)g,
                                   (__attribute__((address_space(3))) void*)l, 16, 0, 0);
}

// ---------------- fp32 -> bf16 convert (8 elems/thread)
__global__ __launch_bounds__(256) void k_conv(const float* __restrict__ src,
                                              bf16* __restrict__ dst, int n8)
{
  int i = blockIdx.x * 256 + threadIdx.x;
  if (i >= n8) return;
  const float* s = src + (size_t)i * 8;
  f4v a = *(const f4v*)s;
  f4v b = *(const f4v*)(s + 4);
  s8v o;
  #pragma unroll
  for (int j = 0; j < 4; j++) { o[j] = (short)f2bu(a[j]); o[4 + j] = (short)f2bu(b[j]); }
  *(s8v*)(dst + (size_t)i * 8) = o;
}

// ---------------- pack Wq/Wk/Wv (layer slice) -> [3072][1024] bf16
__global__ __launch_bounds__(256) void k_convqkv(const float* __restrict__ wq,
                                                 const float* __restrict__ wk,
                                                 const float* __restrict__ wv,
                                                 bf16* __restrict__ dst)
{
  int i = blockIdx.x * 256 + threadIdx.x; // < 393216
  int o = i * 8;
  int row = o >> 10, col = o & 1023;
  int sel = row >> 10, sr = row & 1023;
  const float* src = (sel == 0 ? wq : sel == 1 ? wk : wv) + (size_t)sr * 1024 + col;
  f4v a = *(const f4v*)src;
  f4v b = *(const f4v*)(src + 4);
  s8v out;
  #pragma unroll
  for (int j = 0; j < 4; j++) { out[j] = (short)f2bu(a[j]); out[4 + j] = (short)f2bu(b[j]); }
  *(s8v*)(dst + o) = out;
}

// ---------------- conditioning
__global__ void k_cond(const float* __restrict__ tim, const float* __restrict__ lab,
                       const float* __restrict__ Wl, const float* __restrict__ bl,
                       float* __restrict__ cs)
{
  int b = blockIdx.x, t = threadIdx.x;
  float l0 = lab[b * 2 + 0], l1 = lab[b * 2 + 1], tv = tim[b];
  #pragma unroll
  for (int i = 0; i < 4; i++) {
    int j = t + 256 * i;
    float e = powf(10000.f, (2.f * (float)j) * (1.f / 1024.f));
    float arg = tv / e;
    float te = ((j & 1) == 0) ? sinf(arg) : cosf(arg);
    float c = l0 * Wl[j * 2 + 0] + l1 * Wl[j * 2 + 1] + bl[j] + te;
    cs[b * 1024 + j] = seluf(c);
  }
}

// ---------------- small matvec batch: out = cs(8x1024) @ W(O x 1024)^T + bias
__global__ __launch_bounds__(256) void k_small(
    const float* __restrict__ cs, const float* __restrict__ W, const float* __restrict__ bias,
    float* __restrict__ out, int O, int mode)
{
  __shared__ float cls[8192];
  int t = threadIdx.x;
  #pragma unroll
  for (int i = 0; i < 8; i++)
    *(f4v*)&cls[i * 1024 + t * 4] = *(const f4v*)&cs[i * 1024 + t * 4];
  __syncthreads();
  int w = t >> 6, l = t & 63;
  int o = blockIdx.x * 4 + w;
  if (o >= O) return;
  float acc[8] = {0.f, 0.f, 0.f, 0.f, 0.f, 0.f, 0.f, 0.f};
  const float* Wr = W + (size_t)o * 1024;
  for (int i = 0; i < 16; i++) {
    int k = i * 64 + l;
    float wv = Wr[k];
    #pragma unroll
    for (int b = 0; b < 8; b++) acc[b] += wv * cls[b * 1024 + k];
  }
  #pragma unroll
  for (int b = 0; b < 8; b++) {
    #pragma unroll
    for (int off = 32; off; off >>= 1) acc[b] += __shfl_xor(acc[b], off);
  }
  float bv = bias[o];
  #pragma unroll
  for (int b = 0; b < 8; b++) {
    if (l == b) {
      float val = acc[b] + bv;
      size_t dst;
      if (mode == 0) { int ll = o / 6144, ft = o - ll * 6144; dst = ((size_t)ll * 8 + b) * 6144 + ft; }
      else dst = (size_t)b * 2048 + o;
      out[dst] = val;
    }
  }
}

// ---------------- row LN + modulate (+optional mask) -> bf16
__global__ __launch_bounds__(256) void k_lnmod(
    const float* __restrict__ x, const float* __restrict__ shiftB, const float* __restrict__ scaleB,
    int bstride, const float* __restrict__ xm, bf16* __restrict__ out, int domask)
{
  int row = blockIdx.x, t = threadIdx.x, b = row >> 9;
  const float* xr = x + (size_t)row * 1024;
  f4v v = *(const f4v*)&xr[t * 4];
  float s = v[0] + v[1] + v[2] + v[3];
  float ss = v[0]*v[0] + v[1]*v[1] + v[2]*v[2] + v[3]*v[3];
  #pragma unroll
  for (int off = 32; off; off >>= 1) { s += __shfl_xor(s, off); ss += __shfl_xor(ss, off); }
  __shared__ float rs[4], rss[4];
  int w = t >> 6;
  if ((t & 63) == 0) { rs[w] = s; rss[w] = ss; }
  __syncthreads();
  s = rs[0] + rs[1] + rs[2] + rs[3];
  ss = rss[0] + rss[1] + rss[2] + rss[3];
  float mean = s * (1.f / 1024.f);
  float var = ss * (1.f / 1024.f) - mean * mean;
  float rstd = rsqrtf(var + 1e-6f);
  float mk = domask ? xm[row] : 1.f;
  f4v sh = *(const f4v*)&shiftB[(size_t)b * bstride + t * 4];
  f4v sc = *(const f4v*)&scaleB[(size_t)b * bstride + t * 4];
  s4v o;
  #pragma unroll
  for (int i = 0; i < 4; i++) {
    float hv = ((v[i] - mean) * rstd * (1.f + sc[i]) + sh[i]) * mk;
    o[i] = (short)f2bu(hv);
  }
  *(s4v*)&out[(size_t)row * 1024 + t * 4] = o;
}

// ---------------- x += gm*att; write x; h2 = modulate(ln(x), sf, cf) -> bf16
__global__ __launch_bounds__(256) void k_resid(
    float* __restrict__ x, const bf16* __restrict__ att, const float* __restrict__ m6b,
    bf16* __restrict__ h2)
{
  int row = blockIdx.x, t = threadIdx.x, b = row >> 9;
  float* xr = x + (size_t)row * 1024;
  const float* gm = m6b + (size_t)b * 6144 + 2048;
  const float* sf = m6b + (size_t)b * 6144 + 3072;
  const float* cf = m6b + (size_t)b * 6144 + 4096;
  f4v xv = *(const f4v*)&xr[t * 4];
  s4v av = *(const s4v*)&att[(size_t)row * 1024 + t * 4];
  f4v gv = *(const f4v*)&gm[t * 4];
  f4v vv;
  #pragma unroll
  for (int i = 0; i < 4; i++) vv[i] = xv[i] + gv[i] * bfbits(av[i]);
  *(f4v*)&xr[t * 4] = vv;
  float s = vv[0] + vv[1] + vv[2] + vv[3];
  float ss = vv[0]*vv[0] + vv[1]*vv[1] + vv[2]*vv[2] + vv[3]*vv[3];
  #pragma unroll
  for (int off = 32; off; off >>= 1) { s += __shfl_xor(s, off); ss += __shfl_xor(ss, off); }
  __shared__ float rs[4], rss[4];
  int w = t >> 6;
  if ((t & 63) == 0) { rs[w] = s; rss[w] = ss; }
  __syncthreads();
  s = rs[0] + rs[1] + rs[2] + rs[3];
  ss = rss[0] + rss[1] + rss[2] + rss[3];
  float mean = s * (1.f / 1024.f);
  float var = ss * (1.f / 1024.f) - mean * mean;
  float rstd = rsqrtf(var + 1e-6f);
  f4v sfv = *(const f4v*)&sf[t * 4];
  f4v cfv = *(const f4v*)&cf[t * 4];
  s4v o;
  #pragma unroll
  for (int i = 0; i < 4; i++)
    o[i] = (short)f2bu((vv[i] - mean) * rstd * (1.f + cfv[i]) + sfv[i]);
  *(s4v*)&h2[(size_t)row * 1024 + t * 4] = o;
}

// ---------------- MFMA flash attention (unchanged from R2)
__global__ __launch_bounds__(256) void k_attn(
    const bf16* __restrict__ q, const bf16* __restrict__ k, const bf16* __restrict__ vt,
    const float* __restrict__ xm, bf16* __restrict__ att)
{
  int bh = blockIdx.y, b = bh >> 4, hh = bh & 15;
  int t = threadIdx.x, w = t >> 6, lane = t & 63;
  int fr = lane & 15, g = lane >> 4;
  int qw = blockIdx.x * 128 + w * 32;
  const size_t ho = (size_t)bh * (512 * 64);

  __shared__ float xkl[512];
  __shared__ bf16 Pb[4][32][72];

  for (int i = t; i < 512; i += 256) xkl[i] = xm[b * 512 + i];
  __syncthreads();

  s8v qf[2][2];
  #pragma unroll
  for (int mf = 0; mf < 2; mf++)
    #pragma unroll
    for (int kk = 0; kk < 2; kk++)
      qf[mf][kk] = *(const s8v*)(q + ho + (size_t)(qw + mf * 16 + fr) * 64 + kk * 32 + g * 8);

  float xq[2][4];
  #pragma unroll
  for (int mf = 0; mf < 2; mf++)
    #pragma unroll
    for (int r = 0; r < 4; r++) xq[mf][r] = xkl[qw + mf * 16 + g * 4 + r];

  float mrow[2][4], lsum[2][4];
  f4v oacc[2][4];
  const f4v vzero = {0.f, 0.f, 0.f, 0.f};
  #pragma unroll
  for (int mf = 0; mf < 2; mf++)
    #pragma unroll
    for (int r = 0; r < 4; r++) { mrow[mf][r] = -3.0e38f; lsum[mf][r] = 0.f; }
  #pragma unroll
  for (int mf = 0; mf < 2; mf++)
    #pragma unroll
    for (int nd = 0; nd < 4; nd++) oacc[mf][nd] = vzero;

  for (int kt = 0; kt < 8; kt++) {
    int kb0 = kt * 64;
    f4v sacc[2][4];
    #pragma unroll
    for (int mf = 0; mf < 2; mf++)
      #pragma unroll
      for (int nf = 0; nf < 4; nf++) sacc[mf][nf] = vzero;
    #pragma unroll
    for (int kk = 0; kk < 2; kk++) {
      s8v kf[4];
      #pragma unroll
      for (int nf = 0; nf < 4; nf++)
        kf[nf] = *(const s8v*)(k + ho + (size_t)(kb0 + nf * 16 + fr) * 64 + kk * 32 + g * 8);
      #pragma unroll
      for (int mf = 0; mf < 2; mf++)
        #pragma unroll
        for (int nf = 0; nf < 4; nf++)
          sacc[mf][nf] = __builtin_amdgcn_mfma_f32_16x16x32_bf16(qf[mf][kk], kf[nf], sacc[mf][nf], 0, 0, 0);
    }
    float xk[4];
    #pragma unroll
    for (int nf = 0; nf < 4; nf++) xk[nf] = xkl[kb0 + nf * 16 + fr];
    #pragma unroll
    for (int mf = 0; mf < 2; mf++) {
      #pragma unroll
      for (int r = 0; r < 4; r++) {
        float mx = -3.0e38f;
        #pragma unroll
        for (int nf = 0; nf < 4; nf++) {
          float s = sacc[mf][nf][r] * TPINV;
          if (xq[mf][r] + xk[nf] == 1.0f) s = -1.0e30f;
          sacc[mf][nf][r] = s;
          mx = fmaxf(mx, s);
        }
        mx = fmaxf(mx, __shfl_xor(mx, 1));
        mx = fmaxf(mx, __shfl_xor(mx, 2));
        mx = fmaxf(mx, __shfl_xor(mx, 4));
        mx = fmaxf(mx, __shfl_xor(mx, 8));
        float mnew = fmaxf(mrow[mf][r], mx);
        float corr = __expf(mrow[mf][r] - mnew);
        mrow[mf][r] = mnew;
        float ps = 0.f;
        #pragma unroll
        for (int nf = 0; nf < 4; nf++) {
          float p = __expf(sacc[mf][nf][r] - mnew);
          ps += p;
          Pb[w][mf * 16 + g * 4 + r][nf * 16 + fr] = __float2bfloat16(p);
        }
        lsum[mf][r] = lsum[mf][r] * corr + ps;
        #pragma unroll
        for (int nd = 0; nd < 4; nd++) oacc[mf][nd][r] *= corr;
      }
    }
    #pragma unroll
    for (int kk = 0; kk < 2; kk++) {
      s8v pf[2], vf[4];
      #pragma unroll
      for (int mf = 0; mf < 2; mf++)
        pf[mf] = *(const s8v*)&Pb[w][mf * 16 + fr][kk * 32 + g * 8];
      #pragma unroll
      for (int nd = 0; nd < 4; nd++)
        vf[nd] = *(const s8v*)(vt + ho + (size_t)(nd * 16 + fr) * 512 + kb0 + kk * 32 + g * 8);
      #pragma unroll
      for (int mf = 0; mf < 2; mf++)
        #pragma unroll
        for (int nd = 0; nd < 4; nd++)
          oacc[mf][nd] = __builtin_amdgcn_mfma_f32_16x16x32_bf16(pf[mf], vf[nd], oacc[mf][nd], 0, 0, 0);
    }
  }
  float inv[2][4];
  #pragma unroll
  for (int mf = 0; mf < 2; mf++)
    #pragma unroll
    for (int r = 0; r < 4; r++) {
      float ls = lsum[mf][r];
      ls += __shfl_xor(ls, 1);
      ls += __shfl_xor(ls, 2);
      ls += __shfl_xor(ls, 4);
      ls += __shfl_xor(ls, 8);
      inv[mf][r] = 1.f / ls;
    }
  #pragma unroll
  for (int mf = 0; mf < 2; mf++)
    #pragma unroll
    for (int nd = 0; nd < 4; nd++)
      #pragma unroll
      for (int r = 0; r < 4; r++) {
        int row = qw + mf * 16 + g * 4 + r;
        att[(size_t)(b * 512 + row) * 1024 + hh * 64 + nd * 16 + fr] =
            __float2bfloat16(oacc[mf][nd][r] * inv[mf][r]);
      }
}

// ---------------- m97-structure GEMM: C[m][n] = epi( sum_k A[m][k]*W[n][k] )
// A bf16 (M x K), W bf16 (N x K), both row-major, K%64==0.
// BM=128 fixed, BK=64, BN in {64,128}. global_load_lds(16B) staging, single LDS buffer.
// EPI: 0=QKV store (Q,K:(B,H,N,D); V:(B,H,D,N)), 1=selu+bias->bf16,
//      2=residual+gate+mask (x f32 in/out), 3=bias+mask->f32
template <int EPI, int BN>
__global__ __launch_bounds__(256) void k_gemm(
    const bf16* __restrict__ A, const bf16* __restrict__ W,
    const float* __restrict__ bias, int K, int Ncols,
    bf16* __restrict__ outb, float* __restrict__ outf,
    float* __restrict__ xio, const float* __restrict__ gfb,
    const float* __restrict__ xmk)
{
  constexpr int FN = BN / 32;      // n-fragments per wave
  constexpr int NW = BN / 32;      // W staging insts per thread
  __shared__ bf16 As[128][64];
  __shared__ bf16 Ws[BN][64];
  int t = threadIdx.x, lane = t & 63, w = t >> 6;
  int wr = w >> 1, wc = w & 1;
  int m0 = blockIdx.y * 128, n0 = blockIdx.x * BN;
  int fr = lane & 15, g = lane >> 4;

  const bf16* Abase = A + (size_t)m0 * K;
  const bf16* Wbase = W + (size_t)n0 * K;

  const f4v vzero = {0.f, 0.f, 0.f, 0.f};
  f4v acc[4][FN];
  #pragma unroll
  for (int i = 0; i < 4; i++)
    #pragma unroll
    for (int j = 0; j < FN; j++) acc[i][j] = vzero;

  int nkt = K >> 6;
  for (int kt = 0; kt < nkt; kt++) {
    int k0 = kt << 6;
    __syncthreads();
    // stage A tile: 16 KB, 4 insts/thread; wave w owns bytes [w*4096, w*4096+4096)
    #pragma unroll
    for (int i = 0; i < 4; i++) {
      int off = w * 4096 + i * 1024 + lane * 16;
      int row = off >> 7, ce = (off & 127) >> 1;
      gl16(Abase + (size_t)row * K + k0 + ce, (char*)As + w * 4096 + i * 1024);
    }
    // stage W tile: BN*128 bytes, NW insts/thread
    #pragma unroll
    for (int i = 0; i < NW; i++) {
      int off = w * (NW * 1024) + i * 1024 + lane * 16;
      int row = off >> 7, ce = (off & 127) >> 1;
      gl16(Wbase + (size_t)row * K + k0 + ce, (char*)Ws + w * (NW * 1024) + i * 1024);
    }
    __syncthreads();
    #pragma unroll
    for (int kk = 0; kk < 2; kk++) {
      s8v af[4], bfr[FN];
      #pragma unroll
      for (int mf = 0; mf < 4; mf++)
        af[mf] = *(const s8v*)&As[wr * 64 + mf * 16 + fr][kk * 32 + g * 8];
      #pragma unroll
      for (int nf = 0; nf < FN; nf++)
        bfr[nf] = *(const s8v*)&Ws[wc * (BN / 2) + nf * 16 + fr][kk * 32 + g * 8];
      #pragma unroll
      for (int mf = 0; mf < 4; mf++)
        #pragma unroll
        for (int nf = 0; nf < FN; nf++)
          acc[mf][nf] = __builtin_amdgcn_mfma_f32_16x16x32_bf16(af[mf], bfr[nf], acc[mf][nf], 0, 0, 0);
    }
  }

  int rq = (lane >> 4) * 4;
  #pragma unroll
  for (int mf = 0; mf < 4; mf++) {
    #pragma unroll
    for (int nf = 0; nf < FN; nf++) {
      int row0 = m0 + wr * 64 + mf * 16 + rq;
      int col = n0 + wc * (BN / 2) + nf * 16 + fr;
      if (EPI == 0) {
        int sel = col >> 10, cl = col & 1023;
        int bb = row0 >> 9, nn = row0 & 511;
        int h2 = cl >> 6, dd = cl & 63;
        if (sel == 2) {
          s4v o4;
          #pragma unroll
          for (int r = 0; r < 4; r++) o4[r] = (short)f2bu(acc[mf][nf][r]);
          *(s4v*)&outb[(size_t)2 * 4194304 + (((size_t)bb * 16 + h2) * 64 + dd) * 512 + nn] = o4;
        } else {
          #pragma unroll
          for (int r = 0; r < 4; r++)
            outb[(size_t)sel * 4194304 + (((size_t)bb * 16 + h2) * 512 + (nn + r)) * 64 + dd] =
                __float2bfloat16(acc[mf][nf][r]);
        }
      } else {
        #pragma unroll
        for (int r = 0; r < 4; r++) {
          int row = row0 + r;
          float val = acc[mf][nf][r];
          if (EPI == 1) {
            outb[(size_t)row * Ncols + col] = __float2bfloat16(seluf(val + bias[col]));
          } else if (EPI == 2) {
            int bb = row >> 9;
            size_t idx = (size_t)row * 1024 + col;
            float nx = (xio[idx] + gfb[(size_t)bb * 6144 + col] * (val + bias[col])) * xmk[row];
            xio[idx] = nx;
          } else {
            outf[(size_t)row * 1024 + col] = (val + bias[col]) * xmk[row];
          }
        }
      }
    }
  }
}

extern "C" void kernel_launch(void* const* d_in, const int* in_sizes, int n_in,
                              void* d_out, int out_size, void* d_ws, size_t ws_size,
                              hipStream_t stream)
{
  const float* x_in  = (const float*)d_in[0];
  const float* tim   = (const float*)d_in[1];
  const float* lab   = (const float*)d_in[2];
  const float* xmask = (const float*)d_in[3];
  const float* Wl  = (const float*)d_in[4];
  const float* bl  = (const float*)d_in[5];
  const float* Wq  = (const float*)d_in[6];
  const float* Wk  = (const float*)d_in[7];
  const float* Wv  = (const float*)d_in[8];
  const float* W1  = (const float*)d_in[9];
  const float* b1  = (const float*)d_in[10];
  const float* W2  = (const float*)d_in[11];
  const float* b2  = (const float*)d_in[12];
  const float* Wm  = (const float*)d_in[13];
  const float* bm  = (const float*)d_in[14];
  const float* Wf  = (const float*)d_in[15];
  const float* bfp = (const float*)d_in[16];
  const float* Wmf = (const float*)d_in[17];
  const float* bmf = (const float*)d_in[18];

  char* ws = (char*)d_ws;
  float* x     = (float*)(ws + 0);          // 16777216 B
  float* cs    = (float*)(ws + 16777216);   // 32768 B
  float* mAll  = (float*)(ws + 16809984);   // 1572864 B  [L][B][6144]
  float* m2v   = (float*)(ws + 18382848);   // 65536 B    [B][2048]
  bf16*  h     = (bf16*)(ws + 18448384);    // 8388608 B
  bf16*  qb    = (bf16*)(ws + 26836992);    // 8388608 B  (B,H,N,D)
  bf16*  kb    = (bf16*)(ws + 35225600);    // 8388608 B  (B,H,N,D)
  bf16*  vb    = (bf16*)(ws + 43614208);    // 8388608 B  (B,H,D,N) V^T
  bf16*  att   = (bf16*)(ws + 52002816);    // 8388608 B  (B,N,C)
  bf16*  f1    = (bf16*)(ws + 60391424);    // 33554432 B (4096 x 4096)
  bf16*  wqkvb = (bf16*)(ws + 93945856);    // 6291456 B  [3072][1024]
  bf16*  w1b   = (bf16*)(ws + 100237312);   // 8388608 B  [4096][1024]
  bf16*  w2b   = (bf16*)(ws + 108625920);   // 8388608 B  [1024][4096]
  bf16*  wfb   = (bf16*)(ws + 117014528);   // 2097152 B  [1024][1024]

  hipMemcpyAsync(x, x_in, (size_t)4096 * 1024 * 4, hipMemcpyDeviceToDevice, stream);

  k_cond<<<8, 256, 0, stream>>>(tim, lab, Wl, bl, cs);
  k_small<<<12288, 256, 0, stream>>>(cs, Wm, bm, mAll, 49152, 0);
  k_small<<<512, 256, 0, stream>>>(cs, Wmf, bmf, m2v, 2048, 1);

  for (int l = 0; l < 8; l++) {
    const float* m6b = mAll + (size_t)l * 8 * 6144;
    k_convqkv<<<1536, 256, 0, stream>>>(Wq + (size_t)l * 1048576, Wk + (size_t)l * 1048576,
                                        Wv + (size_t)l * 1048576, wqkvb);
    k_conv<<<2048, 256, 0, stream>>>(W1 + (size_t)l * 4194304, w1b, 524288);
    k_conv<<<2048, 256, 0, stream>>>(W2 + (size_t)l * 4194304, w2b, 524288);

    k_lnmod<<<4096, 256, 0, stream>>>(x, m6b + 0, m6b + 1024, 6144, xmask, h, 1);
    k_gemm<0, 128><<<dim3(24, 32), 256, 0, stream>>>(h, wqkvb, nullptr, 1024, 3072,
                                                     qb, nullptr, nullptr, nullptr, nullptr);
    k_attn<<<dim3(4, 128), 256, 0, stream>>>(qb, kb, vb, xmask, att);
    k_resid<<<4096, 256, 0, stream>>>(x, att, m6b, h);
    k_gemm<1, 128><<<dim3(32, 32), 256, 0, stream>>>(h, w1b, b1 + l * 4096, 1024, 4096,
                                                     f1, nullptr, nullptr, nullptr, nullptr);
    k_gemm<2, 64><<<dim3(16, 32), 256, 0, stream>>>(f1, w2b, b2 + l * 1024, 4096, 1024,
                                                    nullptr, nullptr, x, m6b + 5120, xmask);
  }

  k_conv<<<512, 256, 0, stream>>>(Wf, wfb, 131072);
  k_lnmod<<<4096, 256, 0, stream>>>(x, m2v + 0, m2v + 1024, 2048, xmask, h, 0);
  k_gemm<3, 64><<<dim3(16, 32), 256, 0, stream>>>(h, wfb, bfp, 1024, 1024,
                                                  nullptr, (float*)d_out, nullptr, nullptr, xmask);
}

// Round 4
// 1914.594 us; speedup vs baseline: 2.9555x; 1.1341x over previous
//
#include <hip/hip_runtime.h>
#include <hip/hip_bf16.h>
#include <cstddef>

#define DEVI __device__ __forceinline__

typedef __attribute__((ext_vector_type(4))) float f4v;
typedef __attribute__((ext_vector_type(8))) short s8v;
typedef __attribute__((ext_vector_type(4))) short s4v;

using bf16 = __hip_bfloat16;

// L=8, B=8, N=512, C=1024, H=16, D=64
constexpr float SELU_A = 1.6732632423543772f;
constexpr float SELU_S = 1.0507009873554805f;
constexpr float TPINV  = 0.08838834764831845f; // 1/sqrt(2*D)

DEVI float bfbits(short s) { return __uint_as_float(((unsigned)(unsigned short)s) << 16); }
DEVI unsigned short f2bu(float f) {
  bf16 h = __float2bfloat16(f);
  return __builtin_bit_cast(unsigned short, h);
}
DEVI float seluf(float x) { return x > 0.f ? SELU_S * x : SELU_S * SELU_A * (__expf(x) - 1.f); }

DEVI void gl16(const void* g, void* l) {
  __builtin_amdgcn_global_load_lds((__attribute__((address_space(1))) void*)g,
                                   (__attribute__((address_space(3))) void*)l, 16, 0, 0);
}

// ---------------- mask compaction: per batch, list of live rows + inverse + count
__global__ void k_compact(const float* __restrict__ xm, int* __restrict__ idx,
                          int* __restrict__ pos, int* __restrict__ cnt)
{
  int b = blockIdx.x, lane = threadIdx.x; // 64 threads/block, 8 blocks
  int base = b * 512 + lane * 8;
  int mb[8]; int lc = 0;
  #pragma unroll
  for (int i = 0; i < 8; i++) { mb[i] = (xm[base + i] != 0.f) ? 1 : 0; lc += mb[i]; }
  int s = lc;
  #pragma unroll
  for (int o = 1; o < 64; o <<= 1) { int tt = __shfl_up(s, o); if (lane >= o) s += tt; }
  int run = s - lc;
  #pragma unroll
  for (int i = 0; i < 8; i++) {
    int n = lane * 8 + i;
    if (mb[i]) { idx[b * 512 + run] = n; pos[b * 512 + n] = run; run++; }
    else pos[b * 512 + n] = -1;
  }
  if (lane == 63) cnt[b] = s;
}

// ---------------- gather x into compacted layout (tail slots zeroed)
__global__ __launch_bounds__(256) void k_gather(const float* __restrict__ xin,
    const int* __restrict__ idx, const int* __restrict__ cnt, float* __restrict__ xc)
{
  int row = blockIdx.x, t = threadIdx.x, b = row >> 9, j = row & 511;
  f4v v = {0.f, 0.f, 0.f, 0.f};
  if (j < cnt[b]) v = *(const f4v*)&xin[((size_t)b * 512 + idx[b * 512 + j]) * 1024 + t * 4];
  *(f4v*)&xc[(size_t)row * 1024 + t * 4] = v;
}

// ---------------- scatter final rows back to original order; dead rows = 0
__global__ __launch_bounds__(256) void k_scatter(const float* __restrict__ ffin,
    const int* __restrict__ pos, float* __restrict__ out)
{
  int row = blockIdx.x, t = threadIdx.x, b = row >> 9;
  int p = pos[row];
  f4v v = {0.f, 0.f, 0.f, 0.f};
  if (p >= 0) v = *(const f4v*)&ffin[((size_t)b * 512 + p) * 1024 + t * 4];
  *(f4v*)&out[(size_t)row * 1024 + t * 4] = v;
}

// ---------------- fp32 -> bf16 convert (8 elems/thread)
__global__ __launch_bounds__(256) void k_conv(const float* __restrict__ src,
                                              bf16* __restrict__ dst, int n8)
{
  int i = blockIdx.x * 256 + threadIdx.x;
  if (i >= n8) return;
  const float* s = src + (size_t)i * 8;
  f4v a = *(const f4v*)s;
  f4v b = *(const f4v*)(s + 4);
  s8v o;
  #pragma unroll
  for (int j = 0; j < 4; j++) { o[j] = (short)f2bu(a[j]); o[4 + j] = (short)f2bu(b[j]); }
  *(s8v*)(dst + (size_t)i * 8) = o;
}

// ---------------- pack Wq/Wk/Wv (layer slice) -> [3072][1024] bf16
__global__ __launch_bounds__(256) void k_convqkv(const float* __restrict__ wq,
                                                 const float* __restrict__ wk,
                                                 const float* __restrict__ wv,
                                                 bf16* __restrict__ dst)
{
  int i = blockIdx.x * 256 + threadIdx.x; // < 393216
  int o = i * 8;
  int row = o >> 10, col = o & 1023;
  int sel = row >> 10, sr = row & 1023;
  const float* src = (sel == 0 ? wq : sel == 1 ? wk : wv) + (size_t)sr * 1024 + col;
  f4v a = *(const f4v*)src;
  f4v b = *(const f4v*)(src + 4);
  s8v out;
  #pragma unroll
  for (int j = 0; j < 4; j++) { out[j] = (short)f2bu(a[j]); out[4 + j] = (short)f2bu(b[j]); }
  *(s8v*)(dst + o) = out;
}

// ---------------- conditioning
__global__ void k_cond(const float* __restrict__ tim, const float* __restrict__ lab,
                       const float* __restrict__ Wl, const float* __restrict__ bl,
                       float* __restrict__ cs)
{
  int b = blockIdx.x, t = threadIdx.x;
  float l0 = lab[b * 2 + 0], l1 = lab[b * 2 + 1], tv = tim[b];
  #pragma unroll
  for (int i = 0; i < 4; i++) {
    int j = t + 256 * i;
    float e = powf(10000.f, (2.f * (float)j) * (1.f / 1024.f));
    float arg = tv / e;
    float te = ((j & 1) == 0) ? sinf(arg) : cosf(arg);
    float c = l0 * Wl[j * 2 + 0] + l1 * Wl[j * 2 + 1] + bl[j] + te;
    cs[b * 1024 + j] = seluf(c);
  }
}

// ---------------- small matvec batch: out = cs(8x1024) @ W(O x 1024)^T + bias
__global__ __launch_bounds__(256) void k_small(
    const float* __restrict__ cs, const float* __restrict__ W, const float* __restrict__ bias,
    float* __restrict__ out, int O, int mode)
{
  __shared__ float cls[8192];
  int t = threadIdx.x;
  #pragma unroll
  for (int i = 0; i < 8; i++)
    *(f4v*)&cls[i * 1024 + t * 4] = *(const f4v*)&cs[i * 1024 + t * 4];
  __syncthreads();
  int w = t >> 6, l = t & 63;
  int o = blockIdx.x * 4 + w;
  if (o >= O) return;
  float acc[8] = {0.f, 0.f, 0.f, 0.f, 0.f, 0.f, 0.f, 0.f};
  const float* Wr = W + (size_t)o * 1024;
  for (int i = 0; i < 16; i++) {
    int k = i * 64 + l;
    float wv = Wr[k];
    #pragma unroll
    for (int b = 0; b < 8; b++) acc[b] += wv * cls[b * 1024 + k];
  }
  #pragma unroll
  for (int b = 0; b < 8; b++) {
    #pragma unroll
    for (int off = 32; off; off >>= 1) acc[b] += __shfl_xor(acc[b], off);
  }
  float bv = bias[o];
  #pragma unroll
  for (int b = 0; b < 8; b++) {
    if (l == b) {
      float val = acc[b] + bv;
      size_t dst;
      if (mode == 0) { int ll = o / 6144, ft = o - ll * 6144; dst = ((size_t)ll * 8 + b) * 6144 + ft; }
      else dst = (size_t)b * 2048 + o;
      out[dst] = val;
    }
  }
}

// ---------------- row LN + modulate -> bf16 (compacted rows; tail rows -> 0)
__global__ __launch_bounds__(256) void k_lnmod(
    const float* __restrict__ x, const float* __restrict__ shiftB, const float* __restrict__ scaleB,
    int bstride, const int* __restrict__ cnt, bf16* __restrict__ out)
{
  int row = blockIdx.x, t = threadIdx.x, b = row >> 9;
  if ((row & 511) >= cnt[b]) {
    s4v z = {0, 0, 0, 0};
    *(s4v*)&out[(size_t)row * 1024 + t * 4] = z;
    return;
  }
  const float* xr = x + (size_t)row * 1024;
  f4v v = *(const f4v*)&xr[t * 4];
  float s = v[0] + v[1] + v[2] + v[3];
  float ss = v[0]*v[0] + v[1]*v[1] + v[2]*v[2] + v[3]*v[3];
  #pragma unroll
  for (int off = 32; off; off >>= 1) { s += __shfl_xor(s, off); ss += __shfl_xor(ss, off); }
  __shared__ float rs[4], rss[4];
  int w = t >> 6;
  if ((t & 63) == 0) { rs[w] = s; rss[w] = ss; }
  __syncthreads();
  s = rs[0] + rs[1] + rs[2] + rs[3];
  ss = rss[0] + rss[1] + rss[2] + rss[3];
  float mean = s * (1.f / 1024.f);
  float var = ss * (1.f / 1024.f) - mean * mean;
  float rstd = rsqrtf(var + 1e-6f);
  f4v sh = *(const f4v*)&shiftB[(size_t)b * bstride + t * 4];
  f4v sc = *(const f4v*)&scaleB[(size_t)b * bstride + t * 4];
  s4v o;
  #pragma unroll
  for (int i = 0; i < 4; i++)
    o[i] = (short)f2bu((v[i] - mean) * rstd * (1.f + sc[i]) + sh[i]);
  *(s4v*)&out[(size_t)row * 1024 + t * 4] = o;
}

// ---------------- x += gm*att; h2 = modulate(ln(x), sf, cf) -> bf16 (tail -> 0)
__global__ __launch_bounds__(256) void k_resid(
    float* __restrict__ x, const bf16* __restrict__ att, const float* __restrict__ m6b,
    const int* __restrict__ cnt, bf16* __restrict__ h2)
{
  int row = blockIdx.x, t = threadIdx.x, b = row >> 9;
  if ((row & 511) >= cnt[b]) {
    s4v z = {0, 0, 0, 0};
    *(s4v*)&h2[(size_t)row * 1024 + t * 4] = z;
    return;
  }
  float* xr = x + (size_t)row * 1024;
  const float* gm = m6b + (size_t)b * 6144 + 2048;
  const float* sf = m6b + (size_t)b * 6144 + 3072;
  const float* cf = m6b + (size_t)b * 6144 + 4096;
  f4v xv = *(const f4v*)&xr[t * 4];
  s4v av = *(const s4v*)&att[(size_t)row * 1024 + t * 4];
  f4v gv = *(const f4v*)&gm[t * 4];
  f4v vv;
  #pragma unroll
  for (int i = 0; i < 4; i++) vv[i] = xv[i] + gv[i] * bfbits(av[i]);
  *(f4v*)&xr[t * 4] = vv;
  float s = vv[0] + vv[1] + vv[2] + vv[3];
  float ss = vv[0]*vv[0] + vv[1]*vv[1] + vv[2]*vv[2] + vv[3]*vv[3];
  #pragma unroll
  for (int off = 32; off; off >>= 1) { s += __shfl_xor(s, off); ss += __shfl_xor(ss, off); }
  __shared__ float rs[4], rss[4];
  int w = t >> 6;
  if ((t & 63) == 0) { rs[w] = s; rss[w] = ss; }
  __syncthreads();
  s = rs[0] + rs[1] + rs[2] + rs[3];
  ss = rss[0] + rss[1] + rss[2] + rss[3];
  float mean = s * (1.f / 1024.f);
  float var = ss * (1.f / 1024.f) - mean * mean;
  float rstd = rsqrtf(var + 1e-6f);
  f4v sfv = *(const f4v*)&sf[t * 4];
  f4v cfv = *(const f4v*)&cf[t * 4];
  s4v o;
  #pragma unroll
  for (int i = 0; i < 4; i++)
    o[i] = (short)f2bu((vv[i] - mean) * rstd * (1.f + cfv[i]) + sfv[i]);
  *(s4v*)&h2[(size_t)row * 1024 + t * 4] = o;
}

// ---------------- MFMA flash attention on compacted rows (maskless; cnt-bounded)
__global__ __launch_bounds__(256) void k_attn(
    const bf16* __restrict__ q, const bf16* __restrict__ k, const bf16* __restrict__ vt,
    const int* __restrict__ cnt, bf16* __restrict__ att)
{
  int bh = blockIdx.y, b = bh >> 4, hh = bh & 15;
  int cntb = cnt[b];
  if ((int)blockIdx.x * 128 >= cntb) return;
  int t = threadIdx.x, w = t >> 6, lane = t & 63;
  int fr = lane & 15, g = lane >> 4;
  int qw = blockIdx.x * 128 + w * 32;
  const size_t ho = (size_t)bh * (512 * 64);

  __shared__ bf16 Pb[4][32][72];

  s8v qf[2][2];
  #pragma unroll
  for (int mf = 0; mf < 2; mf++)
    #pragma unroll
    for (int kk = 0; kk < 2; kk++)
      qf[mf][kk] = *(const s8v*)(q + ho + (size_t)(qw + mf * 16 + fr) * 64 + kk * 32 + g * 8);

  float mrow[2][4], lsum[2][4];
  f4v oacc[2][4];
  const f4v vzero = {0.f, 0.f, 0.f, 0.f};
  #pragma unroll
  for (int mf = 0; mf < 2; mf++)
    #pragma unroll
    for (int r = 0; r < 4; r++) { mrow[mf][r] = -3.0e38f; lsum[mf][r] = 0.f; }
  #pragma unroll
  for (int mf = 0; mf < 2; mf++)
    #pragma unroll
    for (int nd = 0; nd < 4; nd++) oacc[mf][nd] = vzero;

  int nkt = (cntb + 63) >> 6;
  for (int kt = 0; kt < nkt; kt++) {
    int kb0 = kt * 64;
    f4v sacc[2][4];
    #pragma unroll
    for (int mf = 0; mf < 2; mf++)
      #pragma unroll
      for (int nf = 0; nf < 4; nf++) sacc[mf][nf] = vzero;
    #pragma unroll
    for (int kk = 0; kk < 2; kk++) {
      s8v kf[4];
      #pragma unroll
      for (int nf = 0; nf < 4; nf++)
        kf[nf] = *(const s8v*)(k + ho + (size_t)(kb0 + nf * 16 + fr) * 64 + kk * 32 + g * 8);
      #pragma unroll
      for (int mf = 0; mf < 2; mf++)
        #pragma unroll
        for (int nf = 0; nf < 4; nf++)
          sacc[mf][nf] = __builtin_amdgcn_mfma_f32_16x16x32_bf16(qf[mf][kk], kf[nf], sacc[mf][nf], 0, 0, 0);
    }
    #pragma unroll
    for (int mf = 0; mf < 2; mf++) {
      #pragma unroll
      for (int r = 0; r < 4; r++) {
        float mx = -3.0e38f;
        #pragma unroll
        for (int nf = 0; nf < 4; nf++) {
          float s = sacc[mf][nf][r] * TPINV;
          if (kb0 + nf * 16 + fr >= cntb) s = -1.0e30f;
          sacc[mf][nf][r] = s;
          mx = fmaxf(mx, s);
        }
        mx = fmaxf(mx, __shfl_xor(mx, 1));
        mx = fmaxf(mx, __shfl_xor(mx, 2));
        mx = fmaxf(mx, __shfl_xor(mx, 4));
        mx = fmaxf(mx, __shfl_xor(mx, 8));
        float mnew = fmaxf(mrow[mf][r], mx);
        float corr = __expf(mrow[mf][r] - mnew);
        mrow[mf][r] = mnew;
        float ps = 0.f;
        #pragma unroll
        for (int nf = 0; nf < 4; nf++) {
          float p = __expf(sacc[mf][nf][r] - mnew);
          ps += p;
          Pb[w][mf * 16 + g * 4 + r][nf * 16 + fr] = __float2bfloat16(p);
        }
        lsum[mf][r] = lsum[mf][r] * corr + ps;
        #pragma unroll
        for (int nd = 0; nd < 4; nd++) oacc[mf][nd][r] *= corr;
      }
    }
    #pragma unroll
    for (int kk = 0; kk < 2; kk++) {
      s8v pf[2], vf[4];
      #pragma unroll
      for (int mf = 0; mf < 2; mf++)
        pf[mf] = *(const s8v*)&Pb[w][mf * 16 + fr][kk * 32 + g * 8];
      #pragma unroll
      for (int nd = 0; nd < 4; nd++)
        vf[nd] = *(const s8v*)(vt + ho + (size_t)(nd * 16 + fr) * 512 + kb0 + kk * 32 + g * 8);
      #pragma unroll
      for (int mf = 0; mf < 2; mf++)
        #pragma unroll
        for (int nd = 0; nd < 4; nd++)
          oacc[mf][nd] = __builtin_amdgcn_mfma_f32_16x16x32_bf16(pf[mf], vf[nd], oacc[mf][nd], 0, 0, 0);
    }
  }
  float inv[2][4];
  #pragma unroll
  for (int mf = 0; mf < 2; mf++)
    #pragma unroll
    for (int r = 0; r < 4; r++) {
      float ls = lsum[mf][r];
      ls += __shfl_xor(ls, 1);
      ls += __shfl_xor(ls, 2);
      ls += __shfl_xor(ls, 4);
      ls += __shfl_xor(ls, 8);
      inv[mf][r] = 1.f / ls;
    }
  #pragma unroll
  for (int mf = 0; mf < 2; mf++)
    #pragma unroll
    for (int nd = 0; nd < 4; nd++)
      #pragma unroll
      for (int r = 0; r < 4; r++) {
        int row = qw + mf * 16 + g * 4 + r;
        att[(size_t)(b * 512 + row) * 1024 + hh * 64 + nd * 16 + fr] =
            __float2bfloat16(oacc[mf][nd][r] * inv[mf][r]);
      }
}

// ---------------- m97-structure GEMM on compacted rows
// A bf16 (M x K), W bf16 (N x K). Dead 128-row m-tiles exit early via cnt.
// EPI: 0=QKV store (Q,K:(B,H,slot,D); V:(B,H,D,slot)), 1=selu+bias->bf16,
//      2=residual+gate (x f32 in/out), 3=bias->f32 (compacted final)
template <int EPI, int BN>
__global__ __launch_bounds__(256) void k_gemm(
    const bf16* __restrict__ A, const bf16* __restrict__ W,
    const float* __restrict__ bias, int K, int Ncols,
    const int* __restrict__ cnt,
    bf16* __restrict__ outb, float* __restrict__ outf,
    float* __restrict__ xio, const float* __restrict__ gfb)
{
  constexpr int FN = BN / 32;
  constexpr int NW = BN / 32;
  __shared__ bf16 As[128][64];
  __shared__ bf16 Ws[BN][64];
  int t = threadIdx.x, lane = t & 63, w = t >> 6;
  int wr = w >> 1, wc = w & 1;
  int m0 = blockIdx.y * 128, n0 = blockIdx.x * BN;
  if ((m0 & 511) >= cnt[m0 >> 9]) return;
  int fr = lane & 15, g = lane >> 4;

  const bf16* Abase = A + (size_t)m0 * K;
  const bf16* Wbase = W + (size_t)n0 * K;

  const f4v vzero = {0.f, 0.f, 0.f, 0.f};
  f4v acc[4][FN];
  #pragma unroll
  for (int i = 0; i < 4; i++)
    #pragma unroll
    for (int j = 0; j < FN; j++) acc[i][j] = vzero;

  int nkt = K >> 6;
  for (int kt = 0; kt < nkt; kt++) {
    int k0 = kt << 6;
    __syncthreads();
    #pragma unroll
    for (int i = 0; i < 4; i++) {
      int off = w * 4096 + i * 1024 + lane * 16;
      int row = off >> 7, ce = (off & 127) >> 1;
      gl16(Abase + (size_t)row * K + k0 + ce, (char*)As + w * 4096 + i * 1024);
    }
    #pragma unroll
    for (int i = 0; i < NW; i++) {
      int off = w * (NW * 1024) + i * 1024 + lane * 16;
      int row = off >> 7, ce = (off & 127) >> 1;
      gl16(Wbase + (size_t)row * K + k0 + ce, (char*)Ws + w * (NW * 1024) + i * 1024);
    }
    __syncthreads();
    #pragma unroll
    for (int kk = 0; kk < 2; kk++) {
      s8v af[4], bfr[FN];
      #pragma unroll
      for (int mf = 0; mf < 4; mf++)
        af[mf] = *(const s8v*)&As[wr * 64 + mf * 16 + fr][kk * 32 + g * 8];
      #pragma unroll
      for (int nf = 0; nf < FN; nf++)
        bfr[nf] = *(const s8v*)&Ws[wc * (BN / 2) + nf * 16 + fr][kk * 32 + g * 8];
      #pragma unroll
      for (int mf = 0; mf < 4; mf++)
        #pragma unroll
        for (int nf = 0; nf < FN; nf++)
          acc[mf][nf] = __builtin_amdgcn_mfma_f32_16x16x32_bf16(af[mf], bfr[nf], acc[mf][nf], 0, 0, 0);
    }
  }

  int rq = (lane >> 4) * 4;
  #pragma unroll
  for (int mf = 0; mf < 4; mf++) {
    #pragma unroll
    for (int nf = 0; nf < FN; nf++) {
      int row0 = m0 + wr * 64 + mf * 16 + rq;
      int col = n0 + wc * (BN / 2) + nf * 16 + fr;
      if (EPI == 0) {
        int sel = col >> 10, cl = col & 1023;
        int bb = row0 >> 9, nn = row0 & 511;
        int h2 = cl >> 6, dd = cl & 63;
        if (sel == 2) {
          s4v o4;
          #pragma unroll
          for (int r = 0; r < 4; r++) o4[r] = (short)f2bu(acc[mf][nf][r]);
          *(s4v*)&outb[(size_t)2 * 4194304 + (((size_t)bb * 16 + h2) * 64 + dd) * 512 + nn] = o4;
        } else {
          #pragma unroll
          for (int r = 0; r < 4; r++)
            outb[(size_t)sel * 4194304 + (((size_t)bb * 16 + h2) * 512 + (nn + r)) * 64 + dd] =
                __float2bfloat16(acc[mf][nf][r]);
        }
      } else {
        #pragma unroll
        for (int r = 0; r < 4; r++) {
          int row = row0 + r;
          float val = acc[mf][nf][r];
          if (EPI == 1) {
            outb[(size_t)row * Ncols + col] = __float2bfloat16(seluf(val + bias[col]));
          } else if (EPI == 2) {
            int bb = row >> 9;
            size_t idx = (size_t)row * 1024 + col;
            xio[idx] = xio[idx] + gfb[(size_t)bb * 6144 + col] * (val + bias[col]);
          } else {
            outf[(size_t)row * 1024 + col] = val + bias[col];
          }
        }
      }
    }
  }
}

extern "C" void kernel_launch(void* const* d_in, const int* in_sizes, int n_in,
                              void* d_out, int out_size, void* d_ws, size_t ws_size,
                              hipStream_t stream)
{
  const float* x_in  = (const float*)d_in[0];
  const float* tim   = (const float*)d_in[1];
  const float* lab   = (const float*)d_in[2];
  const float* xmask = (const float*)d_in[3];
  const float* Wl  = (const float*)d_in[4];
  const float* bl  = (const float*)d_in[5];
  const float* Wq  = (const float*)d_in[6];
  const float* Wk  = (const float*)d_in[7];
  const float* Wv  = (const float*)d_in[8];
  const float* W1  = (const float*)d_in[9];
  const float* b1  = (const float*)d_in[10];
  const float* W2  = (const float*)d_in[11];
  const float* b2  = (const float*)d_in[12];
  const float* Wm  = (const float*)d_in[13];
  const float* bm  = (const float*)d_in[14];
  const float* Wf  = (const float*)d_in[15];
  const float* bfp = (const float*)d_in[16];
  const float* Wmf = (const float*)d_in[17];
  const float* bmf = (const float*)d_in[18];

  char* ws = (char*)d_ws;
  float* x     = (float*)(ws + 0);          // 16777216 B (compacted)
  float* cs    = (float*)(ws + 16777216);   // 32768 B
  float* mAll  = (float*)(ws + 16809984);   // 1572864 B  [L][B][6144]
  float* m2v   = (float*)(ws + 18382848);   // 65536 B    [B][2048]
  bf16*  h     = (bf16*)(ws + 18448384);    // 8388608 B
  bf16*  qb    = (bf16*)(ws + 26836992);    // 8388608 B  (B,H,slot,D)
  bf16*  kb    = (bf16*)(ws + 35225600);    // 8388608 B  (B,H,slot,D)
  bf16*  vb    = (bf16*)(ws + 43614208);    // 8388608 B  (B,H,D,slot) V^T
  bf16*  att   = (bf16*)(ws + 52002816);    // 8388608 B  (B,slot,C)
  bf16*  f1    = (bf16*)(ws + 60391424);    // 33554432 B (4096 x 4096)
  bf16*  wqkvb = (bf16*)(ws + 93945856);    // 6291456 B  [3072][1024]
  bf16*  w1b   = (bf16*)(ws + 100237312);   // 8388608 B  [4096][1024]
  bf16*  w2b   = (bf16*)(ws + 108625920);   // 8388608 B  [1024][4096]
  bf16*  wfb   = (bf16*)(ws + 117014528);   // 2097152 B  [1024][1024]
  float* ffin  = (float*)(ws + 119111680);  // 16777216 B (compacted final)
  int*   idxb  = (int*)(ws + 135888896);    // 16384 B
  int*   posb  = (int*)(ws + 135905280);    // 16384 B
  int*   cntb  = (int*)(ws + 135921664);    // 64 B

  k_compact<<<8, 64, 0, stream>>>(xmask, idxb, posb, cntb);
  k_gather<<<4096, 256, 0, stream>>>(x_in, idxb, cntb, x);

  k_cond<<<8, 256, 0, stream>>>(tim, lab, Wl, bl, cs);
  k_small<<<12288, 256, 0, stream>>>(cs, Wm, bm, mAll, 49152, 0);
  k_small<<<512, 256, 0, stream>>>(cs, Wmf, bmf, m2v, 2048, 1);

  for (int l = 0; l < 8; l++) {
    const float* m6b = mAll + (size_t)l * 8 * 6144;
    k_convqkv<<<1536, 256, 0, stream>>>(Wq + (size_t)l * 1048576, Wk + (size_t)l * 1048576,
                                        Wv + (size_t)l * 1048576, wqkvb);
    k_conv<<<2048, 256, 0, stream>>>(W1 + (size_t)l * 4194304, w1b, 524288);
    k_conv<<<2048, 256, 0, stream>>>(W2 + (size_t)l * 4194304, w2b, 524288);

    k_lnmod<<<4096, 256, 0, stream>>>(x, m6b + 0, m6b + 1024, 6144, cntb, h);
    k_gemm<0, 128><<<dim3(24, 32), 256, 0, stream>>>(h, wqkvb, nullptr, 1024, 3072, cntb,
                                                     qb, nullptr, nullptr, nullptr);
    k_attn<<<dim3(4, 128), 256, 0, stream>>>(qb, kb, vb, cntb, att);
    k_resid<<<4096, 256, 0, stream>>>(x, att, m6b, cntb, h);
    k_gemm<1, 128><<<dim3(32, 32), 256, 0, stream>>>(h, w1b, b1 + l * 4096, 1024, 4096, cntb,
                                                     f1, nullptr, nullptr, nullptr);
    k_gemm<2, 64><<<dim3(16, 32), 256, 0, stream>>>(f1, w2b, b2 + l * 1024, 4096, 1024, cntb,
                                                    nullptr, nullptr, x, m6b + 5120);
  }

  k_conv<<<512, 256, 0, stream>>>(Wf, wfb, 131072);
  k_lnmod<<<4096, 256, 0, stream>>>(x, m2v + 0, m2v + 1024, 2048, cntb, h);
  k_gemm<3, 64><<<dim3(16, 32), 256, 0, stream>>>(h, wfb, bfp, 1024, 1024, cntb,
                                                  nullptr, ffin, nullptr, nullptr);
  k_scatter<<<4096, 256, 0, stream>>>(ffin, posb, (float*)d_out);
}

// Round 5
// 1639.901 us; speedup vs baseline: 3.4506x; 1.1675x over previous
//
#include <hip/hip_runtime.h>
#include <hip/hip_bf16.h>
#include <cstddef>

#define DEVI __device__ __forceinline__

typedef __attribute__((ext_vector_type(4))) float f4v;
typedef __attribute__((ext_vector_type(8))) short s8v;
typedef __attribute__((ext_vector_type(4))) short s4v;

using bf16 = __hip_bfloat16;

// L=8, B=8, N=512, C=1024, H=16, D=64
constexpr float SELU_A = 1.6732632423543772f;
constexpr float SELU_S = 1.0507009873554805f;
constexpr float TPINV  = 0.08838834764831845f; // 1/sqrt(2*D)

DEVI float bfbits(short s) { return __uint_as_float(((unsigned)(unsigned short)s) << 16); }
DEVI unsigned short f2bu(float f) {
  bf16 h = __float2bfloat16(f);
  return __builtin_bit_cast(unsigned short, h);
}
DEVI float seluf(float x) { return x > 0.f ? SELU_S * x : SELU_S * SELU_A * (__expf(x) - 1.f); }

DEVI void gl16(const void* g, void* l) {
  __builtin_amdgcn_global_load_lds((__attribute__((address_space(1))) void*)g,
                                   (__attribute__((address_space(3))) void*)l, 16, 0, 0);
}

// ---------------- mask compaction: global 128-aligned packing.
// idx[b*512+slot]=orig row, pos[b*512+orig]=slot(or -1), cnt[b], start[9], t2b[32]
__global__ void k_compact(const float* __restrict__ xm, int* __restrict__ idx,
                          int* __restrict__ pos, int* __restrict__ cnt,
                          int* __restrict__ start, int* __restrict__ t2b)
{
  int t = threadIdx.x;           // 512 threads, wave w = batch w
  int b = t >> 6, lane = t & 63;
  __shared__ int scnt[8];
  int base = b * 512 + lane * 8;
  int mb[8]; int lc = 0;
  #pragma unroll
  for (int i = 0; i < 8; i++) { mb[i] = (xm[base + i] != 0.f) ? 1 : 0; lc += mb[i]; }
  int s = lc;
  #pragma unroll
  for (int o = 1; o < 64; o <<= 1) { int tt = __shfl_up(s, o); if (lane >= o) s += tt; }
  int run = s - lc;
  #pragma unroll
  for (int i = 0; i < 8; i++) {
    int n = lane * 8 + i;
    if (mb[i]) { idx[b * 512 + run] = n; pos[b * 512 + n] = run; run++; }
    else pos[b * 512 + n] = -1;
  }
  if (lane == 63) scnt[b] = s;
  __syncthreads();
  if (t == 0) {
    int st = 0, tile = 0;
    for (int bb = 0; bb < 8; bb++) {
      cnt[bb] = scnt[bb];
      start[bb] = st;
      int nt = (scnt[bb] + 127) >> 7;
      for (int k = 0; k < nt; k++) t2b[tile++] = bb;
      st += nt * 128;
    }
    start[8] = st;
    for (; tile < 32; tile++) t2b[tile] = 0;
  }
}

// ---------------- gather x into globally-compacted layout (tails zeroed)
__global__ __launch_bounds__(256) void k_gather(const float* __restrict__ xin,
    const int* __restrict__ idx, const int* __restrict__ cnt,
    const int* __restrict__ start, const int* __restrict__ t2b,
    float* __restrict__ xc)
{
  int row = blockIdx.x, t = threadIdx.x;
  if (row >= start[8]) return;
  int tb = t2b[row >> 7], slot = row - start[tb];
  f4v v = {0.f, 0.f, 0.f, 0.f};
  if (slot < cnt[tb])
    v = *(const f4v*)&xin[((size_t)tb * 512 + idx[tb * 512 + slot]) * 1024 + t * 4];
  *(f4v*)&xc[(size_t)row * 1024 + t * 4] = v;
}

// ---------------- scatter final rows back; dead rows = 0
__global__ __launch_bounds__(256) void k_scatter(const float* __restrict__ ffin,
    const int* __restrict__ pos, const int* __restrict__ start, float* __restrict__ out)
{
  int row = blockIdx.x, t = threadIdx.x, b = row >> 9;
  int p = pos[row];
  f4v v = {0.f, 0.f, 0.f, 0.f};
  if (p >= 0) v = *(const f4v*)&ffin[(size_t)(start[b] + p) * 1024 + t * 4];
  *(f4v*)&out[(size_t)row * 1024 + t * 4] = v;
}

// ---------------- fp32 -> bf16 (8/thread)
__global__ __launch_bounds__(256) void k_conv(const float* __restrict__ src,
                                              bf16* __restrict__ dst, int n8)
{
  int i = blockIdx.x * 256 + threadIdx.x;
  if (i >= n8) return;
  const float* s = src + (size_t)i * 8;
  f4v a = *(const f4v*)s;
  f4v b = *(const f4v*)(s + 4);
  s8v o;
  #pragma unroll
  for (int j = 0; j < 4; j++) { o[j] = (short)f2bu(a[j]); o[4 + j] = (short)f2bu(b[j]); }
  *(s8v*)(dst + (size_t)i * 8) = o;
}

// ---------------- per-layer merged weight conversion: QKV pack + W1 + W2
__global__ __launch_bounds__(256) void k_convall(
    const float* __restrict__ wq, const float* __restrict__ wk, const float* __restrict__ wv,
    const float* __restrict__ w1, const float* __restrict__ w2,
    bf16* __restrict__ wqkvb, bf16* __restrict__ w1b, bf16* __restrict__ w2b)
{
  int i = blockIdx.x * 256 + threadIdx.x;
  const float* src; bf16* dst;
  if (i < 393216) {
    int o = i * 8;
    int row = o >> 10, col = o & 1023;
    int sel = row >> 10, sr = row & 1023;
    src = (sel == 0 ? wq : sel == 1 ? wk : wv) + (size_t)sr * 1024 + col;
    dst = wqkvb + o;
  } else if (i < 917504) {
    size_t o = (size_t)(i - 393216) * 8;
    src = w1 + o; dst = w1b + o;
  } else if (i < 1441792) {
    size_t o = (size_t)(i - 917504) * 8;
    src = w2 + o; dst = w2b + o;
  } else return;
  f4v a = *(const f4v*)src;
  f4v b = *(const f4v*)(src + 4);
  s8v out;
  #pragma unroll
  for (int j = 0; j < 4; j++) { out[j] = (short)f2bu(a[j]); out[4 + j] = (short)f2bu(b[j]); }
  *(s8v*)dst = out;
}

// ---------------- conditioning
__global__ void k_cond(const float* __restrict__ tim, const float* __restrict__ lab,
                       const float* __restrict__ Wl, const float* __restrict__ bl,
                       float* __restrict__ cs)
{
  int b = blockIdx.x, t = threadIdx.x;
  float l0 = lab[b * 2 + 0], l1 = lab[b * 2 + 1], tv = tim[b];
  #pragma unroll
  for (int i = 0; i < 4; i++) {
    int j = t + 256 * i;
    float e = powf(10000.f, (2.f * (float)j) * (1.f / 1024.f));
    float arg = tv / e;
    float te = ((j & 1) == 0) ? sinf(arg) : cosf(arg);
    float c = l0 * Wl[j * 2 + 0] + l1 * Wl[j * 2 + 1] + bl[j] + te;
    cs[b * 1024 + j] = seluf(c);
  }
}

// ---------------- small matvec batch
__global__ __launch_bounds__(256) void k_small(
    const float* __restrict__ cs, const float* __restrict__ W, const float* __restrict__ bias,
    float* __restrict__ out, int O, int mode)
{
  __shared__ float cls[8192];
  int t = threadIdx.x;
  #pragma unroll
  for (int i = 0; i < 8; i++)
    *(f4v*)&cls[i * 1024 + t * 4] = *(const f4v*)&cs[i * 1024 + t * 4];
  __syncthreads();
  int w = t >> 6, l = t & 63;
  int o = blockIdx.x * 4 + w;
  if (o >= O) return;
  float acc[8] = {0.f, 0.f, 0.f, 0.f, 0.f, 0.f, 0.f, 0.f};
  const float* Wr = W + (size_t)o * 1024;
  for (int i = 0; i < 16; i++) {
    int k = i * 64 + l;
    float wv = Wr[k];
    #pragma unroll
    for (int b = 0; b < 8; b++) acc[b] += wv * cls[b * 1024 + k];
  }
  #pragma unroll
  for (int b = 0; b < 8; b++) {
    #pragma unroll
    for (int off = 32; off; off >>= 1) acc[b] += __shfl_xor(acc[b], off);
  }
  float bv = bias[o];
  #pragma unroll
  for (int b = 0; b < 8; b++) {
    if (l == b) {
      float val = acc[b] + bv;
      size_t dst;
      if (mode == 0) { int ll = o / 6144, ft = o - ll * 6144; dst = ((size_t)ll * 8 + b) * 6144 + ft; }
      else dst = (size_t)b * 2048 + o;
      out[dst] = val;
    }
  }
}

// ---------------- row LN + modulate -> bf16 (global compacted; tails -> 0)
__global__ __launch_bounds__(256) void k_lnmod(
    const float* __restrict__ x, const float* __restrict__ shiftB, const float* __restrict__ scaleB,
    int bstride, const int* __restrict__ cnt, const int* __restrict__ start,
    const int* __restrict__ t2b, bf16* __restrict__ out)
{
  int row = blockIdx.x, t = threadIdx.x;
  if (row >= start[8]) return;
  int tb = t2b[row >> 7], slot = row - start[tb];
  if (slot >= cnt[tb]) {
    s4v z = {0, 0, 0, 0};
    *(s4v*)&out[(size_t)row * 1024 + t * 4] = z;
    return;
  }
  const float* xr = x + (size_t)row * 1024;
  f4v v = *(const f4v*)&xr[t * 4];
  float s = v[0] + v[1] + v[2] + v[3];
  float ss = v[0]*v[0] + v[1]*v[1] + v[2]*v[2] + v[3]*v[3];
  #pragma unroll
  for (int off = 32; off; off >>= 1) { s += __shfl_xor(s, off); ss += __shfl_xor(ss, off); }
  __shared__ float rs[4], rss[4];
  int w = t >> 6;
  if ((t & 63) == 0) { rs[w] = s; rss[w] = ss; }
  __syncthreads();
  s = rs[0] + rs[1] + rs[2] + rs[3];
  ss = rss[0] + rss[1] + rss[2] + rss[3];
  float mean = s * (1.f / 1024.f);
  float var = ss * (1.f / 1024.f) - mean * mean;
  float rstd = rsqrtf(var + 1e-6f);
  f4v sh = *(const f4v*)&shiftB[(size_t)tb * bstride + t * 4];
  f4v sc = *(const f4v*)&scaleB[(size_t)tb * bstride + t * 4];
  s4v o;
  #pragma unroll
  for (int i = 0; i < 4; i++)
    o[i] = (short)f2bu((v[i] - mean) * rstd * (1.f + sc[i]) + sh[i]);
  *(s4v*)&out[(size_t)row * 1024 + t * 4] = o;
}

// ---------------- x += gm*att; h2 = modulate(ln(x), sf, cf) -> bf16 (tails -> 0)
__global__ __launch_bounds__(256) void k_resid(
    float* __restrict__ x, const bf16* __restrict__ att, const float* __restrict__ m6b,
    const int* __restrict__ cnt, const int* __restrict__ start,
    const int* __restrict__ t2b, bf16* __restrict__ h2)
{
  int row = blockIdx.x, t = threadIdx.x;
  if (row >= start[8]) return;
  int tb = t2b[row >> 7], slot = row - start[tb];
  if (slot >= cnt[tb]) {
    s4v z = {0, 0, 0, 0};
    *(s4v*)&h2[(size_t)row * 1024 + t * 4] = z;
    return;
  }
  float* xr = x + (size_t)row * 1024;
  const float* gm = m6b + (size_t)tb * 6144 + 2048;
  const float* sf = m6b + (size_t)tb * 6144 + 3072;
  const float* cf = m6b + (size_t)tb * 6144 + 4096;
  f4v xv = *(const f4v*)&xr[t * 4];
  s4v av = *(const s4v*)&att[((size_t)tb * 512 + slot) * 1024 + t * 4];
  f4v gv = *(const f4v*)&gm[t * 4];
  f4v vv;
  #pragma unroll
  for (int i = 0; i < 4; i++) vv[i] = xv[i] + gv[i] * bfbits(av[i]);
  *(f4v*)&xr[t * 4] = vv;
  float s = vv[0] + vv[1] + vv[2] + vv[3];
  float ss = vv[0]*vv[0] + vv[1]*vv[1] + vv[2]*vv[2] + vv[3]*vv[3];
  #pragma unroll
  for (int off = 32; off; off >>= 1) { s += __shfl_xor(s, off); ss += __shfl_xor(ss, off); }
  __shared__ float rs[4], rss[4];
  int w = t >> 6;
  if ((t & 63) == 0) { rs[w] = s; rss[w] = ss; }
  __syncthreads();
  s = rs[0] + rs[1] + rs[2] + rs[3];
  ss = rss[0] + rss[1] + rss[2] + rss[3];
  float mean = s * (1.f / 1024.f);
  float var = ss * (1.f / 1024.f) - mean * mean;
  float rstd = rsqrtf(var + 1e-6f);
  f4v sfv = *(const f4v*)&sf[t * 4];
  f4v cfv = *(const f4v*)&cf[t * 4];
  s4v o;
  #pragma unroll
  for (int i = 0; i < 4; i++)
    o[i] = (short)f2bu((vv[i] - mean) * rstd * (1.f + cfv[i]) + sfv[i]);
  *(s4v*)&h2[(size_t)row * 1024 + t * 4] = o;
}

// ---------------- MFMA flash attention (per-batch local slots; maskless)
__global__ __launch_bounds__(256) void k_attn(
    const bf16* __restrict__ q, const bf16* __restrict__ k, const bf16* __restrict__ vt,
    const int* __restrict__ cnt, bf16* __restrict__ att)
{
  int bh = blockIdx.y, b = bh >> 4, hh = bh & 15;
  int cntb = cnt[b];
  if ((int)blockIdx.x * 128 >= cntb) return;
  int t = threadIdx.x, w = t >> 6, lane = t & 63;
  int fr = lane & 15, g = lane >> 4;
  int qw = blockIdx.x * 128 + w * 32;
  const size_t ho = (size_t)bh * (512 * 64);

  __shared__ bf16 Pb[4][32][72];

  s8v qf[2][2];
  #pragma unroll
  for (int mf = 0; mf < 2; mf++)
    #pragma unroll
    for (int kk = 0; kk < 2; kk++)
      qf[mf][kk] = *(const s8v*)(q + ho + (size_t)(qw + mf * 16 + fr) * 64 + kk * 32 + g * 8);

  float mrow[2][4], lsum[2][4];
  f4v oacc[2][4];
  const f4v vzero = {0.f, 0.f, 0.f, 0.f};
  #pragma unroll
  for (int mf = 0; mf < 2; mf++)
    #pragma unroll
    for (int r = 0; r < 4; r++) { mrow[mf][r] = -3.0e38f; lsum[mf][r] = 0.f; }
  #pragma unroll
  for (int mf = 0; mf < 2; mf++)
    #pragma unroll
    for (int nd = 0; nd < 4; nd++) oacc[mf][nd] = vzero;

  int nkt = (cntb + 63) >> 6;
  for (int kt = 0; kt < nkt; kt++) {
    int kb0 = kt * 64;
    f4v sacc[2][4];
    #pragma unroll
    for (int mf = 0; mf < 2; mf++)
      #pragma unroll
      for (int nf = 0; nf < 4; nf++) sacc[mf][nf] = vzero;
    #pragma unroll
    for (int kk = 0; kk < 2; kk++) {
      s8v kf[4];
      #pragma unroll
      for (int nf = 0; nf < 4; nf++)
        kf[nf] = *(const s8v*)(k + ho + (size_t)(kb0 + nf * 16 + fr) * 64 + kk * 32 + g * 8);
      #pragma unroll
      for (int mf = 0; mf < 2; mf++)
        #pragma unroll
        for (int nf = 0; nf < 4; nf++)
          sacc[mf][nf] = __builtin_amdgcn_mfma_f32_16x16x32_bf16(qf[mf][kk], kf[nf], sacc[mf][nf], 0, 0, 0);
    }
    #pragma unroll
    for (int mf = 0; mf < 2; mf++) {
      #pragma unroll
      for (int r = 0; r < 4; r++) {
        float mx = -3.0e38f;
        #pragma unroll
        for (int nf = 0; nf < 4; nf++) {
          float s = sacc[mf][nf][r] * TPINV;
          if (kb0 + nf * 16 + fr >= cntb) s = -1.0e30f;
          sacc[mf][nf][r] = s;
          mx = fmaxf(mx, s);
        }
        mx = fmaxf(mx, __shfl_xor(mx, 1));
        mx = fmaxf(mx, __shfl_xor(mx, 2));
        mx = fmaxf(mx, __shfl_xor(mx, 4));
        mx = fmaxf(mx, __shfl_xor(mx, 8));
        float mnew = fmaxf(mrow[mf][r], mx);
        float corr = __expf(mrow[mf][r] - mnew);
        mrow[mf][r] = mnew;
        float ps = 0.f;
        #pragma unroll
        for (int nf = 0; nf < 4; nf++) {
          float p = __expf(sacc[mf][nf][r] - mnew);
          ps += p;
          Pb[w][mf * 16 + g * 4 + r][nf * 16 + fr] = __float2bfloat16(p);
        }
        lsum[mf][r] = lsum[mf][r] * corr + ps;
        #pragma unroll
        for (int nd = 0; nd < 4; nd++) oacc[mf][nd][r] *= corr;
      }
    }
    #pragma unroll
    for (int kk = 0; kk < 2; kk++) {
      s8v pf[2], vf[4];
      #pragma unroll
      for (int mf = 0; mf < 2; mf++)
        pf[mf] = *(const s8v*)&Pb[w][mf * 16 + fr][kk * 32 + g * 8];
      #pragma unroll
      for (int nd = 0; nd < 4; nd++)
        vf[nd] = *(const s8v*)(vt + ho + (size_t)(nd * 16 + fr) * 512 + kb0 + kk * 32 + g * 8);
      #pragma unroll
      for (int mf = 0; mf < 2; mf++)
        #pragma unroll
        for (int nd = 0; nd < 4; nd++)
          oacc[mf][nd] = __builtin_amdgcn_mfma_f32_16x16x32_bf16(pf[mf], vf[nd], oacc[mf][nd], 0, 0, 0);
    }
  }
  float inv[2][4];
  #pragma unroll
  for (int mf = 0; mf < 2; mf++)
    #pragma unroll
    for (int r = 0; r < 4; r++) {
      float ls = lsum[mf][r];
      ls += __shfl_xor(ls, 1);
      ls += __shfl_xor(ls, 2);
      ls += __shfl_xor(ls, 4);
      ls += __shfl_xor(ls, 8);
      inv[mf][r] = 1.f / ls;
    }
  #pragma unroll
  for (int mf = 0; mf < 2; mf++)
    #pragma unroll
    for (int nd = 0; nd < 4; nd++)
      #pragma unroll
      for (int r = 0; r < 4; r++) {
        int row = qw + mf * 16 + g * 4 + r;
        att[(size_t)(b * 512 + row) * 1024 + hh * 64 + nd * 16 + fr] =
            __float2bfloat16(oacc[mf][nd][r] * inv[mf][r]);
      }
}

// ---------------- m97-structure GEMM, globally-compacted M, optional K-slice.
// EPI: 0=QKV store (Q,K:(b,h,slot,D); V:(b,h,D,slot)), 1=selu+bias->bf16,
//      2=residual+gate (x f32 in/out), 3=bias->f32, 4=f32 partial (split-K)
template <int EPI, int BN>
__global__ __launch_bounds__(256) void k_gemm(
    const bf16* __restrict__ A, const bf16* __restrict__ W,
    const float* __restrict__ bias, int Kst, int kLen, int Ncols,
    const int* __restrict__ cnt, const int* __restrict__ start, const int* __restrict__ t2b,
    bf16* __restrict__ outb, float* __restrict__ outf,
    float* __restrict__ xio, const float* __restrict__ gfb)
{
  constexpr int FN = BN / 32;
  constexpr int NW = BN / 32;
  __shared__ bf16 As[128][64];
  __shared__ bf16 Ws[BN][64];
  int t = threadIdx.x, lane = t & 63, w = t >> 6;
  int wr = w >> 1, wc = w & 1;
  int m0 = blockIdx.y * 128, n0 = blockIdx.x * BN;
  if (m0 >= start[8]) return;
  int kOff = blockIdx.z * kLen;
  int fr = lane & 15, g = lane >> 4;

  const bf16* Abase = A + (size_t)m0 * Kst + kOff;
  const bf16* Wbase = W + (size_t)n0 * Kst + kOff;

  const f4v vzero = {0.f, 0.f, 0.f, 0.f};
  f4v acc[4][FN];
  #pragma unroll
  for (int i = 0; i < 4; i++)
    #pragma unroll
    for (int j = 0; j < FN; j++) acc[i][j] = vzero;

  int nkt = kLen >> 6;
  for (int kt = 0; kt < nkt; kt++) {
    int k0 = kt << 6;
    __syncthreads();
    #pragma unroll
    for (int i = 0; i < 4; i++) {
      int off = w * 4096 + i * 1024 + lane * 16;
      int row = off >> 7, ce = (off & 127) >> 1;
      gl16(Abase + (size_t)row * Kst + k0 + ce, (char*)As + w * 4096 + i * 1024);
    }
    #pragma unroll
    for (int i = 0; i < NW; i++) {
      int off = w * (NW * 1024) + i * 1024 + lane * 16;
      int row = off >> 7, ce = (off & 127) >> 1;
      gl16(Wbase + (size_t)row * Kst + k0 + ce, (char*)Ws + w * (NW * 1024) + i * 1024);
    }
    __syncthreads();
    #pragma unroll
    for (int kk = 0; kk < 2; kk++) {
      s8v af[4], bfr[FN];
      #pragma unroll
      for (int mf = 0; mf < 4; mf++)
        af[mf] = *(const s8v*)&As[wr * 64 + mf * 16 + fr][kk * 32 + g * 8];
      #pragma unroll
      for (int nf = 0; nf < FN; nf++)
        bfr[nf] = *(const s8v*)&Ws[wc * (BN / 2) + nf * 16 + fr][kk * 32 + g * 8];
      #pragma unroll
      for (int mf = 0; mf < 4; mf++)
        #pragma unroll
        for (int nf = 0; nf < FN; nf++)
          acc[mf][nf] = __builtin_amdgcn_mfma_f32_16x16x32_bf16(af[mf], bfr[nf], acc[mf][nf], 0, 0, 0);
    }
  }

  int tb = t2b[m0 >> 7];
  int sb = start[tb];
  int rq = (lane >> 4) * 4;
  #pragma unroll
  for (int mf = 0; mf < 4; mf++) {
    #pragma unroll
    for (int nf = 0; nf < FN; nf++) {
      int row0 = m0 + wr * 64 + mf * 16 + rq;
      int col = n0 + wc * (BN / 2) + nf * 16 + fr;
      if (EPI == 0) {
        int sel = col >> 10, cl = col & 1023;
        int nn = row0 - sb;
        int h2 = cl >> 6, dd = cl & 63;
        if (sel == 2) {
          s4v o4;
          #pragma unroll
          for (int r = 0; r < 4; r++) o4[r] = (short)f2bu(acc[mf][nf][r]);
          *(s4v*)&outb[(size_t)2 * 4194304 + (((size_t)tb * 16 + h2) * 64 + dd) * 512 + nn] = o4;
        } else {
          #pragma unroll
          for (int r = 0; r < 4; r++)
            outb[(size_t)sel * 4194304 + (((size_t)tb * 16 + h2) * 512 + (nn + r)) * 64 + dd] =
                __float2bfloat16(acc[mf][nf][r]);
        }
      } else {
        #pragma unroll
        for (int r = 0; r < 4; r++) {
          int row = row0 + r;
          float val = acc[mf][nf][r];
          if (EPI == 1) {
            outb[(size_t)row * Ncols + col] = __float2bfloat16(seluf(val + bias[col]));
          } else if (EPI == 2) {
            size_t idx = (size_t)row * 1024 + col;
            xio[idx] = xio[idx] + gfb[(size_t)tb * 6144 + col] * (val + bias[col]);
          } else if (EPI == 3) {
            outf[(size_t)row * 1024 + col] = val + bias[col];
          } else {
            outf[((size_t)blockIdx.z * 4096 + row) * 1024 + col] = val;
          }
        }
      }
    }
  }
}

// ---------------- split-K combine for FFN2: x += gf * (sum parts + bias)
__global__ __launch_bounds__(256) void k_comb(
    const float* __restrict__ part, const float* __restrict__ bias,
    const float* __restrict__ m6b, float* __restrict__ x,
    const int* __restrict__ cnt, const int* __restrict__ start, const int* __restrict__ t2b)
{
  int row = blockIdx.x, t = threadIdx.x;
  if (row >= start[8]) return;
  int tb = t2b[row >> 7], slot = row - start[tb];
  if (slot >= cnt[tb]) return;
  size_t o = (size_t)row * 1024 + t * 4;
  f4v s0 = *(const f4v*)&part[o];
  f4v s1 = *(const f4v*)&part[o + 4194304];
  f4v s2 = *(const f4v*)&part[o + 8388608];
  f4v s3 = *(const f4v*)&part[o + 12582912];
  f4v bv = *(const f4v*)&bias[t * 4];
  f4v gf = *(const f4v*)&m6b[(size_t)tb * 6144 + 5120 + t * 4];
  f4v xv = *(const f4v*)&x[o];
  #pragma unroll
  for (int i = 0; i < 4; i++)
    xv[i] = xv[i] + gf[i] * ((s0[i] + s1[i] + s2[i] + s3[i]) + bv[i]);
  *(f4v*)&x[o] = xv;
}

extern "C" void kernel_launch(void* const* d_in, const int* in_sizes, int n_in,
                              void* d_out, int out_size, void* d_ws, size_t ws_size,
                              hipStream_t stream)
{
  const float* x_in  = (const float*)d_in[0];
  const float* tim   = (const float*)d_in[1];
  const float* lab   = (const float*)d_in[2];
  const float* xmask = (const float*)d_in[3];
  const float* Wl  = (const float*)d_in[4];
  const float* bl  = (const float*)d_in[5];
  const float* Wq  = (const float*)d_in[6];
  const float* Wk  = (const float*)d_in[7];
  const float* Wv  = (const float*)d_in[8];
  const float* W1  = (const float*)d_in[9];
  const float* b1  = (const float*)d_in[10];
  const float* W2  = (const float*)d_in[11];
  const float* b2  = (const float*)d_in[12];
  const float* Wm  = (const float*)d_in[13];
  const float* bm  = (const float*)d_in[14];
  const float* Wf  = (const float*)d_in[15];
  const float* bfp = (const float*)d_in[16];
  const float* Wmf = (const float*)d_in[17];
  const float* bmf = (const float*)d_in[18];

  char* ws = (char*)d_ws;
  float* x     = (float*)(ws + 0);          // 16777216 B (global compacted)
  float* cs    = (float*)(ws + 16777216);   // 32768 B
  float* mAll  = (float*)(ws + 16809984);   // 1572864 B  [L][B][6144]
  float* m2v   = (float*)(ws + 18382848);   // 65536 B    [B][2048]
  bf16*  h     = (bf16*)(ws + 18448384);    // 8388608 B
  bf16*  qb    = (bf16*)(ws + 26836992);    // 8388608 B  (B,H,slot,D)
  bf16*  kb    = (bf16*)(ws + 35225600);    // 8388608 B  (B,H,slot,D)
  bf16*  vb    = (bf16*)(ws + 43614208);    // 8388608 B  (B,H,D,slot) V^T
  bf16*  att   = (bf16*)(ws + 52002816);    // 8388608 B  (B,slot,C)
  bf16*  f1    = (bf16*)(ws + 60391424);    // 33554432 B (4096 x 4096)
  bf16*  wqkvb = (bf16*)(ws + 93945856);    // 6291456 B  [3072][1024]
  bf16*  w1b   = (bf16*)(ws + 100237312);   // 8388608 B  [4096][1024]
  bf16*  w2b   = (bf16*)(ws + 108625920);   // 8388608 B  [1024][4096]
  bf16*  wfb   = (bf16*)(ws + 117014528);   // 2097152 B  [1024][1024]
  float* ffin  = (float*)(ws + 119111680);  // 16777216 B
  int*   idxb  = (int*)(ws + 135888896);    // 16384 B
  int*   posb  = (int*)(ws + 135905280);    // 16384 B
  int*   cntb  = (int*)(ws + 135921664);    // 64 B
  int*   strtb = (int*)(ws + 135921728);    // 64 B (start[9])
  int*   t2bb  = (int*)(ws + 135921792);    // 128 B (t2b[32])
  float* part  = (float*)(ws + 135921920);  // 67108864 B (4 x 4096 x 1024 f32)

  k_compact<<<1, 512, 0, stream>>>(xmask, idxb, posb, cntb, strtb, t2bb);
  k_gather<<<4096, 256, 0, stream>>>(x_in, idxb, cntb, strtb, t2bb, x);

  k_cond<<<8, 256, 0, stream>>>(tim, lab, Wl, bl, cs);
  k_small<<<12288, 256, 0, stream>>>(cs, Wm, bm, mAll, 49152, 0);
  k_small<<<512, 256, 0, stream>>>(cs, Wmf, bmf, m2v, 2048, 1);

  for (int l = 0; l < 8; l++) {
    const float* m6b = mAll + (size_t)l * 8 * 6144;
    k_convall<<<5632, 256, 0, stream>>>(Wq + (size_t)l * 1048576, Wk + (size_t)l * 1048576,
                                        Wv + (size_t)l * 1048576, W1 + (size_t)l * 4194304,
                                        W2 + (size_t)l * 4194304, wqkvb, w1b, w2b);

    k_lnmod<<<4096, 256, 0, stream>>>(x, m6b + 0, m6b + 1024, 6144, cntb, strtb, t2bb, h);
    k_gemm<0, 128><<<dim3(24, 32), 256, 0, stream>>>(h, wqkvb, nullptr, 1024, 1024, 3072,
                                                     cntb, strtb, t2bb,
                                                     qb, nullptr, nullptr, nullptr);
    k_attn<<<dim3(4, 128), 256, 0, stream>>>(qb, kb, vb, cntb, att);
    k_resid<<<4096, 256, 0, stream>>>(x, att, m6b, cntb, strtb, t2bb, h);
    k_gemm<1, 128><<<dim3(32, 32), 256, 0, stream>>>(h, w1b, b1 + l * 4096, 1024, 1024, 4096,
                                                     cntb, strtb, t2bb,
                                                     f1, nullptr, nullptr, nullptr);
    k_gemm<4, 64><<<dim3(16, 32, 4), 256, 0, stream>>>(f1, w2b, nullptr, 4096, 1024, 1024,
                                                       cntb, strtb, t2bb,
                                                       nullptr, part, nullptr, nullptr);
    k_comb<<<4096, 256, 0, stream>>>(part, b2 + l * 1024, m6b, x, cntb, strtb, t2bb);
  }

  k_conv<<<512, 256, 0, stream>>>(Wf, wfb, 131072);
  k_lnmod<<<4096, 256, 0, stream>>>(x, m2v + 0, m2v + 1024, 2048, cntb, strtb, t2bb, h);
  k_gemm<3, 64><<<dim3(16, 32), 256, 0, stream>>>(h, wfb, bfp, 1024, 1024, 1024,
                                                  cntb, strtb, t2bb,
                                                  nullptr, ffin, nullptr, nullptr);
  k_scatter<<<4096, 256, 0, stream>>>(ffin, posb, strtb, (float*)d_out);
}

// Round 6
// 1629.743 us; speedup vs baseline: 3.4721x; 1.0062x over previous
//
#include <hip/hip_runtime.h>
#include <hip/hip_bf16.h>
#include <cstddef>

#define DEVI __device__ __forceinline__

typedef __attribute__((ext_vector_type(4))) float f4v;
typedef __attribute__((ext_vector_type(8))) short s8v;
typedef __attribute__((ext_vector_type(4))) short s4v;

using bf16 = __hip_bfloat16;

// L=8, B=8, N=512, C=1024, H=16, D=64
constexpr float SELU_A = 1.6732632423543772f;
constexpr float SELU_S = 1.0507009873554805f;
constexpr float TPINV  = 0.08838834764831845f; // 1/sqrt(2*D)

DEVI float bfbits(short s) { return __uint_as_float(((unsigned)(unsigned short)s) << 16); }
DEVI unsigned short f2bu(float f) {
  bf16 h = __float2bfloat16(f);
  return __builtin_bit_cast(unsigned short, h);
}
DEVI float seluf(float x) { return x > 0.f ? SELU_S * x : SELU_S * SELU_A * (__expf(x) - 1.f); }

DEVI void gl16(const void* g, void* l) {
  __builtin_amdgcn_global_load_lds((__attribute__((address_space(1))) void*)g,
                                   (__attribute__((address_space(3))) void*)l, 16, 0, 0);
}

DEVI void conv8(const float* __restrict__ src, bf16* __restrict__ dst) {
  f4v a = *(const f4v*)src;
  f4v b = *(const f4v*)(src + 4);
  s8v o;
  #pragma unroll
  for (int j = 0; j < 4; j++) { o[j] = (short)f2bu(a[j]); o[4 + j] = (short)f2bu(b[j]); }
  *(s8v*)dst = o;
}

// ---------------- mask compaction: global 128-aligned packing.
__global__ void k_compact(const float* __restrict__ xm, int* __restrict__ idx,
                          int* __restrict__ pos, int* __restrict__ cnt,
                          int* __restrict__ start, int* __restrict__ t2b)
{
  int t = threadIdx.x;           // 512 threads, wave w = batch w
  int b = t >> 6, lane = t & 63;
  __shared__ int scnt[8];
  int base = b * 512 + lane * 8;
  int mb[8]; int lc = 0;
  #pragma unroll
  for (int i = 0; i < 8; i++) { mb[i] = (xm[base + i] != 0.f) ? 1 : 0; lc += mb[i]; }
  int s = lc;
  #pragma unroll
  for (int o = 1; o < 64; o <<= 1) { int tt = __shfl_up(s, o); if (lane >= o) s += tt; }
  int run = s - lc;
  #pragma unroll
  for (int i = 0; i < 8; i++) {
    int n = lane * 8 + i;
    if (mb[i]) { idx[b * 512 + run] = n; pos[b * 512 + n] = run; run++; }
    else pos[b * 512 + n] = -1;
  }
  if (lane == 63) scnt[b] = s;
  __syncthreads();
  if (t == 0) {
    int st = 0, tile = 0;
    for (int bb = 0; bb < 8; bb++) {
      cnt[bb] = scnt[bb];
      start[bb] = st;
      int nt = (scnt[bb] + 127) >> 7;
      for (int k = 0; k < nt; k++) t2b[tile++] = bb;
      st += nt * 128;
    }
    start[8] = st;
    for (; tile < 32; tile++) t2b[tile] = 0;
  }
}

// ---------------- gather x into globally-compacted layout (tails zeroed)
__global__ __launch_bounds__(256) void k_gather(const float* __restrict__ xin,
    const int* __restrict__ idx, const int* __restrict__ cnt,
    const int* __restrict__ start, const int* __restrict__ t2b,
    float* __restrict__ xc)
{
  int row = blockIdx.x, t = threadIdx.x;
  if (row >= start[8]) return;
  int tb = t2b[row >> 7], slot = row - start[tb];
  f4v v = {0.f, 0.f, 0.f, 0.f};
  if (slot < cnt[tb])
    v = *(const f4v*)&xin[((size_t)tb * 512 + idx[tb * 512 + slot]) * 1024 + t * 4];
  *(f4v*)&xc[(size_t)row * 1024 + t * 4] = v;
}

// ---------------- scatter final rows back; dead rows = 0
__global__ __launch_bounds__(256) void k_scatter(const float* __restrict__ ffin,
    const int* __restrict__ pos, const int* __restrict__ start, float* __restrict__ out)
{
  int row = blockIdx.x, t = threadIdx.x, b = row >> 9;
  int p = pos[row];
  f4v v = {0.f, 0.f, 0.f, 0.f};
  if (p >= 0) v = *(const f4v*)&ffin[(size_t)(start[b] + p) * 1024 + t * 4];
  *(f4v*)&out[(size_t)row * 1024 + t * 4] = v;
}

// ---------------- per-layer merged weight conversion (prologue, layer 0)
__global__ __launch_bounds__(256) void k_convall(
    const float* __restrict__ wq, const float* __restrict__ wk, const float* __restrict__ wv,
    const float* __restrict__ w1, const float* __restrict__ w2,
    bf16* __restrict__ wqkvb, bf16* __restrict__ w1b, bf16* __restrict__ w2b)
{
  int i = blockIdx.x * 256 + threadIdx.x;
  if (i < 393216) {
    int o = i * 8;
    int row = o >> 10, col = o & 1023;
    int sel = row >> 10, sr = row & 1023;
    conv8((sel == 0 ? wq : sel == 1 ? wk : wv) + (size_t)sr * 1024 + col, wqkvb + o);
  } else if (i < 917504) {
    size_t o = (size_t)(i - 393216) * 8;
    conv8(w1 + o, w1b + o);
  } else if (i < 1441792) {
    size_t o = (size_t)(i - 917504) * 8;
    conv8(w2 + o, w2b + o);
  }
}

// ---------------- conditioning
__global__ void k_cond(const float* __restrict__ tim, const float* __restrict__ lab,
                       const float* __restrict__ Wl, const float* __restrict__ bl,
                       float* __restrict__ cs)
{
  int b = blockIdx.x, t = threadIdx.x;
  float l0 = lab[b * 2 + 0], l1 = lab[b * 2 + 1], tv = tim[b];
  #pragma unroll
  for (int i = 0; i < 4; i++) {
    int j = t + 256 * i;
    float e = powf(10000.f, (2.f * (float)j) * (1.f / 1024.f));
    float arg = tv / e;
    float te = ((j & 1) == 0) ? sinf(arg) : cosf(arg);
    float c = l0 * Wl[j * 2 + 0] + l1 * Wl[j * 2 + 1] + bl[j] + te;
    cs[b * 1024 + j] = seluf(c);
  }
}

// ---------------- small matvec batch
__global__ __launch_bounds__(256) void k_small(
    const float* __restrict__ cs, const float* __restrict__ W, const float* __restrict__ bias,
    float* __restrict__ out, int O, int mode)
{
  __shared__ float cls[8192];
  int t = threadIdx.x;
  #pragma unroll
  for (int i = 0; i < 8; i++)
    *(f4v*)&cls[i * 1024 + t * 4] = *(const f4v*)&cs[i * 1024 + t * 4];
  __syncthreads();
  int w = t >> 6, l = t & 63;
  int o = blockIdx.x * 4 + w;
  if (o >= O) return;
  float acc[8] = {0.f, 0.f, 0.f, 0.f, 0.f, 0.f, 0.f, 0.f};
  const float* Wr = W + (size_t)o * 1024;
  for (int i = 0; i < 16; i++) {
    int k = i * 64 + l;
    float wv = Wr[k];
    #pragma unroll
    for (int b = 0; b < 8; b++) acc[b] += wv * cls[b * 1024 + k];
  }
  #pragma unroll
  for (int b = 0; b < 8; b++) {
    #pragma unroll
    for (int off = 32; off; off >>= 1) acc[b] += __shfl_xor(acc[b], off);
  }
  float bv = bias[o];
  #pragma unroll
  for (int b = 0; b < 8; b++) {
    if (l == b) {
      float val = acc[b] + bv;
      size_t dst;
      if (mode == 0) { int ll = o / 6144, ft = o - ll * 6144; dst = ((size_t)ll * 8 + b) * 6144 + ft; }
      else dst = (size_t)b * 2048 + o;
      out[dst] = val;
    }
  }
}

// ---------------- row LN + modulate -> bf16 (layer 0 only; zeroes tails)
__global__ __launch_bounds__(256) void k_lnmod(
    const float* __restrict__ x, const float* __restrict__ shiftB, const float* __restrict__ scaleB,
    int bstride, const int* __restrict__ cnt, const int* __restrict__ start,
    const int* __restrict__ t2b, bf16* __restrict__ out)
{
  int row = blockIdx.x, t = threadIdx.x;
  if (row >= start[8]) return;
  int tb = t2b[row >> 7], slot = row - start[tb];
  if (slot >= cnt[tb]) {
    s4v z = {0, 0, 0, 0};
    *(s4v*)&out[(size_t)row * 1024 + t * 4] = z;
    return;
  }
  const float* xr = x + (size_t)row * 1024;
  f4v v = *(const f4v*)&xr[t * 4];
  float s = v[0] + v[1] + v[2] + v[3];
  float ss = v[0]*v[0] + v[1]*v[1] + v[2]*v[2] + v[3]*v[3];
  #pragma unroll
  for (int off = 32; off; off >>= 1) { s += __shfl_xor(s, off); ss += __shfl_xor(ss, off); }
  __shared__ float rs[4], rss[4];
  int w = t >> 6;
  if ((t & 63) == 0) { rs[w] = s; rss[w] = ss; }
  __syncthreads();
  s = rs[0] + rs[1] + rs[2] + rs[3];
  ss = rss[0] + rss[1] + rss[2] + rss[3];
  float mean = s * (1.f / 1024.f);
  float var = ss * (1.f / 1024.f) - mean * mean;
  float rstd = rsqrtf(var + 1e-6f);
  f4v sh = *(const f4v*)&shiftB[(size_t)tb * bstride + t * 4];
  f4v sc = *(const f4v*)&scaleB[(size_t)tb * bstride + t * 4];
  s4v o;
  #pragma unroll
  for (int i = 0; i < 4; i++)
    o[i] = (short)f2bu((v[i] - mean) * rstd * (1.f + sc[i]) + sh[i]);
  *(s4v*)&out[(size_t)row * 1024 + t * 4] = o;
}

// ---------------- x += gm*att; h2 = modulate(ln(x), sf, cf) -> bf16 (tails -> 0)
__global__ __launch_bounds__(256) void k_resid(
    float* __restrict__ x, const bf16* __restrict__ att, const float* __restrict__ m6b,
    const int* __restrict__ cnt, const int* __restrict__ start,
    const int* __restrict__ t2b, bf16* __restrict__ h2)
{
  int row = blockIdx.x, t = threadIdx.x;
  if (row >= start[8]) return;
  int tb = t2b[row >> 7], slot = row - start[tb];
  if (slot >= cnt[tb]) {
    s4v z = {0, 0, 0, 0};
    *(s4v*)&h2[(size_t)row * 1024 + t * 4] = z;
    return;
  }
  float* xr = x + (size_t)row * 1024;
  const float* gm = m6b + (size_t)tb * 6144 + 2048;
  const float* sf = m6b + (size_t)tb * 6144 + 3072;
  const float* cf = m6b + (size_t)tb * 6144 + 4096;
  f4v xv = *(const f4v*)&xr[t * 4];
  s4v av = *(const s4v*)&att[((size_t)tb * 512 + slot) * 1024 + t * 4];
  f4v gv = *(const f4v*)&gm[t * 4];
  f4v vv;
  #pragma unroll
  for (int i = 0; i < 4; i++) vv[i] = xv[i] + gv[i] * bfbits(av[i]);
  *(f4v*)&xr[t * 4] = vv;
  float s = vv[0] + vv[1] + vv[2] + vv[3];
  float ss = vv[0]*vv[0] + vv[1]*vv[1] + vv[2]*vv[2] + vv[3]*vv[3];
  #pragma unroll
  for (int off = 32; off; off >>= 1) { s += __shfl_xor(s, off); ss += __shfl_xor(ss, off); }
  __shared__ float rs[4], rss[4];
  int w = t >> 6;
  if ((t & 63) == 0) { rs[w] = s; rss[w] = ss; }
  __syncthreads();
  s = rs[0] + rs[1] + rs[2] + rs[3];
  ss = rss[0] + rss[1] + rss[2] + rss[3];
  float mean = s * (1.f / 1024.f);
  float var = ss * (1.f / 1024.f) - mean * mean;
  float rstd = rsqrtf(var + 1e-6f);
  f4v sfv = *(const f4v*)&sf[t * 4];
  f4v cfv = *(const f4v*)&cf[t * 4];
  s4v o;
  #pragma unroll
  for (int i = 0; i < 4; i++)
    o[i] = (short)f2bu((vv[i] - mean) * rstd * (1.f + cfv[i]) + sfv[i]);
  *(s4v*)&h2[(size_t)row * 1024 + t * 4] = o;
}

// ---------------- MFMA flash attention + fused next-layer weight conversion.
// blockIdx.x < 4: attention (per-batch local slots, maskless).
// blockIdx.x >= 4: convert next layer's weights (mode 0) or Wf (mode 1).
__global__ __launch_bounds__(256) void k_attn(
    const bf16* __restrict__ q, const bf16* __restrict__ k, const bf16* __restrict__ vt,
    const int* __restrict__ cnt, bf16* __restrict__ att,
    const float* __restrict__ nwq, const float* __restrict__ nwk, const float* __restrict__ nwv,
    const float* __restrict__ nw1, const float* __restrict__ nw2,
    bf16* __restrict__ dqkv, bf16* __restrict__ dw1, bf16* __restrict__ dw2, int mode)
{
  if (blockIdx.x >= 4) {
    int cid = (blockIdx.x - 4) * 128 + blockIdx.y;
    int i0 = cid * 256 + threadIdx.x;
    #pragma unroll
    for (int half = 0; half < 2; half++) {
      int j = i0 * 2 + half;
      if (mode == 1) {
        if (j < 131072) conv8(nwq + (size_t)j * 8, dqkv + (size_t)j * 8);
      } else {
        if (j < 393216) {
          int o = j * 8;
          int row = o >> 10, col = o & 1023;
          int sel = row >> 10, sr = row & 1023;
          conv8((sel == 0 ? nwq : sel == 1 ? nwk : nwv) + (size_t)sr * 1024 + col, dqkv + o);
        } else if (j < 917504) {
          size_t o = (size_t)(j - 393216) * 8;
          conv8(nw1 + o, dw1 + o);
        } else {
          size_t o = (size_t)(j - 917504) * 8;
          conv8(nw2 + o, dw2 + o);
        }
      }
    }
    return;
  }

  int bh = blockIdx.y, b = bh >> 4, hh = bh & 15;
  int cntb = cnt[b];
  if ((int)blockIdx.x * 128 >= cntb) return;
  int t = threadIdx.x, w = t >> 6, lane = t & 63;
  int fr = lane & 15, g = lane >> 4;
  int qw = blockIdx.x * 128 + w * 32;
  const size_t ho = (size_t)bh * (512 * 64);

  __shared__ bf16 Pb[4][32][72];

  s8v qf[2][2];
  #pragma unroll
  for (int mf = 0; mf < 2; mf++)
    #pragma unroll
    for (int kk = 0; kk < 2; kk++)
      qf[mf][kk] = *(const s8v*)(q + ho + (size_t)(qw + mf * 16 + fr) * 64 + kk * 32 + g * 8);

  float mrow[2][4], lsum[2][4];
  f4v oacc[2][4];
  const f4v vzero = {0.f, 0.f, 0.f, 0.f};
  #pragma unroll
  for (int mf = 0; mf < 2; mf++)
    #pragma unroll
    for (int r = 0; r < 4; r++) { mrow[mf][r] = -3.0e38f; lsum[mf][r] = 0.f; }
  #pragma unroll
  for (int mf = 0; mf < 2; mf++)
    #pragma unroll
    for (int nd = 0; nd < 4; nd++) oacc[mf][nd] = vzero;

  int nkt = (cntb + 63) >> 6;
  for (int kt = 0; kt < nkt; kt++) {
    int kb0 = kt * 64;
    f4v sacc[2][4];
    #pragma unroll
    for (int mf = 0; mf < 2; mf++)
      #pragma unroll
      for (int nf = 0; nf < 4; nf++) sacc[mf][nf] = vzero;
    #pragma unroll
    for (int kk = 0; kk < 2; kk++) {
      s8v kf[4];
      #pragma unroll
      for (int nf = 0; nf < 4; nf++)
        kf[nf] = *(const s8v*)(k + ho + (size_t)(kb0 + nf * 16 + fr) * 64 + kk * 32 + g * 8);
      #pragma unroll
      for (int mf = 0; mf < 2; mf++)
        #pragma unroll
        for (int nf = 0; nf < 4; nf++)
          sacc[mf][nf] = __builtin_amdgcn_mfma_f32_16x16x32_bf16(qf[mf][kk], kf[nf], sacc[mf][nf], 0, 0, 0);
    }
    #pragma unroll
    for (int mf = 0; mf < 2; mf++) {
      #pragma unroll
      for (int r = 0; r < 4; r++) {
        float mx = -3.0e38f;
        #pragma unroll
        for (int nf = 0; nf < 4; nf++) {
          float s = sacc[mf][nf][r] * TPINV;
          if (kb0 + nf * 16 + fr >= cntb) s = -1.0e30f;
          sacc[mf][nf][r] = s;
          mx = fmaxf(mx, s);
        }
        mx = fmaxf(mx, __shfl_xor(mx, 1));
        mx = fmaxf(mx, __shfl_xor(mx, 2));
        mx = fmaxf(mx, __shfl_xor(mx, 4));
        mx = fmaxf(mx, __shfl_xor(mx, 8));
        float mnew = fmaxf(mrow[mf][r], mx);
        float corr = __expf(mrow[mf][r] - mnew);
        mrow[mf][r] = mnew;
        float ps = 0.f;
        #pragma unroll
        for (int nf = 0; nf < 4; nf++) {
          float p = __expf(sacc[mf][nf][r] - mnew);
          ps += p;
          Pb[w][mf * 16 + g * 4 + r][nf * 16 + fr] = __float2bfloat16(p);
        }
        lsum[mf][r] = lsum[mf][r] * corr + ps;
        #pragma unroll
        for (int nd = 0; nd < 4; nd++) oacc[mf][nd][r] *= corr;
      }
    }
    #pragma unroll
    for (int kk = 0; kk < 2; kk++) {
      s8v pf[2], vf[4];
      #pragma unroll
      for (int mf = 0; mf < 2; mf++)
        pf[mf] = *(const s8v*)&Pb[w][mf * 16 + fr][kk * 32 + g * 8];
      #pragma unroll
      for (int nd = 0; nd < 4; nd++)
        vf[nd] = *(const s8v*)(vt + ho + (size_t)(nd * 16 + fr) * 512 + kb0 + kk * 32 + g * 8);
      #pragma unroll
      for (int mf = 0; mf < 2; mf++)
        #pragma unroll
        for (int nd = 0; nd < 4; nd++)
          oacc[mf][nd] = __builtin_amdgcn_mfma_f32_16x16x32_bf16(pf[mf], vf[nd], oacc[mf][nd], 0, 0, 0);
    }
  }
  float inv[2][4];
  #pragma unroll
  for (int mf = 0; mf < 2; mf++)
    #pragma unroll
    for (int r = 0; r < 4; r++) {
      float ls = lsum[mf][r];
      ls += __shfl_xor(ls, 1);
      ls += __shfl_xor(ls, 2);
      ls += __shfl_xor(ls, 4);
      ls += __shfl_xor(ls, 8);
      inv[mf][r] = 1.f / ls;
    }
  #pragma unroll
  for (int mf = 0; mf < 2; mf++)
    #pragma unroll
    for (int nd = 0; nd < 4; nd++)
      #pragma unroll
      for (int r = 0; r < 4; r++) {
        int row = qw + mf * 16 + g * 4 + r;
        att[(size_t)(b * 512 + row) * 1024 + hh * 64 + nd * 16 + fr] =
            __float2bfloat16(oacc[mf][nd][r] * inv[mf][r]);
      }
}

// ---------------- m97-structure GEMM, globally-compacted M, optional K-slice.
// EPI: 0=QKV store (Q,K:(b,h,slot,D); V:(b,h,D,slot)), 1=selu+bias->bf16,
//      3=bias->f32, 4=bf16 partial (split-K)
template <int EPI, int BN>
__global__ __launch_bounds__(256) void k_gemm(
    const bf16* __restrict__ A, const bf16* __restrict__ W,
    const float* __restrict__ bias, int Kst, int kLen, int Ncols,
    const int* __restrict__ cnt, const int* __restrict__ start, const int* __restrict__ t2b,
    bf16* __restrict__ outb, float* __restrict__ outf)
{
  constexpr int FN = BN / 32;
  constexpr int NW = BN / 32;
  __shared__ bf16 As[128][64];
  __shared__ bf16 Ws[BN][64];
  int t = threadIdx.x, lane = t & 63, w = t >> 6;
  int wr = w >> 1, wc = w & 1;
  int m0 = blockIdx.y * 128, n0 = blockIdx.x * BN;
  if (m0 >= start[8]) return;
  int kOff = blockIdx.z * kLen;
  int fr = lane & 15, g = lane >> 4;

  const bf16* Abase = A + (size_t)m0 * Kst + kOff;
  const bf16* Wbase = W + (size_t)n0 * Kst + kOff;

  const f4v vzero = {0.f, 0.f, 0.f, 0.f};
  f4v acc[4][FN];
  #pragma unroll
  for (int i = 0; i < 4; i++)
    #pragma unroll
    for (int j = 0; j < FN; j++) acc[i][j] = vzero;

  int nkt = kLen >> 6;
  for (int kt = 0; kt < nkt; kt++) {
    int k0 = kt << 6;
    __syncthreads();
    #pragma unroll
    for (int i = 0; i < 4; i++) {
      int off = w * 4096 + i * 1024 + lane * 16;
      int row = off >> 7, ce = (off & 127) >> 1;
      gl16(Abase + (size_t)row * Kst + k0 + ce, (char*)As + w * 4096 + i * 1024);
    }
    #pragma unroll
    for (int i = 0; i < NW; i++) {
      int off = w * (NW * 1024) + i * 1024 + lane * 16;
      int row = off >> 7, ce = (off & 127) >> 1;
      gl16(Wbase + (size_t)row * Kst + k0 + ce, (char*)Ws + w * (NW * 1024) + i * 1024);
    }
    __syncthreads();
    #pragma unroll
    for (int kk = 0; kk < 2; kk++) {
      s8v af[4], bfr[FN];
      #pragma unroll
      for (int mf = 0; mf < 4; mf++)
        af[mf] = *(const s8v*)&As[wr * 64 + mf * 16 + fr][kk * 32 + g * 8];
      #pragma unroll
      for (int nf = 0; nf < FN; nf++)
        bfr[nf] = *(const s8v*)&Ws[wc * (BN / 2) + nf * 16 + fr][kk * 32 + g * 8];
      #pragma unroll
      for (int mf = 0; mf < 4; mf++)
        #pragma unroll
        for (int nf = 0; nf < FN; nf++)
          acc[mf][nf] = __builtin_amdgcn_mfma_f32_16x16x32_bf16(af[mf], bfr[nf], acc[mf][nf], 0, 0, 0);
    }
  }

  int tb = t2b[m0 >> 7];
  int sb = start[tb];
  int rq = (lane >> 4) * 4;
  #pragma unroll
  for (int mf = 0; mf < 4; mf++) {
    #pragma unroll
    for (int nf = 0; nf < FN; nf++) {
      int row0 = m0 + wr * 64 + mf * 16 + rq;
      int col = n0 + wc * (BN / 2) + nf * 16 + fr;
      if (EPI == 0) {
        int sel = col >> 10, cl = col & 1023;
        int nn = row0 - sb;
        int h2 = cl >> 6, dd = cl & 63;
        if (sel == 2) {
          s4v o4;
          #pragma unroll
          for (int r = 0; r < 4; r++) o4[r] = (short)f2bu(acc[mf][nf][r]);
          *(s4v*)&outb[(size_t)2 * 4194304 + (((size_t)tb * 16 + h2) * 64 + dd) * 512 + nn] = o4;
        } else {
          #pragma unroll
          for (int r = 0; r < 4; r++)
            outb[(size_t)sel * 4194304 + (((size_t)tb * 16 + h2) * 512 + (nn + r)) * 64 + dd] =
                __float2bfloat16(acc[mf][nf][r]);
        }
      } else {
        #pragma unroll
        for (int r = 0; r < 4; r++) {
          int row = row0 + r;
          float val = acc[mf][nf][r];
          if (EPI == 1) {
            outb[(size_t)row * Ncols + col] = __float2bfloat16(seluf(val + bias[col]));
          } else if (EPI == 3) {
            outf[(size_t)row * 1024 + col] = val + bias[col];
          } else {
            outb[(size_t)blockIdx.z * 4194304 + (size_t)row * 1024 + col] = __float2bfloat16(val);
          }
        }
      }
    }
  }
}

// ---------------- split-K combine + residual + NEXT-layer LN/modulate -> h
__global__ __launch_bounds__(256) void k_comb(
    const bf16* __restrict__ part, const float* __restrict__ bias,
    const float* __restrict__ gfb, const float* __restrict__ shiftN,
    const float* __restrict__ scaleN, int strideN,
    float* __restrict__ x, const int* __restrict__ cnt, const int* __restrict__ start,
    const int* __restrict__ t2b, bf16* __restrict__ h)
{
  int row = blockIdx.x, t = threadIdx.x;
  if (row >= start[8]) return;
  int tb = t2b[row >> 7], slot = row - start[tb];
  if (slot >= cnt[tb]) return;  // h tail slots stay zero (written once by layer-0 lnmod)
  size_t o = (size_t)row * 1024 + t * 4;
  s4v p0 = *(const s4v*)&part[o];
  s4v p1 = *(const s4v*)&part[o + 4194304];
  s4v p2 = *(const s4v*)&part[o + 8388608];
  s4v p3 = *(const s4v*)&part[o + 12582912];
  f4v bv = *(const f4v*)&bias[t * 4];
  f4v gf = *(const f4v*)&gfb[(size_t)tb * 6144 + t * 4];
  f4v xv = *(const f4v*)&x[o];
  f4v vv;
  #pragma unroll
  for (int i = 0; i < 4; i++)
    vv[i] = xv[i] + gf[i] * ((bfbits(p0[i]) + bfbits(p1[i]) + bfbits(p2[i]) + bfbits(p3[i])) + bv[i]);
  *(f4v*)&x[o] = vv;
  float s = vv[0] + vv[1] + vv[2] + vv[3];
  float ss = vv[0]*vv[0] + vv[1]*vv[1] + vv[2]*vv[2] + vv[3]*vv[3];
  #pragma unroll
  for (int off = 32; off; off >>= 1) { s += __shfl_xor(s, off); ss += __shfl_xor(ss, off); }
  __shared__ float rs[4], rss[4];
  int w = t >> 6;
  if ((t & 63) == 0) { rs[w] = s; rss[w] = ss; }
  __syncthreads();
  s = rs[0] + rs[1] + rs[2] + rs[3];
  ss = rss[0] + rss[1] + rss[2] + rss[3];
  float mean = s * (1.f / 1024.f);
  float var = ss * (1.f / 1024.f) - mean * mean;
  float rstd = rsqrtf(var + 1e-6f);
  f4v sh = *(const f4v*)&shiftN[(size_t)tb * strideN + t * 4];
  f4v sc = *(const f4v*)&scaleN[(size_t)tb * strideN + t * 4];
  s4v ho;
  #pragma unroll
  for (int i = 0; i < 4; i++)
    ho[i] = (short)f2bu((vv[i] - mean) * rstd * (1.f + sc[i]) + sh[i]);
  *(s4v*)&h[(size_t)row * 1024 + t * 4] = ho;
}

extern "C" void kernel_launch(void* const* d_in, const int* in_sizes, int n_in,
                              void* d_out, int out_size, void* d_ws, size_t ws_size,
                              hipStream_t stream)
{
  const float* x_in  = (const float*)d_in[0];
  const float* tim   = (const float*)d_in[1];
  const float* lab   = (const float*)d_in[2];
  const float* xmask = (const float*)d_in[3];
  const float* Wl  = (const float*)d_in[4];
  const float* bl  = (const float*)d_in[5];
  const float* Wq  = (const float*)d_in[6];
  const float* Wk  = (const float*)d_in[7];
  const float* Wv  = (const float*)d_in[8];
  const float* W1  = (const float*)d_in[9];
  const float* b1  = (const float*)d_in[10];
  const float* W2  = (const float*)d_in[11];
  const float* b2  = (const float*)d_in[12];
  const float* Wm  = (const float*)d_in[13];
  const float* bm  = (const float*)d_in[14];
  const float* Wf  = (const float*)d_in[15];
  const float* bfp = (const float*)d_in[16];
  const float* Wmf = (const float*)d_in[17];
  const float* bmf = (const float*)d_in[18];

  char* ws = (char*)d_ws;
  float* x     = (float*)(ws + 0);          // 16777216 B (global compacted)
  float* cs    = (float*)(ws + 16777216);   // 32768 B
  float* mAll  = (float*)(ws + 16809984);   // 1572864 B  [L][B][6144]
  float* m2v   = (float*)(ws + 18382848);   // 65536 B    [B][2048]
  bf16*  h     = (bf16*)(ws + 18448384);    // 8388608 B
  bf16*  qb    = (bf16*)(ws + 26836992);    // 8388608 B  (B,H,slot,D)
  bf16*  kb    = (bf16*)(ws + 35225600);    // 8388608 B  (B,H,slot,D)
  bf16*  vb    = (bf16*)(ws + 43614208);    // 8388608 B  (B,H,D,slot) V^T
  bf16*  att   = (bf16*)(ws + 52002816);    // 8388608 B  (B,slot,C)
  bf16*  f1    = (bf16*)(ws + 60391424);    // 33554432 B (4096 x 4096)
  bf16*  wqkv0 = (bf16*)(ws + 93945856);    // 6291456 B
  bf16*  w1b0  = (bf16*)(ws + 100237312);   // 8388608 B
  bf16*  w2b0  = (bf16*)(ws + 108625920);   // 8388608 B
  bf16*  wfb   = (bf16*)(ws + 117014528);   // 2097152 B
  float* ffin  = (float*)(ws + 119111680);  // 16777216 B
  int*   idxb  = (int*)(ws + 135888896);    // 16384 B
  int*   posb  = (int*)(ws + 135905280);    // 16384 B
  int*   cntb  = (int*)(ws + 135921664);    // 64 B
  int*   strtb = (int*)(ws + 135921728);    // 64 B (start[9])
  int*   t2bb  = (int*)(ws + 135921792);    // 128 B (t2b[32])
  bf16*  part  = (bf16*)(ws + 135921920);   // 33554432 B (4 x 4096 x 1024 bf16)
  bf16*  wqkv1 = (bf16*)(ws + 169476352);   // 6291456 B
  bf16*  w1b1  = (bf16*)(ws + 175767808);   // 8388608 B
  bf16*  w2b1  = (bf16*)(ws + 184156416);   // 8388608 B  (ends 192545024)

  bf16* wqkvS[2] = { wqkv0, wqkv1 };
  bf16* w1S[2]   = { w1b0, w1b1 };
  bf16* w2S[2]   = { w2b0, w2b1 };

  k_compact<<<1, 512, 0, stream>>>(xmask, idxb, posb, cntb, strtb, t2bb);
  k_gather<<<4096, 256, 0, stream>>>(x_in, idxb, cntb, strtb, t2bb, x);

  k_cond<<<8, 256, 0, stream>>>(tim, lab, Wl, bl, cs);
  k_small<<<12288, 256, 0, stream>>>(cs, Wm, bm, mAll, 49152, 0);
  k_small<<<512, 256, 0, stream>>>(cs, Wmf, bmf, m2v, 2048, 1);

  k_convall<<<5632, 256, 0, stream>>>(Wq, Wk, Wv, W1, W2, wqkv0, w1b0, w2b0);
  k_lnmod<<<4096, 256, 0, stream>>>(x, mAll + 0, mAll + 1024, 6144, cntb, strtb, t2bb, h);

  for (int l = 0; l < 8; l++) {
    const float* m6b = mAll + (size_t)l * 49152;
    int sel = l & 1, nsel = sel ^ 1;
    int last = (l == 7);

    k_gemm<0, 128><<<dim3(24, 32), 256, 0, stream>>>(h, wqkvS[sel], nullptr, 1024, 1024, 3072,
                                                     cntb, strtb, t2bb, qb, nullptr);
    if (!last) {
      k_attn<<<dim3(26, 128), 256, 0, stream>>>(qb, kb, vb, cntb, att,
          Wq + (size_t)(l + 1) * 1048576, Wk + (size_t)(l + 1) * 1048576,
          Wv + (size_t)(l + 1) * 1048576, W1 + (size_t)(l + 1) * 4194304,
          W2 + (size_t)(l + 1) * 4194304,
          wqkvS[nsel], w1S[nsel], w2S[nsel], 0);
    } else {
      k_attn<<<dim3(26, 128), 256, 0, stream>>>(qb, kb, vb, cntb, att,
          Wf, Wf, Wf, Wf, Wf, wfb, wfb, wfb, 1);
    }
    k_resid<<<4096, 256, 0, stream>>>(x, att, m6b, cntb, strtb, t2bb, h);
    k_gemm<1, 128><<<dim3(32, 32), 256, 0, stream>>>(h, w1S[sel], b1 + l * 4096, 1024, 1024, 4096,
                                                     cntb, strtb, t2bb, f1, nullptr);
    k_gemm<4, 128><<<dim3(8, 32, 4), 256, 0, stream>>>(f1, w2S[sel], nullptr, 4096, 1024, 1024,
                                                       cntb, strtb, t2bb, part, nullptr);
    const float* nShift = last ? m2v : (mAll + (size_t)(l + 1) * 49152);
    const float* nScale = last ? (m2v + 1024) : (mAll + (size_t)(l + 1) * 49152 + 1024);
    int nStride = last ? 2048 : 6144;
    k_comb<<<4096, 256, 0, stream>>>(part, b2 + l * 1024, m6b + 5120,
                                     nShift, nScale, nStride,
                                     x, cntb, strtb, t2bb, h);
  }

  k_gemm<3, 64><<<dim3(16, 32), 256, 0, stream>>>(h, wfb, bfp, 1024, 1024, 1024,
                                                  cntb, strtb, t2bb, nullptr, ffin);
  k_scatter<<<4096, 256, 0, stream>>>(ffin, posb, strtb, (float*)d_out);
}

// Round 7
// 1500.009 us; speedup vs baseline: 3.7724x; 1.0865x over previous
//
#include <hip/hip_runtime.h>
#include <hip/hip_bf16.h>
#include <cstddef>

#define DEVI __device__ __forceinline__

typedef __attribute__((ext_vector_type(4))) float f4v;
typedef __attribute__((ext_vector_type(8))) short s8v;
typedef __attribute__((ext_vector_type(4))) short s4v;

using bf16 = __hip_bfloat16;

// L=8, B=8, N=512, C=1024, H=16, D=64
constexpr float SELU_A = 1.6732632423543772f;
constexpr float SELU_S = 1.0507009873554805f;
constexpr float TPINV  = 0.08838834764831845f; // 1/sqrt(2*D)

DEVI float bfbits(short s) { return __uint_as_float(((unsigned)(unsigned short)s) << 16); }
DEVI unsigned short f2bu(float f) {
  bf16 h = __float2bfloat16(f);
  return __builtin_bit_cast(unsigned short, h);
}
DEVI float seluf(float x) { return x > 0.f ? SELU_S * x : SELU_S * SELU_A * (__expf(x) - 1.f); }

DEVI void gl16(const void* g, void* l) {
  __builtin_amdgcn_global_load_lds((__attribute__((address_space(1))) void*)g,
                                   (__attribute__((address_space(3))) void*)l, 16, 0, 0);
}

DEVI void conv8(const float* __restrict__ src, bf16* __restrict__ dst) {
  f4v a = *(const f4v*)src;
  f4v b = *(const f4v*)(src + 4);
  s8v o;
  #pragma unroll
  for (int j = 0; j < 4; j++) { o[j] = (short)f2bu(a[j]); o[4 + j] = (short)f2bu(b[j]); }
  *(s8v*)dst = o;
}

// ---------------- mask compaction: global 128-aligned packing.
__global__ void k_compact(const float* __restrict__ xm, int* __restrict__ idx,
                          int* __restrict__ pos, int* __restrict__ cnt,
                          int* __restrict__ start, int* __restrict__ t2b)
{
  int t = threadIdx.x;           // 512 threads, wave w = batch w
  int b = t >> 6, lane = t & 63;
  __shared__ int scnt[8];
  int base = b * 512 + lane * 8;
  int mb[8]; int lc = 0;
  #pragma unroll
  for (int i = 0; i < 8; i++) { mb[i] = (xm[base + i] != 0.f) ? 1 : 0; lc += mb[i]; }
  int s = lc;
  #pragma unroll
  for (int o = 1; o < 64; o <<= 1) { int tt = __shfl_up(s, o); if (lane >= o) s += tt; }
  int run = s - lc;
  #pragma unroll
  for (int i = 0; i < 8; i++) {
    int n = lane * 8 + i;
    if (mb[i]) { idx[b * 512 + run] = n; pos[b * 512 + n] = run; run++; }
    else pos[b * 512 + n] = -1;
  }
  if (lane == 63) scnt[b] = s;
  __syncthreads();
  if (t == 0) {
    int st = 0, tile = 0;
    for (int bb = 0; bb < 8; bb++) {
      cnt[bb] = scnt[bb];
      start[bb] = st;
      int nt = (scnt[bb] + 127) >> 7;
      for (int k = 0; k < nt; k++) t2b[tile++] = bb;
      st += nt * 128;
    }
    start[8] = st;
    for (; tile < 32; tile++) t2b[tile] = 0;
  }
}

// ---------------- gather x into globally-compacted layout (tails zeroed)
__global__ __launch_bounds__(256) void k_gather(const float* __restrict__ xin,
    const int* __restrict__ idx, const int* __restrict__ cnt,
    const int* __restrict__ start, const int* __restrict__ t2b,
    float* __restrict__ xc)
{
  int row = blockIdx.x, t = threadIdx.x;
  if (row >= start[8]) return;
  int tb = t2b[row >> 7], slot = row - start[tb];
  f4v v = {0.f, 0.f, 0.f, 0.f};
  if (slot < cnt[tb])
    v = *(const f4v*)&xin[((size_t)tb * 512 + idx[tb * 512 + slot]) * 1024 + t * 4];
  *(f4v*)&xc[(size_t)row * 1024 + t * 4] = v;
}

// ---------------- scatter final rows back; dead rows = 0
__global__ __launch_bounds__(256) void k_scatter(const float* __restrict__ ffin,
    const int* __restrict__ pos, const int* __restrict__ start, float* __restrict__ out)
{
  int row = blockIdx.x, t = threadIdx.x, b = row >> 9;
  int p = pos[row];
  f4v v = {0.f, 0.f, 0.f, 0.f};
  if (p >= 0) v = *(const f4v*)&ffin[(size_t)(start[b] + p) * 1024 + t * 4];
  *(f4v*)&out[(size_t)row * 1024 + t * 4] = v;
}

// ---------------- per-layer merged weight conversion (prologue, layer 0)
__global__ __launch_bounds__(256) void k_convall(
    const float* __restrict__ wq, const float* __restrict__ wk, const float* __restrict__ wv,
    const float* __restrict__ w1, const float* __restrict__ w2,
    bf16* __restrict__ wqkvb, bf16* __restrict__ w1b, bf16* __restrict__ w2b)
{
  int i = blockIdx.x * 256 + threadIdx.x;
  if (i < 393216) {
    int o = i * 8;
    int row = o >> 10, col = o & 1023;
    int sel = row >> 10, sr = row & 1023;
    conv8((sel == 0 ? wq : sel == 1 ? wk : wv) + (size_t)sr * 1024 + col, wqkvb + o);
  } else if (i < 917504) {
    size_t o = (size_t)(i - 393216) * 8;
    conv8(w1 + o, w1b + o);
  } else if (i < 1441792) {
    size_t o = (size_t)(i - 917504) * 8;
    conv8(w2 + o, w2b + o);
  }
}

// ---------------- conditioning
__global__ void k_cond(const float* __restrict__ tim, const float* __restrict__ lab,
                       const float* __restrict__ Wl, const float* __restrict__ bl,
                       float* __restrict__ cs)
{
  int b = blockIdx.x, t = threadIdx.x;
  float l0 = lab[b * 2 + 0], l1 = lab[b * 2 + 1], tv = tim[b];
  #pragma unroll
  for (int i = 0; i < 4; i++) {
    int j = t + 256 * i;
    float e = powf(10000.f, (2.f * (float)j) * (1.f / 1024.f));
    float arg = tv / e;
    float te = ((j & 1) == 0) ? sinf(arg) : cosf(arg);
    float c = l0 * Wl[j * 2 + 0] + l1 * Wl[j * 2 + 1] + bl[j] + te;
    cs[b * 1024 + j] = seluf(c);
  }
}

// ---------------- small matvec batch
__global__ __launch_bounds__(256) void k_small(
    const float* __restrict__ cs, const float* __restrict__ W, const float* __restrict__ bias,
    float* __restrict__ out, int O, int mode)
{
  __shared__ float cls[8192];
  int t = threadIdx.x;
  #pragma unroll
  for (int i = 0; i < 8; i++)
    *(f4v*)&cls[i * 1024 + t * 4] = *(const f4v*)&cs[i * 1024 + t * 4];
  __syncthreads();
  int w = t >> 6, l = t & 63;
  int o = blockIdx.x * 4 + w;
  if (o >= O) return;
  float acc[8] = {0.f, 0.f, 0.f, 0.f, 0.f, 0.f, 0.f, 0.f};
  const float* Wr = W + (size_t)o * 1024;
  for (int i = 0; i < 16; i++) {
    int k = i * 64 + l;
    float wv = Wr[k];
    #pragma unroll
    for (int b = 0; b < 8; b++) acc[b] += wv * cls[b * 1024 + k];
  }
  #pragma unroll
  for (int b = 0; b < 8; b++) {
    #pragma unroll
    for (int off = 32; off; off >>= 1) acc[b] += __shfl_xor(acc[b], off);
  }
  float bv = bias[o];
  #pragma unroll
  for (int b = 0; b < 8; b++) {
    if (l == b) {
      float val = acc[b] + bv;
      size_t dst;
      if (mode == 0) { int ll = o / 6144, ft = o - ll * 6144; dst = ((size_t)ll * 8 + b) * 6144 + ft; }
      else dst = (size_t)b * 2048 + o;
      out[dst] = val;
    }
  }
}

// ---------------- row LN + modulate -> bf16 (layer 0 only; zeroes tails)
__global__ __launch_bounds__(256) void k_lnmod(
    const float* __restrict__ x, const float* __restrict__ shiftB, const float* __restrict__ scaleB,
    int bstride, const int* __restrict__ cnt, const int* __restrict__ start,
    const int* __restrict__ t2b, bf16* __restrict__ out)
{
  int row = blockIdx.x, t = threadIdx.x;
  if (row >= start[8]) return;
  int tb = t2b[row >> 7], slot = row - start[tb];
  if (slot >= cnt[tb]) {
    s4v z = {0, 0, 0, 0};
    *(s4v*)&out[(size_t)row * 1024 + t * 4] = z;
    return;
  }
  const float* xr = x + (size_t)row * 1024;
  f4v v = *(const f4v*)&xr[t * 4];
  float s = v[0] + v[1] + v[2] + v[3];
  float ss = v[0]*v[0] + v[1]*v[1] + v[2]*v[2] + v[3]*v[3];
  #pragma unroll
  for (int off = 32; off; off >>= 1) { s += __shfl_xor(s, off); ss += __shfl_xor(ss, off); }
  __shared__ float rs[4], rss[4];
  int w = t >> 6;
  if ((t & 63) == 0) { rs[w] = s; rss[w] = ss; }
  __syncthreads();
  s = rs[0] + rs[1] + rs[2] + rs[3];
  ss = rss[0] + rss[1] + rss[2] + rss[3];
  float mean = s * (1.f / 1024.f);
  float var = ss * (1.f / 1024.f) - mean * mean;
  float rstd = rsqrtf(var + 1e-6f);
  f4v sh = *(const f4v*)&shiftB[(size_t)tb * bstride + t * 4];
  f4v sc = *(const f4v*)&scaleB[(size_t)tb * bstride + t * 4];
  s4v o;
  #pragma unroll
  for (int i = 0; i < 4; i++)
    o[i] = (short)f2bu((v[i] - mean) * rstd * (1.f + sc[i]) + sh[i]);
  *(s4v*)&out[(size_t)row * 1024 + t * 4] = o;
}

// ---------------- x += gm*att; h2 = modulate(ln(x), sf, cf) -> bf16 (tails -> 0)
__global__ __launch_bounds__(256) void k_resid(
    float* __restrict__ x, const bf16* __restrict__ att, const float* __restrict__ m6b,
    const int* __restrict__ cnt, const int* __restrict__ start,
    const int* __restrict__ t2b, bf16* __restrict__ h2)
{
  int row = blockIdx.x, t = threadIdx.x;
  if (row >= start[8]) return;
  int tb = t2b[row >> 7], slot = row - start[tb];
  if (slot >= cnt[tb]) {
    s4v z = {0, 0, 0, 0};
    *(s4v*)&h2[(size_t)row * 1024 + t * 4] = z;
    return;
  }
  float* xr = x + (size_t)row * 1024;
  const float* gm = m6b + (size_t)tb * 6144 + 2048;
  const float* sf = m6b + (size_t)tb * 6144 + 3072;
  const float* cf = m6b + (size_t)tb * 6144 + 4096;
  f4v xv = *(const f4v*)&xr[t * 4];
  s4v av = *(const s4v*)&att[((size_t)tb * 512 + slot) * 1024 + t * 4];
  f4v gv = *(const f4v*)&gm[t * 4];
  f4v vv;
  #pragma unroll
  for (int i = 0; i < 4; i++) vv[i] = xv[i] + gv[i] * bfbits(av[i]);
  *(f4v*)&xr[t * 4] = vv;
  float s = vv[0] + vv[1] + vv[2] + vv[3];
  float ss = vv[0]*vv[0] + vv[1]*vv[1] + vv[2]*vv[2] + vv[3]*vv[3];
  #pragma unroll
  for (int off = 32; off; off >>= 1) { s += __shfl_xor(s, off); ss += __shfl_xor(ss, off); }
  __shared__ float rs[4], rss[4];
  int w = t >> 6;
  if ((t & 63) == 0) { rs[w] = s; rss[w] = ss; }
  __syncthreads();
  s = rs[0] + rs[1] + rs[2] + rs[3];
  ss = rss[0] + rss[1] + rss[2] + rss[3];
  float mean = s * (1.f / 1024.f);
  float var = ss * (1.f / 1024.f) - mean * mean;
  float rstd = rsqrtf(var + 1e-6f);
  f4v sfv = *(const f4v*)&sf[t * 4];
  f4v cfv = *(const f4v*)&cf[t * 4];
  s4v o;
  #pragma unroll
  for (int i = 0; i < 4; i++)
    o[i] = (short)f2bu((vv[i] - mean) * rstd * (1.f + cfv[i]) + sfv[i]);
  *(s4v*)&h2[(size_t)row * 1024 + t * 4] = o;
}

// ---------------- MFMA flash attention + fused next-layer weight conversion.
__global__ __launch_bounds__(256) void k_attn(
    const bf16* __restrict__ q, const bf16* __restrict__ k, const bf16* __restrict__ vt,
    const int* __restrict__ cnt, bf16* __restrict__ att,
    const float* __restrict__ nwq, const float* __restrict__ nwk, const float* __restrict__ nwv,
    const float* __restrict__ nw1, const float* __restrict__ nw2,
    bf16* __restrict__ dqkv, bf16* __restrict__ dw1, bf16* __restrict__ dw2, int mode)
{
  if (blockIdx.x >= 4) {
    int cid = (blockIdx.x - 4) * 128 + blockIdx.y;
    int i0 = cid * 256 + threadIdx.x;
    #pragma unroll
    for (int half = 0; half < 2; half++) {
      int j = i0 * 2 + half;
      if (mode == 1) {
        if (j < 131072) conv8(nwq + (size_t)j * 8, dqkv + (size_t)j * 8);
      } else {
        if (j < 393216) {
          int o = j * 8;
          int row = o >> 10, col = o & 1023;
          int sel = row >> 10, sr = row & 1023;
          conv8((sel == 0 ? nwq : sel == 1 ? nwk : nwv) + (size_t)sr * 1024 + col, dqkv + o);
        } else if (j < 917504) {
          size_t o = (size_t)(j - 393216) * 8;
          conv8(nw1 + o, dw1 + o);
        } else {
          size_t o = (size_t)(j - 917504) * 8;
          conv8(nw2 + o, dw2 + o);
        }
      }
    }
    return;
  }

  int bh = blockIdx.y, b = bh >> 4, hh = bh & 15;
  int cntb = cnt[b];
  if ((int)blockIdx.x * 128 >= cntb) return;
  int t = threadIdx.x, w = t >> 6, lane = t & 63;
  int fr = lane & 15, g = lane >> 4;
  int qw = blockIdx.x * 128 + w * 32;
  const size_t ho = (size_t)bh * (512 * 64);

  __shared__ bf16 Pb[4][32][72];

  s8v qf[2][2];
  #pragma unroll
  for (int mf = 0; mf < 2; mf++)
    #pragma unroll
    for (int kk = 0; kk < 2; kk++)
      qf[mf][kk] = *(const s8v*)(q + ho + (size_t)(qw + mf * 16 + fr) * 64 + kk * 32 + g * 8);

  float mrow[2][4], lsum[2][4];
  f4v oacc[2][4];
  const f4v vzero = {0.f, 0.f, 0.f, 0.f};
  #pragma unroll
  for (int mf = 0; mf < 2; mf++)
    #pragma unroll
    for (int r = 0; r < 4; r++) { mrow[mf][r] = -3.0e38f; lsum[mf][r] = 0.f; }
  #pragma unroll
  for (int mf = 0; mf < 2; mf++)
    #pragma unroll
    for (int nd = 0; nd < 4; nd++) oacc[mf][nd] = vzero;

  int nkt = (cntb + 63) >> 6;
  for (int kt = 0; kt < nkt; kt++) {
    int kb0 = kt * 64;
    f4v sacc[2][4];
    #pragma unroll
    for (int mf = 0; mf < 2; mf++)
      #pragma unroll
      for (int nf = 0; nf < 4; nf++) sacc[mf][nf] = vzero;
    #pragma unroll
    for (int kk = 0; kk < 2; kk++) {
      s8v kf[4];
      #pragma unroll
      for (int nf = 0; nf < 4; nf++)
        kf[nf] = *(const s8v*)(k + ho + (size_t)(kb0 + nf * 16 + fr) * 64 + kk * 32 + g * 8);
      #pragma unroll
      for (int mf = 0; mf < 2; mf++)
        #pragma unroll
        for (int nf = 0; nf < 4; nf++)
          sacc[mf][nf] = __builtin_amdgcn_mfma_f32_16x16x32_bf16(qf[mf][kk], kf[nf], sacc[mf][nf], 0, 0, 0);
    }
    #pragma unroll
    for (int mf = 0; mf < 2; mf++) {
      #pragma unroll
      for (int r = 0; r < 4; r++) {
        float mx = -3.0e38f;
        #pragma unroll
        for (int nf = 0; nf < 4; nf++) {
          float s = sacc[mf][nf][r] * TPINV;
          if (kb0 + nf * 16 + fr >= cntb) s = -1.0e30f;
          sacc[mf][nf][r] = s;
          mx = fmaxf(mx, s);
        }
        mx = fmaxf(mx, __shfl_xor(mx, 1));
        mx = fmaxf(mx, __shfl_xor(mx, 2));
        mx = fmaxf(mx, __shfl_xor(mx, 4));
        mx = fmaxf(mx, __shfl_xor(mx, 8));
        float mnew = fmaxf(mrow[mf][r], mx);
        float corr = __expf(mrow[mf][r] - mnew);
        mrow[mf][r] = mnew;
        float ps = 0.f;
        #pragma unroll
        for (int nf = 0; nf < 4; nf++) {
          float p = __expf(sacc[mf][nf][r] - mnew);
          ps += p;
          Pb[w][mf * 16 + g * 4 + r][nf * 16 + fr] = __float2bfloat16(p);
        }
        lsum[mf][r] = lsum[mf][r] * corr + ps;
        #pragma unroll
        for (int nd = 0; nd < 4; nd++) oacc[mf][nd][r] *= corr;
      }
    }
    #pragma unroll
    for (int kk = 0; kk < 2; kk++) {
      s8v pf[2], vf[4];
      #pragma unroll
      for (int mf = 0; mf < 2; mf++)
        pf[mf] = *(const s8v*)&Pb[w][mf * 16 + fr][kk * 32 + g * 8];
      #pragma unroll
      for (int nd = 0; nd < 4; nd++)
        vf[nd] = *(const s8v*)(vt + ho + (size_t)(nd * 16 + fr) * 512 + kb0 + kk * 32 + g * 8);
      #pragma unroll
      for (int mf = 0; mf < 2; mf++)
        #pragma unroll
        for (int nd = 0; nd < 4; nd++)
          oacc[mf][nd] = __builtin_amdgcn_mfma_f32_16x16x32_bf16(pf[mf], vf[nd], oacc[mf][nd], 0, 0, 0);
    }
  }
  float inv[2][4];
  #pragma unroll
  for (int mf = 0; mf < 2; mf++)
    #pragma unroll
    for (int r = 0; r < 4; r++) {
      float ls = lsum[mf][r];
      ls += __shfl_xor(ls, 1);
      ls += __shfl_xor(ls, 2);
      ls += __shfl_xor(ls, 4);
      ls += __shfl_xor(ls, 8);
      inv[mf][r] = 1.f / ls;
    }
  #pragma unroll
  for (int mf = 0; mf < 2; mf++)
    #pragma unroll
    for (int nd = 0; nd < 4; nd++)
      #pragma unroll
      for (int r = 0; r < 4; r++) {
        int row = qw + mf * 16 + g * 4 + r;
        att[(size_t)(b * 512 + row) * 1024 + hh * 64 + nd * 16 + fr] =
            __float2bfloat16(oacc[mf][nd][r] * inv[mf][r]);
      }
}

// ---------------- m97-structure GEMM, globally-compacted M, optional K-slice.
// EPI: 0=QKV store (Q,K:(b,h,slot,D); V:(b,h,D,slot)), 1=selu+bias->bf16,
//      3=bias->f32, 4=bf16 partial (split-K)
template <int EPI, int BN>
__global__ __launch_bounds__(256) void k_gemm(
    const bf16* __restrict__ A, const bf16* __restrict__ W,
    const float* __restrict__ bias, int Kst, int kLen, int Ncols,
    const int* __restrict__ cnt, const int* __restrict__ start, const int* __restrict__ t2b,
    bf16* __restrict__ outb, float* __restrict__ outf)
{
  constexpr int FN = BN / 32;
  constexpr int NW = BN / 32;
  __shared__ bf16 As[128][64];
  __shared__ bf16 Ws[BN][64];
  int t = threadIdx.x, lane = t & 63, w = t >> 6;
  int wr = w >> 1, wc = w & 1;
  int m0 = blockIdx.y * 128, n0 = blockIdx.x * BN;
  if (m0 >= start[8]) return;
  int kOff = blockIdx.z * kLen;
  int fr = lane & 15, g = lane >> 4;

  const bf16* Abase = A + (size_t)m0 * Kst + kOff;
  const bf16* Wbase = W + (size_t)n0 * Kst + kOff;

  const f4v vzero = {0.f, 0.f, 0.f, 0.f};
  f4v acc[4][FN];
  #pragma unroll
  for (int i = 0; i < 4; i++)
    #pragma unroll
    for (int j = 0; j < FN; j++) acc[i][j] = vzero;

  int nkt = kLen >> 6;
  for (int kt = 0; kt < nkt; kt++) {
    int k0 = kt << 6;
    __syncthreads();
    #pragma unroll
    for (int i = 0; i < 4; i++) {
      int off = w * 4096 + i * 1024 + lane * 16;
      int row = off >> 7, ce = (off & 127) >> 1;
      gl16(Abase + (size_t)row * Kst + k0 + ce, (char*)As + w * 4096 + i * 1024);
    }
    #pragma unroll
    for (int i = 0; i < NW; i++) {
      int off = w * (NW * 1024) + i * 1024 + lane * 16;
      int row = off >> 7, ce = (off & 127) >> 1;
      gl16(Wbase + (size_t)row * Kst + k0 + ce, (char*)Ws + w * (NW * 1024) + i * 1024);
    }
    __syncthreads();
    #pragma unroll
    for (int kk = 0; kk < 2; kk++) {
      s8v af[4], bfr[FN];
      #pragma unroll
      for (int mf = 0; mf < 4; mf++)
        af[mf] = *(const s8v*)&As[wr * 64 + mf * 16 + fr][kk * 32 + g * 8];
      #pragma unroll
      for (int nf = 0; nf < FN; nf++)
        bfr[nf] = *(const s8v*)&Ws[wc * (BN / 2) + nf * 16 + fr][kk * 32 + g * 8];
      #pragma unroll
      for (int mf = 0; mf < 4; mf++)
        #pragma unroll
        for (int nf = 0; nf < FN; nf++)
          acc[mf][nf] = __builtin_amdgcn_mfma_f32_16x16x32_bf16(af[mf], bfr[nf], acc[mf][nf], 0, 0, 0);
    }
  }

  int tb = t2b[m0 >> 7];
  int sb = start[tb];
  int rq = (lane >> 4) * 4;
  #pragma unroll
  for (int mf = 0; mf < 4; mf++) {
    #pragma unroll
    for (int nf = 0; nf < FN; nf++) {
      int row0 = m0 + wr * 64 + mf * 16 + rq;
      int col = n0 + wc * (BN / 2) + nf * 16 + fr;
      if (EPI == 0) {
        int sel = col >> 10, cl = col & 1023;
        int nn = row0 - sb;
        int h2 = cl >> 6, dd = cl & 63;
        if (sel == 2) {
          s4v o4;
          #pragma unroll
          for (int r = 0; r < 4; r++) o4[r] = (short)f2bu(acc[mf][nf][r]);
          *(s4v*)&outb[(size_t)2 * 4194304 + (((size_t)tb * 16 + h2) * 64 + dd) * 512 + nn] = o4;
        } else {
          #pragma unroll
          for (int r = 0; r < 4; r++)
            outb[(size_t)sel * 4194304 + (((size_t)tb * 16 + h2) * 512 + (nn + r)) * 64 + dd] =
                __float2bfloat16(acc[mf][nf][r]);
        }
      } else {
        #pragma unroll
        for (int r = 0; r < 4; r++) {
          int row = row0 + r;
          float val = acc[mf][nf][r];
          if (EPI == 1) {
            outb[(size_t)row * Ncols + col] = __float2bfloat16(seluf(val + bias[col]));
          } else if (EPI == 3) {
            outf[(size_t)row * 1024 + col] = val + bias[col];
          } else {
            outb[(size_t)blockIdx.z * 4194304 + (size_t)row * 1024 + col] = __float2bfloat16(val);
          }
        }
      }
    }
  }
}

// ---------------- split-K(8) combine + residual + NEXT-layer LN/modulate -> h
__global__ __launch_bounds__(256) void k_comb(
    const bf16* __restrict__ part, const float* __restrict__ bias,
    const float* __restrict__ gfb, const float* __restrict__ shiftN,
    const float* __restrict__ scaleN, int strideN,
    float* __restrict__ x, const int* __restrict__ cnt, const int* __restrict__ start,
    const int* __restrict__ t2b, bf16* __restrict__ h)
{
  int row = blockIdx.x, t = threadIdx.x;
  if (row >= start[8]) return;
  int tb = t2b[row >> 7], slot = row - start[tb];
  if (slot >= cnt[tb]) return;  // h tail slots stay zero (written once by layer-0 lnmod)
  size_t o = (size_t)row * 1024 + t * 4;
  f4v sum = {0.f, 0.f, 0.f, 0.f};
  #pragma unroll
  for (int p = 0; p < 8; p++) {
    s4v pv = *(const s4v*)&part[o + (size_t)p * 4194304];
    #pragma unroll
    for (int i = 0; i < 4; i++) sum[i] += bfbits(pv[i]);
  }
  f4v bv = *(const f4v*)&bias[t * 4];
  f4v gf = *(const f4v*)&gfb[(size_t)tb * 6144 + t * 4];
  f4v xv = *(const f4v*)&x[o];
  f4v vv;
  #pragma unroll
  for (int i = 0; i < 4; i++)
    vv[i] = xv[i] + gf[i] * (sum[i] + bv[i]);
  *(f4v*)&x[o] = vv;
  float s = vv[0] + vv[1] + vv[2] + vv[3];
  float ss = vv[0]*vv[0] + vv[1]*vv[1] + vv[2]*vv[2] + vv[3]*vv[3];
  #pragma unroll
  for (int off = 32; off; off >>= 1) { s += __shfl_xor(s, off); ss += __shfl_xor(ss, off); }
  __shared__ float rs[4], rss[4];
  int w = t >> 6;
  if ((t & 63) == 0) { rs[w] = s; rss[w] = ss; }
  __syncthreads();
  s = rs[0] + rs[1] + rs[2] + rs[3];
  ss = rss[0] + rss[1] + rss[2] + rss[3];
  float mean = s * (1.f / 1024.f);
  float var = ss * (1.f / 1024.f) - mean * mean;
  float rstd = rsqrtf(var + 1e-6f);
  f4v sh = *(const f4v*)&shiftN[(size_t)tb * strideN + t * 4];
  f4v sc = *(const f4v*)&scaleN[(size_t)tb * strideN + t * 4];
  s4v ho;
  #pragma unroll
  for (int i = 0; i < 4; i++)
    ho[i] = (short)f2bu((vv[i] - mean) * rstd * (1.f + sc[i]) + sh[i]);
  *(s4v*)&h[(size_t)row * 1024 + t * 4] = ho;
}

extern "C" void kernel_launch(void* const* d_in, const int* in_sizes, int n_in,
                              void* d_out, int out_size, void* d_ws, size_t ws_size,
                              hipStream_t stream)
{
  const float* x_in  = (const float*)d_in[0];
  const float* tim   = (const float*)d_in[1];
  const float* lab   = (const float*)d_in[2];
  const float* xmask = (const float*)d_in[3];
  const float* Wl  = (const float*)d_in[4];
  const float* bl  = (const float*)d_in[5];
  const float* Wq  = (const float*)d_in[6];
  const float* Wk  = (const float*)d_in[7];
  const float* Wv  = (const float*)d_in[8];
  const float* W1  = (const float*)d_in[9];
  const float* b1  = (const float*)d_in[10];
  const float* W2  = (const float*)d_in[11];
  const float* b2  = (const float*)d_in[12];
  const float* Wm  = (const float*)d_in[13];
  const float* bm  = (const float*)d_in[14];
  const float* Wf  = (const float*)d_in[15];
  const float* bfp = (const float*)d_in[16];
  const float* Wmf = (const float*)d_in[17];
  const float* bmf = (const float*)d_in[18];

  char* ws = (char*)d_ws;
  float* x     = (float*)(ws + 0);          // 16777216 B (global compacted)
  float* cs    = (float*)(ws + 16777216);   // 32768 B
  float* mAll  = (float*)(ws + 16809984);   // 1572864 B  [L][B][6144]
  float* m2v   = (float*)(ws + 18382848);   // 65536 B    [B][2048]
  bf16*  h     = (bf16*)(ws + 18448384);    // 8388608 B
  bf16*  qb    = (bf16*)(ws + 26836992);    // 8388608 B  (B,H,slot,D)
  bf16*  kb    = (bf16*)(ws + 35225600);    // 8388608 B  (B,H,slot,D)
  bf16*  vb    = (bf16*)(ws + 43614208);    // 8388608 B  (B,H,D,slot) V^T
  bf16*  att   = (bf16*)(ws + 52002816);    // 8388608 B  (B,slot,C)
  bf16*  f1    = (bf16*)(ws + 60391424);    // 33554432 B (4096 x 4096)
  bf16*  wqkv0 = (bf16*)(ws + 93945856);    // 6291456 B
  bf16*  w1b0  = (bf16*)(ws + 100237312);   // 8388608 B
  bf16*  w2b0  = (bf16*)(ws + 108625920);   // 8388608 B
  bf16*  wfb   = (bf16*)(ws + 117014528);   // 2097152 B
  float* ffin  = (float*)(ws + 119111680);  // 16777216 B
  int*   idxb  = (int*)(ws + 135888896);    // 16384 B
  int*   posb  = (int*)(ws + 135905280);    // 16384 B
  int*   cntb  = (int*)(ws + 135921664);    // 64 B
  int*   strtb = (int*)(ws + 135921728);    // 64 B (start[9])
  int*   t2bb  = (int*)(ws + 135921792);    // 128 B (t2b[32])
  bf16*  wqkv1 = (bf16*)(ws + 135921920);   // 6291456 B
  bf16*  w1b1  = (bf16*)(ws + 142213376);   // 8388608 B
  bf16*  w2b1  = (bf16*)(ws + 150601984);   // 8388608 B
  bf16*  part  = (bf16*)(ws + 158990592);   // 67108864 B (8 x 4096 x 1024 bf16; ends 226099456)

  bf16* wqkvS[2] = { wqkv0, wqkv1 };
  bf16* w1S[2]   = { w1b0, w1b1 };
  bf16* w2S[2]   = { w2b0, w2b1 };

  k_compact<<<1, 512, 0, stream>>>(xmask, idxb, posb, cntb, strtb, t2bb);
  k_gather<<<4096, 256, 0, stream>>>(x_in, idxb, cntb, strtb, t2bb, x);

  k_cond<<<8, 256, 0, stream>>>(tim, lab, Wl, bl, cs);
  k_small<<<12288, 256, 0, stream>>>(cs, Wm, bm, mAll, 49152, 0);
  k_small<<<512, 256, 0, stream>>>(cs, Wmf, bmf, m2v, 2048, 1);

  k_convall<<<5632, 256, 0, stream>>>(Wq, Wk, Wv, W1, W2, wqkv0, w1b0, w2b0);
  k_lnmod<<<4096, 256, 0, stream>>>(x, mAll + 0, mAll + 1024, 6144, cntb, strtb, t2bb, h);

  for (int l = 0; l < 8; l++) {
    const float* m6b = mAll + (size_t)l * 49152;
    int sel = l & 1, nsel = sel ^ 1;
    int last = (l == 7);

    k_gemm<0, 64><<<dim3(48, 32), 256, 0, stream>>>(h, wqkvS[sel], nullptr, 1024, 1024, 3072,
                                                    cntb, strtb, t2bb, qb, nullptr);
    if (!last) {
      k_attn<<<dim3(26, 128), 256, 0, stream>>>(qb, kb, vb, cntb, att,
          Wq + (size_t)(l + 1) * 1048576, Wk + (size_t)(l + 1) * 1048576,
          Wv + (size_t)(l + 1) * 1048576, W1 + (size_t)(l + 1) * 4194304,
          W2 + (size_t)(l + 1) * 4194304,
          wqkvS[nsel], w1S[nsel], w2S[nsel], 0);
    } else {
      k_attn<<<dim3(26, 128), 256, 0, stream>>>(qb, kb, vb, cntb, att,
          Wf, Wf, Wf, Wf, Wf, wfb, wfb, wfb, 1);
    }
    k_resid<<<4096, 256, 0, stream>>>(x, att, m6b, cntb, strtb, t2bb, h);
    k_gemm<1, 64><<<dim3(64, 32), 256, 0, stream>>>(h, w1S[sel], b1 + l * 4096, 1024, 1024, 4096,
                                                    cntb, strtb, t2bb, f1, nullptr);
    k_gemm<4, 128><<<dim3(8, 32, 8), 256, 0, stream>>>(f1, w2S[sel], nullptr, 4096, 512, 1024,
                                                       cntb, strtb, t2bb, part, nullptr);
    const float* nShift = last ? m2v : (mAll + (size_t)(l + 1) * 49152);
    const float* nScale = last ? (m2v + 1024) : (mAll + (size_t)(l + 1) * 49152 + 1024);
    int nStride = last ? 2048 : 6144;
    k_comb<<<4096, 256, 0, stream>>>(part, b2 + l * 1024, m6b + 5120,
                                     nShift, nScale, nStride,
                                     x, cntb, strtb, t2bb, h);
  }

  k_gemm<3, 64><<<dim3(16, 32), 256, 0, stream>>>(h, wfb, bfp, 1024, 1024, 1024,
                                                  cntb, strtb, t2bb, nullptr, ffin);
  k_scatter<<<4096, 256, 0, stream>>>(ffin, posb, strtb, (float*)d_out);
}

// Round 8
// 1366.344 us; speedup vs baseline: 4.1414x; 1.0978x over previous
//
#include <hip/hip_runtime.h>
#include <hip/hip_bf16.h>
#include <cstddef>

#define DEVI __device__ __forceinline__

typedef __attribute__((ext_vector_type(4))) float f4v;
typedef __attribute__((ext_vector_type(16))) float f16v;
typedef __attribute__((ext_vector_type(8))) short s8v;
typedef __attribute__((ext_vector_type(4))) short s4v;

using bf16 = __hip_bfloat16;

// L=8, B=8, N=512, C=1024, H=16, D=64
constexpr float SELU_A = 1.6732632423543772f;
constexpr float SELU_S = 1.0507009873554805f;
constexpr float TPINV  = 0.08838834764831845f; // 1/sqrt(2*D)

DEVI float bfbits(short s) { return __uint_as_float(((unsigned)(unsigned short)s) << 16); }
DEVI unsigned short f2bu(float f) {
  bf16 h = __float2bfloat16(f);
  return __builtin_bit_cast(unsigned short, h);
}
DEVI float seluf(float x) { return x > 0.f ? SELU_S * x : SELU_S * SELU_A * (__expf(x) - 1.f); }

DEVI void gl16(const void* g, void* l) {
  __builtin_amdgcn_global_load_lds((__attribute__((address_space(1))) void*)g,
                                   (__attribute__((address_space(3))) void*)l, 16, 0, 0);
}

DEVI void conv8(const float* __restrict__ src, bf16* __restrict__ dst) {
  f4v a = *(const f4v*)src;
  f4v b = *(const f4v*)(src + 4);
  s8v o;
  #pragma unroll
  for (int j = 0; j < 4; j++) { o[j] = (short)f2bu(a[j]); o[4 + j] = (short)f2bu(b[j]); }
  *(s8v*)dst = o;
}

// ---------------- mask compaction: global 128-aligned packing.
__global__ void k_compact(const float* __restrict__ xm, int* __restrict__ idx,
                          int* __restrict__ pos, int* __restrict__ cnt,
                          int* __restrict__ start, int* __restrict__ t2b)
{
  int t = threadIdx.x;           // 512 threads, wave w = batch w
  int b = t >> 6, lane = t & 63;
  __shared__ int scnt[8];
  int base = b * 512 + lane * 8;
  int mb[8]; int lc = 0;
  #pragma unroll
  for (int i = 0; i < 8; i++) { mb[i] = (xm[base + i] != 0.f) ? 1 : 0; lc += mb[i]; }
  int s = lc;
  #pragma unroll
  for (int o = 1; o < 64; o <<= 1) { int tt = __shfl_up(s, o); if (lane >= o) s += tt; }
  int run = s - lc;
  #pragma unroll
  for (int i = 0; i < 8; i++) {
    int n = lane * 8 + i;
    if (mb[i]) { idx[b * 512 + run] = n; pos[b * 512 + n] = run; run++; }
    else pos[b * 512 + n] = -1;
  }
  if (lane == 63) scnt[b] = s;
  __syncthreads();
  if (t == 0) {
    int st = 0, tile = 0;
    for (int bb = 0; bb < 8; bb++) {
      cnt[bb] = scnt[bb];
      start[bb] = st;
      int nt = (scnt[bb] + 127) >> 7;
      for (int k = 0; k < nt; k++) t2b[tile++] = bb;
      st += nt * 128;
    }
    start[8] = st;
    for (; tile < 32; tile++) t2b[tile] = 0;
  }
}

// ---------------- gather x into globally-compacted layout (tails zeroed)
__global__ __launch_bounds__(256) void k_gather(const float* __restrict__ xin,
    const int* __restrict__ idx, const int* __restrict__ cnt,
    const int* __restrict__ start, const int* __restrict__ t2b,
    float* __restrict__ xc)
{
  int row = blockIdx.x, t = threadIdx.x;
  if (row >= start[8]) return;
  int tb = t2b[row >> 7], slot = row - start[tb];
  f4v v = {0.f, 0.f, 0.f, 0.f};
  if (slot < cnt[tb])
    v = *(const f4v*)&xin[((size_t)tb * 512 + idx[tb * 512 + slot]) * 1024 + t * 4];
  *(f4v*)&xc[(size_t)row * 1024 + t * 4] = v;
}

// ---------------- scatter final rows back; dead rows = 0
__global__ __launch_bounds__(256) void k_scatter(const float* __restrict__ ffin,
    const int* __restrict__ pos, const int* __restrict__ start, float* __restrict__ out)
{
  int row = blockIdx.x, t = threadIdx.x, b = row >> 9;
  int p = pos[row];
  f4v v = {0.f, 0.f, 0.f, 0.f};
  if (p >= 0) v = *(const f4v*)&ffin[(size_t)(start[b] + p) * 1024 + t * 4];
  *(f4v*)&out[(size_t)row * 1024 + t * 4] = v;
}

// ---------------- per-layer merged weight conversion (prologue, layer 0)
__global__ __launch_bounds__(256) void k_convall(
    const float* __restrict__ wq, const float* __restrict__ wk, const float* __restrict__ wv,
    const float* __restrict__ w1, const float* __restrict__ w2,
    bf16* __restrict__ wqkvb, bf16* __restrict__ w1b, bf16* __restrict__ w2b)
{
  int i = blockIdx.x * 256 + threadIdx.x;
  if (i < 393216) {
    int o = i * 8;
    int row = o >> 10, col = o & 1023;
    int sel = row >> 10, sr = row & 1023;
    conv8((sel == 0 ? wq : sel == 1 ? wk : wv) + (size_t)sr * 1024 + col, wqkvb + o);
  } else if (i < 917504) {
    size_t o = (size_t)(i - 393216) * 8;
    conv8(w1 + o, w1b + o);
  } else if (i < 1441792) {
    size_t o = (size_t)(i - 917504) * 8;
    conv8(w2 + o, w2b + o);
  }
}

// ---------------- conditioning
__global__ void k_cond(const float* __restrict__ tim, const float* __restrict__ lab,
                       const float* __restrict__ Wl, const float* __restrict__ bl,
                       float* __restrict__ cs)
{
  int b = blockIdx.x, t = threadIdx.x;
  float l0 = lab[b * 2 + 0], l1 = lab[b * 2 + 1], tv = tim[b];
  #pragma unroll
  for (int i = 0; i < 4; i++) {
    int j = t + 256 * i;
    float e = powf(10000.f, (2.f * (float)j) * (1.f / 1024.f));
    float arg = tv / e;
    float te = ((j & 1) == 0) ? sinf(arg) : cosf(arg);
    float c = l0 * Wl[j * 2 + 0] + l1 * Wl[j * 2 + 1] + bl[j] + te;
    cs[b * 1024 + j] = seluf(c);
  }
}

// ---------------- small matvec batch
__global__ __launch_bounds__(256) void k_small(
    const float* __restrict__ cs, const float* __restrict__ W, const float* __restrict__ bias,
    float* __restrict__ out, int O, int mode)
{
  __shared__ float cls[8192];
  int t = threadIdx.x;
  #pragma unroll
  for (int i = 0; i < 8; i++)
    *(f4v*)&cls[i * 1024 + t * 4] = *(const f4v*)&cs[i * 1024 + t * 4];
  __syncthreads();
  int w = t >> 6, l = t & 63;
  int o = blockIdx.x * 4 + w;
  if (o >= O) return;
  float acc[8] = {0.f, 0.f, 0.f, 0.f, 0.f, 0.f, 0.f, 0.f};
  const float* Wr = W + (size_t)o * 1024;
  for (int i = 0; i < 16; i++) {
    int k = i * 64 + l;
    float wv = Wr[k];
    #pragma unroll
    for (int b = 0; b < 8; b++) acc[b] += wv * cls[b * 1024 + k];
  }
  #pragma unroll
  for (int b = 0; b < 8; b++) {
    #pragma unroll
    for (int off = 32; off; off >>= 1) acc[b] += __shfl_xor(acc[b], off);
  }
  float bv = bias[o];
  #pragma unroll
  for (int b = 0; b < 8; b++) {
    if (l == b) {
      float val = acc[b] + bv;
      size_t dst;
      if (mode == 0) { int ll = o / 6144, ft = o - ll * 6144; dst = ((size_t)ll * 8 + b) * 6144 + ft; }
      else dst = (size_t)b * 2048 + o;
      out[dst] = val;
    }
  }
}

// ---------------- row LN + modulate -> bf16 (layer 0 only; zeroes tails)
__global__ __launch_bounds__(256) void k_lnmod(
    const float* __restrict__ x, const float* __restrict__ shiftB, const float* __restrict__ scaleB,
    int bstride, const int* __restrict__ cnt, const int* __restrict__ start,
    const int* __restrict__ t2b, bf16* __restrict__ out)
{
  int row = blockIdx.x, t = threadIdx.x;
  if (row >= start[8]) return;
  int tb = t2b[row >> 7], slot = row - start[tb];
  if (slot >= cnt[tb]) {
    s4v z = {0, 0, 0, 0};
    *(s4v*)&out[(size_t)row * 1024 + t * 4] = z;
    return;
  }
  const float* xr = x + (size_t)row * 1024;
  f4v v = *(const f4v*)&xr[t * 4];
  float s = v[0] + v[1] + v[2] + v[3];
  float ss = v[0]*v[0] + v[1]*v[1] + v[2]*v[2] + v[3]*v[3];
  #pragma unroll
  for (int off = 32; off; off >>= 1) { s += __shfl_xor(s, off); ss += __shfl_xor(ss, off); }
  __shared__ float rs[4], rss[4];
  int w = t >> 6;
  if ((t & 63) == 0) { rs[w] = s; rss[w] = ss; }
  __syncthreads();
  s = rs[0] + rs[1] + rs[2] + rs[3];
  ss = rss[0] + rss[1] + rss[2] + rss[3];
  float mean = s * (1.f / 1024.f);
  float var = ss * (1.f / 1024.f) - mean * mean;
  float rstd = rsqrtf(var + 1e-6f);
  f4v sh = *(const f4v*)&shiftB[(size_t)tb * bstride + t * 4];
  f4v sc = *(const f4v*)&scaleB[(size_t)tb * bstride + t * 4];
  s4v o;
  #pragma unroll
  for (int i = 0; i < 4; i++)
    o[i] = (short)f2bu((v[i] - mean) * rstd * (1.f + sc[i]) + sh[i]);
  *(s4v*)&out[(size_t)row * 1024 + t * 4] = o;
}

// ---------------- x += gm*att; h2 = modulate(ln(x), sf, cf) -> bf16 (tails -> 0)
__global__ __launch_bounds__(256) void k_resid(
    float* __restrict__ x, const bf16* __restrict__ att, const float* __restrict__ m6b,
    const int* __restrict__ cnt, const int* __restrict__ start,
    const int* __restrict__ t2b, bf16* __restrict__ h2)
{
  int row = blockIdx.x, t = threadIdx.x;
  if (row >= start[8]) return;
  int tb = t2b[row >> 7], slot = row - start[tb];
  if (slot >= cnt[tb]) {
    s4v z = {0, 0, 0, 0};
    *(s4v*)&h2[(size_t)row * 1024 + t * 4] = z;
    return;
  }
  float* xr = x + (size_t)row * 1024;
  const float* gm = m6b + (size_t)tb * 6144 + 2048;
  const float* sf = m6b + (size_t)tb * 6144 + 3072;
  const float* cf = m6b + (size_t)tb * 6144 + 4096;
  f4v xv = *(const f4v*)&xr[t * 4];
  s4v av = *(const s4v*)&att[((size_t)tb * 512 + slot) * 1024 + t * 4];
  f4v gv = *(const f4v*)&gm[t * 4];
  f4v vv;
  #pragma unroll
  for (int i = 0; i < 4; i++) vv[i] = xv[i] + gv[i] * bfbits(av[i]);
  *(f4v*)&xr[t * 4] = vv;
  float s = vv[0] + vv[1] + vv[2] + vv[3];
  float ss = vv[0]*vv[0] + vv[1]*vv[1] + vv[2]*vv[2] + vv[3]*vv[3];
  #pragma unroll
  for (int off = 32; off; off >>= 1) { s += __shfl_xor(s, off); ss += __shfl_xor(ss, off); }
  __shared__ float rs[4], rss[4];
  int w = t >> 6;
  if ((t & 63) == 0) { rs[w] = s; rss[w] = ss; }
  __syncthreads();
  s = rs[0] + rs[1] + rs[2] + rs[3];
  ss = rss[0] + rss[1] + rss[2] + rss[3];
  float mean = s * (1.f / 1024.f);
  float var = ss * (1.f / 1024.f) - mean * mean;
  float rstd = rsqrtf(var + 1e-6f);
  f4v sfv = *(const f4v*)&sf[t * 4];
  f4v cfv = *(const f4v*)&cf[t * 4];
  s4v o;
  #pragma unroll
  for (int i = 0; i < 4; i++)
    o[i] = (short)f2bu((vv[i] - mean) * rstd * (1.f + cfv[i]) + sfv[i]);
  *(s4v*)&h2[(size_t)row * 1024 + t * 4] = o;
}

// ---------------- MFMA flash attention + fused next-layer weight conversion.
__global__ __launch_bounds__(256) void k_attn(
    const bf16* __restrict__ q, const bf16* __restrict__ k, const bf16* __restrict__ vt,
    const int* __restrict__ cnt, bf16* __restrict__ att,
    const float* __restrict__ nwq, const float* __restrict__ nwk, const float* __restrict__ nwv,
    const float* __restrict__ nw1, const float* __restrict__ nw2,
    bf16* __restrict__ dqkv, bf16* __restrict__ dw1, bf16* __restrict__ dw2, int mode)
{
  if (blockIdx.x >= 4) {
    int cid = (blockIdx.x - 4) * 128 + blockIdx.y;
    int i0 = cid * 256 + threadIdx.x;
    #pragma unroll
    for (int half = 0; half < 2; half++) {
      int j = i0 * 2 + half;
      if (mode == 1) {
        if (j < 131072) conv8(nwq + (size_t)j * 8, dqkv + (size_t)j * 8);
      } else {
        if (j < 393216) {
          int o = j * 8;
          int row = o >> 10, col = o & 1023;
          int sel = row >> 10, sr = row & 1023;
          conv8((sel == 0 ? nwq : sel == 1 ? nwk : nwv) + (size_t)sr * 1024 + col, dqkv + o);
        } else if (j < 917504) {
          size_t o = (size_t)(j - 393216) * 8;
          conv8(nw1 + o, dw1 + o);
        } else {
          size_t o = (size_t)(j - 917504) * 8;
          conv8(nw2 + o, dw2 + o);
        }
      }
    }
    return;
  }

  int bh = blockIdx.y, b = bh >> 4, hh = bh & 15;
  int cntb = cnt[b];
  if ((int)blockIdx.x * 128 >= cntb) return;
  int t = threadIdx.x, w = t >> 6, lane = t & 63;
  int fr = lane & 15, g = lane >> 4;
  int qw = blockIdx.x * 128 + w * 32;
  const size_t ho = (size_t)bh * (512 * 64);

  __shared__ bf16 Pb[4][32][72];

  s8v qf[2][2];
  #pragma unroll
  for (int mf = 0; mf < 2; mf++)
    #pragma unroll
    for (int kk = 0; kk < 2; kk++)
      qf[mf][kk] = *(const s8v*)(q + ho + (size_t)(qw + mf * 16 + fr) * 64 + kk * 32 + g * 8);

  float mrow[2][4], lsum[2][4];
  f4v oacc[2][4];
  const f4v vzero = {0.f, 0.f, 0.f, 0.f};
  #pragma unroll
  for (int mf = 0; mf < 2; mf++)
    #pragma unroll
    for (int r = 0; r < 4; r++) { mrow[mf][r] = -3.0e38f; lsum[mf][r] = 0.f; }
  #pragma unroll
  for (int mf = 0; mf < 2; mf++)
    #pragma unroll
    for (int nd = 0; nd < 4; nd++) oacc[mf][nd] = vzero;

  int nkt = (cntb + 63) >> 6;
  for (int kt = 0; kt < nkt; kt++) {
    int kb0 = kt * 64;
    f4v sacc[2][4];
    #pragma unroll
    for (int mf = 0; mf < 2; mf++)
      #pragma unroll
      for (int nf = 0; nf < 4; nf++) sacc[mf][nf] = vzero;
    #pragma unroll
    for (int kk = 0; kk < 2; kk++) {
      s8v kf[4];
      #pragma unroll
      for (int nf = 0; nf < 4; nf++)
        kf[nf] = *(const s8v*)(k + ho + (size_t)(kb0 + nf * 16 + fr) * 64 + kk * 32 + g * 8);
      #pragma unroll
      for (int mf = 0; mf < 2; mf++)
        #pragma unroll
        for (int nf = 0; nf < 4; nf++)
          sacc[mf][nf] = __builtin_amdgcn_mfma_f32_16x16x32_bf16(qf[mf][kk], kf[nf], sacc[mf][nf], 0, 0, 0);
    }
    #pragma unroll
    for (int mf = 0; mf < 2; mf++) {
      #pragma unroll
      for (int r = 0; r < 4; r++) {
        float mx = -3.0e38f;
        #pragma unroll
        for (int nf = 0; nf < 4; nf++) {
          float s = sacc[mf][nf][r] * TPINV;
          if (kb0 + nf * 16 + fr >= cntb) s = -1.0e30f;
          sacc[mf][nf][r] = s;
          mx = fmaxf(mx, s);
        }
        mx = fmaxf(mx, __shfl_xor(mx, 1));
        mx = fmaxf(mx, __shfl_xor(mx, 2));
        mx = fmaxf(mx, __shfl_xor(mx, 4));
        mx = fmaxf(mx, __shfl_xor(mx, 8));
        float mnew = fmaxf(mrow[mf][r], mx);
        float corr = __expf(mrow[mf][r] - mnew);
        mrow[mf][r] = mnew;
        float ps = 0.f;
        #pragma unroll
        for (int nf = 0; nf < 4; nf++) {
          float p = __expf(sacc[mf][nf][r] - mnew);
          ps += p;
          Pb[w][mf * 16 + g * 4 + r][nf * 16 + fr] = __float2bfloat16(p);
        }
        lsum[mf][r] = lsum[mf][r] * corr + ps;
        #pragma unroll
        for (int nd = 0; nd < 4; nd++) oacc[mf][nd][r] *= corr;
      }
    }
    #pragma unroll
    for (int kk = 0; kk < 2; kk++) {
      s8v pf[2], vf[4];
      #pragma unroll
      for (int mf = 0; mf < 2; mf++)
        pf[mf] = *(const s8v*)&Pb[w][mf * 16 + fr][kk * 32 + g * 8];
      #pragma unroll
      for (int nd = 0; nd < 4; nd++)
        vf[nd] = *(const s8v*)(vt + ho + (size_t)(nd * 16 + fr) * 512 + kb0 + kk * 32 + g * 8);
      #pragma unroll
      for (int mf = 0; mf < 2; mf++)
        #pragma unroll
        for (int nd = 0; nd < 4; nd++)
          oacc[mf][nd] = __builtin_amdgcn_mfma_f32_16x16x32_bf16(pf[mf], vf[nd], oacc[mf][nd], 0, 0, 0);
    }
  }
  float inv[2][4];
  #pragma unroll
  for (int mf = 0; mf < 2; mf++)
    #pragma unroll
    for (int r = 0; r < 4; r++) {
      float ls = lsum[mf][r];
      ls += __shfl_xor(ls, 1);
      ls += __shfl_xor(ls, 2);
      ls += __shfl_xor(ls, 4);
      ls += __shfl_xor(ls, 8);
      inv[mf][r] = 1.f / ls;
    }
  #pragma unroll
  for (int mf = 0; mf < 2; mf++)
    #pragma unroll
    for (int nd = 0; nd < 4; nd++)
      #pragma unroll
      for (int r = 0; r < 4; r++) {
        int row = qw + mf * 16 + g * 4 + r;
        att[(size_t)(b * 512 + row) * 1024 + hh * 64 + nd * 16 + fr] =
            __float2bfloat16(oacc[mf][nd][r] * inv[mf][r]);
      }
}

// ---------------- GEMM: 32x32x16 MFMA + XOR-swizzled LDS (pre-swizzled source).
// Block 128 x BN, 4 waves (2x2). Each wave: 2 m-frags (32 rows) x NFR n-frags (32 cols).
// LDS rows are 64 bf16 = 128 B = 8 slots of 16 B; slot s of row r holds global slot s^(r&7).
// EPI: 0=QKV store (Q,K:(b,h,slot,D); V:(b,h,D,slot)), 1=selu+bias->bf16,
//      3=bias->f32, 4=bf16 partial (split-K)
template <int EPI, int BN>
__global__ __launch_bounds__(256) void k_gemm(
    const bf16* __restrict__ A, const bf16* __restrict__ W,
    const float* __restrict__ bias, int Kst, int kLen, int Ncols,
    const int* __restrict__ cnt, const int* __restrict__ start, const int* __restrict__ t2b,
    bf16* __restrict__ outb, float* __restrict__ outf)
{
  constexpr int NFR = BN / 64;     // n-frags (32 cols) per wave
  constexpr int NW  = BN / 32;     // W staging insts per thread
  __shared__ bf16 As[128][64];
  __shared__ bf16 Ws[BN][64];
  int t = threadIdx.x, lane = t & 63, w = t >> 6;
  int wr = w >> 1, wc = w & 1;
  int m0 = blockIdx.y * 128, n0 = blockIdx.x * BN;
  if (m0 >= start[8]) return;
  int kOff = blockIdx.z * kLen;
  int r32 = lane & 31, hi = lane >> 5;

  const bf16* Abase = A + (size_t)m0 * Kst + kOff;
  const bf16* Wbase = W + (size_t)n0 * Kst + kOff;

  f16v acc[2][NFR];
  #pragma unroll
  for (int i = 0; i < 2; i++)
    #pragma unroll
    for (int j = 0; j < NFR; j++)
      #pragma unroll
      for (int e = 0; e < 16; e++) acc[i][j][e] = 0.f;

  int nkt = kLen >> 6;
  for (int kt = 0; kt < nkt; kt++) {
    int k0 = kt << 6;
    __syncthreads();
    // stage A tile (16 KB): LDS dest linear, global source pre-swizzled slot^=(row&7)
    #pragma unroll
    for (int i = 0; i < 4; i++) {
      int Z = w * 4096 + i * 1024 + lane * 16;
      int row = Z >> 7, slot = (Z >> 4) & 7;
      int ss = slot ^ (row & 7);
      gl16(Abase + (size_t)row * Kst + k0 + ss * 8, (char*)As + Z);
    }
    #pragma unroll
    for (int i = 0; i < NW; i++) {
      int Z = w * (NW * 1024) + i * 1024 + lane * 16;
      int row = Z >> 7, slot = (Z >> 4) & 7;
      int ss = slot ^ (row & 7);
      gl16(Wbase + (size_t)row * Kst + k0 + ss * 8, (char*)Ws + Z);
    }
    __syncthreads();
    #pragma unroll
    for (int kk = 0; kk < 4; kk++) {
      s8v af[2], bfr[NFR];
      #pragma unroll
      for (int mf = 0; mf < 2; mf++) {
        int row = wr * 64 + mf * 32 + r32;
        int sl = (kk * 2 + hi) ^ (row & 7);
        af[mf] = *(const s8v*)((const char*)As + row * 128 + sl * 16);
      }
      #pragma unroll
      for (int nf = 0; nf < NFR; nf++) {
        int row = wc * (BN / 2) + nf * 32 + r32;
        int sl = (kk * 2 + hi) ^ (row & 7);
        bfr[nf] = *(const s8v*)((const char*)Ws + row * 128 + sl * 16);
      }
      #pragma unroll
      for (int mf = 0; mf < 2; mf++)
        #pragma unroll
        for (int nf = 0; nf < NFR; nf++)
          acc[mf][nf] = __builtin_amdgcn_mfma_f32_32x32x16_bf16(af[mf], bfr[nf], acc[mf][nf], 0, 0, 0);
    }
  }

  // epilogue: C/D layout col=lane&31, row=(reg&3)+8*(reg>>2)+4*hi
  int tb = t2b[m0 >> 7];
  int sb = start[tb];
  #pragma unroll
  for (int mf = 0; mf < 2; mf++) {
    #pragma unroll
    for (int nf = 0; nf < NFR; nf++) {
      int col = n0 + wc * (BN / 2) + nf * 32 + r32;
      #pragma unroll
      for (int qd = 0; qd < 4; qd++) {
        int row0 = m0 + wr * 64 + mf * 32 + qd * 8 + hi * 4;
        if (EPI == 0) {
          int sel = col >> 10, cl = col & 1023;
          int nn = row0 - sb;
          int h2 = cl >> 6, dd = cl & 63;
          if (sel == 2) {
            s4v o4;
            #pragma unroll
            for (int r = 0; r < 4; r++) o4[r] = (short)f2bu(acc[mf][nf][qd * 4 + r]);
            *(s4v*)&outb[(size_t)2 * 4194304 + (((size_t)tb * 16 + h2) * 64 + dd) * 512 + nn] = o4;
          } else {
            #pragma unroll
            for (int r = 0; r < 4; r++)
              outb[(size_t)sel * 4194304 + (((size_t)tb * 16 + h2) * 512 + (nn + r)) * 64 + dd] =
                  __float2bfloat16(acc[mf][nf][qd * 4 + r]);
          }
        } else {
          #pragma unroll
          for (int r = 0; r < 4; r++) {
            int row = row0 + r;
            float val = acc[mf][nf][qd * 4 + r];
            if (EPI == 1) {
              outb[(size_t)row * Ncols + col] = __float2bfloat16(seluf(val + bias[col]));
            } else if (EPI == 3) {
              outf[(size_t)row * 1024 + col] = val + bias[col];
            } else {
              outb[(size_t)blockIdx.z * 4194304 + (size_t)row * 1024 + col] = __float2bfloat16(val);
            }
          }
        }
      }
    }
  }
}

// ---------------- split-K(8) combine + residual + NEXT-layer LN/modulate -> h
__global__ __launch_bounds__(256) void k_comb(
    const bf16* __restrict__ part, const float* __restrict__ bias,
    const float* __restrict__ gfb, const float* __restrict__ shiftN,
    const float* __restrict__ scaleN, int strideN,
    float* __restrict__ x, const int* __restrict__ cnt, const int* __restrict__ start,
    const int* __restrict__ t2b, bf16* __restrict__ h)
{
  int row = blockIdx.x, t = threadIdx.x;
  if (row >= start[8]) return;
  int tb = t2b[row >> 7], slot = row - start[tb];
  if (slot >= cnt[tb]) return;  // h tail slots stay zero (written once by layer-0 lnmod)
  size_t o = (size_t)row * 1024 + t * 4;
  f4v sum = {0.f, 0.f, 0.f, 0.f};
  #pragma unroll
  for (int p = 0; p < 8; p++) {
    s4v pv = *(const s4v*)&part[o + (size_t)p * 4194304];
    #pragma unroll
    for (int i = 0; i < 4; i++) sum[i] += bfbits(pv[i]);
  }
  f4v bv = *(const f4v*)&bias[t * 4];
  f4v gf = *(const f4v*)&gfb[(size_t)tb * 6144 + t * 4];
  f4v xv = *(const f4v*)&x[o];
  f4v vv;
  #pragma unroll
  for (int i = 0; i < 4; i++)
    vv[i] = xv[i] + gf[i] * (sum[i] + bv[i]);
  *(f4v*)&x[o] = vv;
  float s = vv[0] + vv[1] + vv[2] + vv[3];
  float ss = vv[0]*vv[0] + vv[1]*vv[1] + vv[2]*vv[2] + vv[3]*vv[3];
  #pragma unroll
  for (int off = 32; off; off >>= 1) { s += __shfl_xor(s, off); ss += __shfl_xor(ss, off); }
  __shared__ float rs[4], rss[4];
  int w = t >> 6;
  if ((t & 63) == 0) { rs[w] = s; rss[w] = ss; }
  __syncthreads();
  s = rs[0] + rs[1] + rs[2] + rs[3];
  ss = rss[0] + rss[1] + rss[2] + rss[3];
  float mean = s * (1.f / 1024.f);
  float var = ss * (1.f / 1024.f) - mean * mean;
  float rstd = rsqrtf(var + 1e-6f);
  f4v sh = *(const f4v*)&shiftN[(size_t)tb * strideN + t * 4];
  f4v sc = *(const f4v*)&scaleN[(size_t)tb * strideN + t * 4];
  s4v ho;
  #pragma unroll
  for (int i = 0; i < 4; i++)
    ho[i] = (short)f2bu((vv[i] - mean) * rstd * (1.f + sc[i]) + sh[i]);
  *(s4v*)&h[(size_t)row * 1024 + t * 4] = ho;
}

extern "C" void kernel_launch(void* const* d_in, const int* in_sizes, int n_in,
                              void* d_out, int out_size, void* d_ws, size_t ws_size,
                              hipStream_t stream)
{
  const float* x_in  = (const float*)d_in[0];
  const float* tim   = (const float*)d_in[1];
  const float* lab   = (const float*)d_in[2];
  const float* xmask = (const float*)d_in[3];
  const float* Wl  = (const float*)d_in[4];
  const float* bl  = (const float*)d_in[5];
  const float* Wq  = (const float*)d_in[6];
  const float* Wk  = (const float*)d_in[7];
  const float* Wv  = (const float*)d_in[8];
  const float* W1  = (const float*)d_in[9];
  const float* b1  = (const float*)d_in[10];
  const float* W2  = (const float*)d_in[11];
  const float* b2  = (const float*)d_in[12];
  const float* Wm  = (const float*)d_in[13];
  const float* bm  = (const float*)d_in[14];
  const float* Wf  = (const float*)d_in[15];
  const float* bfp = (const float*)d_in[16];
  const float* Wmf = (const float*)d_in[17];
  const float* bmf = (const float*)d_in[18];

  char* ws = (char*)d_ws;
  float* x     = (float*)(ws + 0);          // 16777216 B (global compacted)
  float* cs    = (float*)(ws + 16777216);   // 32768 B
  float* mAll  = (float*)(ws + 16809984);   // 1572864 B  [L][B][6144]
  float* m2v   = (float*)(ws + 18382848);   // 65536 B    [B][2048]
  bf16*  h     = (bf16*)(ws + 18448384);    // 8388608 B
  bf16*  qb    = (bf16*)(ws + 26836992);    // 8388608 B  (B,H,slot,D)
  bf16*  kb    = (bf16*)(ws + 35225600);    // 8388608 B  (B,H,slot,D)
  bf16*  vb    = (bf16*)(ws + 43614208);    // 8388608 B  (B,H,D,slot) V^T
  bf16*  att   = (bf16*)(ws + 52002816);    // 8388608 B  (B,slot,C)
  bf16*  f1    = (bf16*)(ws + 60391424);    // 33554432 B (4096 x 4096)
  bf16*  wqkv0 = (bf16*)(ws + 93945856);    // 6291456 B
  bf16*  w1b0  = (bf16*)(ws + 100237312);   // 8388608 B
  bf16*  w2b0  = (bf16*)(ws + 108625920);   // 8388608 B
  bf16*  wfb   = (bf16*)(ws + 117014528);   // 2097152 B
  float* ffin  = (float*)(ws + 119111680);  // 16777216 B
  int*   idxb  = (int*)(ws + 135888896);    // 16384 B
  int*   posb  = (int*)(ws + 135905280);    // 16384 B
  int*   cntb  = (int*)(ws + 135921664);    // 64 B
  int*   strtb = (int*)(ws + 135921728);    // 64 B (start[9])
  int*   t2bb  = (int*)(ws + 135921792);    // 128 B (t2b[32])
  bf16*  wqkv1 = (bf16*)(ws + 135921920);   // 6291456 B
  bf16*  w1b1  = (bf16*)(ws + 142213376);   // 8388608 B
  bf16*  w2b1  = (bf16*)(ws + 150601984);   // 8388608 B
  bf16*  part  = (bf16*)(ws + 158990592);   // 67108864 B (8 x 4096 x 1024 bf16; ends 226099456)

  bf16* wqkvS[2] = { wqkv0, wqkv1 };
  bf16* w1S[2]   = { w1b0, w1b1 };
  bf16* w2S[2]   = { w2b0, w2b1 };

  k_compact<<<1, 512, 0, stream>>>(xmask, idxb, posb, cntb, strtb, t2bb);
  k_gather<<<4096, 256, 0, stream>>>(x_in, idxb, cntb, strtb, t2bb, x);

  k_cond<<<8, 256, 0, stream>>>(tim, lab, Wl, bl, cs);
  k_small<<<12288, 256, 0, stream>>>(cs, Wm, bm, mAll, 49152, 0);
  k_small<<<512, 256, 0, stream>>>(cs, Wmf, bmf, m2v, 2048, 1);

  k_convall<<<5632, 256, 0, stream>>>(Wq, Wk, Wv, W1, W2, wqkv0, w1b0, w2b0);
  k_lnmod<<<4096, 256, 0, stream>>>(x, mAll + 0, mAll + 1024, 6144, cntb, strtb, t2bb, h);

  for (int l = 0; l < 8; l++) {
    const float* m6b = mAll + (size_t)l * 49152;
    int sel = l & 1, nsel = sel ^ 1;
    int last = (l == 7);

    k_gemm<0, 64><<<dim3(48, 32), 256, 0, stream>>>(h, wqkvS[sel], nullptr, 1024, 1024, 3072,
                                                    cntb, strtb, t2bb, qb, nullptr);
    if (!last) {
      k_attn<<<dim3(26, 128), 256, 0, stream>>>(qb, kb, vb, cntb, att,
          Wq + (size_t)(l + 1) * 1048576, Wk + (size_t)(l + 1) * 1048576,
          Wv + (size_t)(l + 1) * 1048576, W1 + (size_t)(l + 1) * 4194304,
          W2 + (size_t)(l + 1) * 4194304,
          wqkvS[nsel], w1S[nsel], w2S[nsel], 0);
    } else {
      k_attn<<<dim3(26, 128), 256, 0, stream>>>(qb, kb, vb, cntb, att,
          Wf, Wf, Wf, Wf, Wf, wfb, wfb, wfb, 1);
    }
    k_resid<<<4096, 256, 0, stream>>>(x, att, m6b, cntb, strtb, t2bb, h);
    k_gemm<1, 64><<<dim3(64, 32), 256, 0, stream>>>(h, w1S[sel], b1 + l * 4096, 1024, 1024, 4096,
                                                    cntb, strtb, t2bb, f1, nullptr);
    k_gemm<4, 128><<<dim3(8, 32, 8), 256, 0, stream>>>(f1, w2S[sel], nullptr, 4096, 512, 1024,
                                                       cntb, strtb, t2bb, part, nullptr);
    const float* nShift = last ? m2v : (mAll + (size_t)(l + 1) * 49152);
    const float* nScale = last ? (m2v + 1024) : (mAll + (size_t)(l + 1) * 49152 + 1024);
    int nStride = last ? 2048 : 6144;
    k_comb<<<4096, 256, 0, stream>>>(part, b2 + l * 1024, m6b + 5120,
                                     nShift, nScale, nStride,
                                     x, cntb, strtb, t2bb, h);
  }

  k_gemm<3, 64><<<dim3(16, 32), 256, 0, stream>>>(h, wfb, bfp, 1024, 1024, 1024,
                                                  cntb, strtb, t2bb, nullptr, ffin);
  k_scatter<<<4096, 256, 0, stream>>>(ffin, posb, strtb, (float*)d_out);
}